// Round 1
// baseline (1229.195 us; speedup 1.0000x reference)
//
#include <hip/hip_runtime.h>

#define N_NODES_C 50000
#define N_EDGES_C 600000
#define NODE_DIM_C 64
#define EDGE_DIM_C 16
#define HID 128
#define N_GRAPHS_C 256
#define BN_EPS_C 1e-5f

// ---------------- node encoder: h = x @ node_w + node_b ----------------
__global__ __launch_bounds__(128)
void k_node_encode(const float* __restrict__ x, const float* __restrict__ w,
                   const float* __restrict__ b, float* __restrict__ h) {
  __shared__ float ws[NODE_DIM_C * HID];   // 32 KB
  __shared__ float xs[8][NODE_DIM_C];      // 2 KB
  int t = threadIdx.x;
  for (int i = t; i < NODE_DIM_C * HID; i += 128) ws[i] = w[i];
  int n0 = blockIdx.x * 8;
  for (int i = t; i < 8 * NODE_DIM_C; i += 128) {
    int r = i >> 6, c = i & 63;
    int n = n0 + r;
    xs[r][c] = (n < N_NODES_C) ? x[(size_t)n * NODE_DIM_C + c] : 0.f;
  }
  __syncthreads();
  float bias = b[t];
  for (int r = 0; r < 8; ++r) {
    int n = n0 + r;
    if (n >= N_NODES_C) return;
    float acc = bias;
#pragma unroll
    for (int k = 0; k < NODE_DIM_C; ++k) acc += xs[r][k] * ws[k * HID + t];
    h[(size_t)n * HID + t] = acc;
  }
}

// ---------------- CSR build (counting sort by dst) ----------------
__global__ __launch_bounds__(256)
void k_histogram(const int* __restrict__ dst, int* __restrict__ counts) {
  int e = blockIdx.x * 256 + threadIdx.x;
  if (e < N_EDGES_C) atomicAdd(&counts[dst[e]], 1);
}

// single-block exclusive scan; cnt buffer becomes the bucket cursor in place
__global__ __launch_bounds__(1024)
void k_scan(int* cnt, int* row_ptr) {
  __shared__ int sums[1024];
  int t = threadIdx.x;
  const int CH = (N_NODES_C + 1023) / 1024;  // 49
  int base = t * CH;
  int s = 0;
  for (int i = 0; i < CH; ++i) {
    int idx = base + i;
    if (idx < N_NODES_C) s += cnt[idx];
  }
  sums[t] = s;
  __syncthreads();
  for (int d = 1; d < 1024; d <<= 1) {
    int v = (t >= d) ? sums[t - d] : 0;
    __syncthreads();
    sums[t] += v;
    __syncthreads();
  }
  int run = sums[t] - s;  // exclusive prefix of this thread's chunk
  for (int i = 0; i < CH; ++i) {
    int idx = base + i;
    if (idx < N_NODES_C) {
      int c = cnt[idx];
      row_ptr[idx] = run;
      cnt[idx] = run;   // cursor init
      run += c;
    }
  }
  if (t == 1023) row_ptr[N_NODES_C] = sums[1023];
}

__global__ __launch_bounds__(256)
void k_bucket(const int* __restrict__ dst, int* __restrict__ cursor,
              int* __restrict__ perm) {
  int e = blockIdx.x * 256 + threadIdx.x;
  if (e < N_EDGES_C) {
    int p = atomicAdd(&cursor[dst[e]], 1);
    perm[p] = e;
  }
}

// -------- aggregate: z[n] = h[n] + sum_{e: dst=n} relu(h[src_e] + ea_e) -----
// one wave per node; each lane owns 2 features; edge-encoder computed on the fly
__global__ __launch_bounds__(256)
void k_aggregate(const float* __restrict__ h, const float* __restrict__ eattr,
                 const float* __restrict__ ew, const float* __restrict__ ebias,
                 const int* __restrict__ srcArr, const int* __restrict__ perm,
                 const int* __restrict__ row_ptr, float* __restrict__ z) {
  int t = threadIdx.x;
  int lane = t & 63;
  int wave = t >> 6;
  int node = blockIdx.x * 4 + wave;
  if (node >= N_NODES_C) return;
  int f0 = lane * 2;
  float w0[EDGE_DIM_C], w1[EDGE_DIM_C];
#pragma unroll
  for (int k = 0; k < EDGE_DIM_C; ++k) {
    float2 wv = *(const float2*)&ew[k * HID + f0];
    w0[k] = wv.x; w1[k] = wv.y;
  }
  float2 bv = *(const float2*)&ebias[f0];
  float2 hv = *(const float2*)&h[(size_t)node * HID + f0];
  float acc0 = hv.x, acc1 = hv.y;
  int beg = row_ptr[node], end = row_ptr[node + 1];
  for (int i = beg; i < end; ++i) {
    int e = perm[i];
    int s = srcArr[e];
    const float4* a4 = (const float4*)(eattr + (size_t)e * EDGE_DIM_C);
    float4 A0 = a4[0], A1 = a4[1], A2 = a4[2], A3 = a4[3];
    float a[16] = {A0.x, A0.y, A0.z, A0.w, A1.x, A1.y, A1.z, A1.w,
                   A2.x, A2.y, A2.z, A2.w, A3.x, A3.y, A3.z, A3.w};
    float m0 = bv.x, m1 = bv.y;
#pragma unroll
    for (int k = 0; k < EDGE_DIM_C; ++k) { m0 += a[k] * w0[k]; m1 += a[k] * w1[k]; }
    float2 hs = *(const float2*)&h[(size_t)s * HID + f0];
    m0 += hs.x; m1 += hs.y;
    acc0 += fmaxf(m0, 0.f);
    acc1 += fmaxf(m1, 0.f);
  }
  *(float2*)&z[(size_t)node * HID + f0] = make_float2(acc0, acc1);
}

// ------------- [50000,128] @ [128,128] + bias (opt relu, opt BN stats) -------
template <bool RELU, bool STATS>
__global__ __launch_bounds__(256)
void k_gemm128(const float* __restrict__ in, const float* __restrict__ W,
               const float* __restrict__ bias, float* __restrict__ out,
               float* __restrict__ gsum, float* __restrict__ gsumsq) {
  __shared__ float ws[HID * HID];  // 64 KB
  __shared__ float xs[32 * HID];   // 16 KB
  int t = threadIdx.x;
  for (int i = t; i < HID * HID; i += 256) ws[i] = W[i];
  int r0 = blockIdx.x * 32;
  for (int i = t; i < 32 * HID; i += 256) {
    int r = i >> 7, c = i & 127;
    int rr = r0 + r;
    xs[i] = (rr < N_NODES_C) ? in[(size_t)rr * HID + c] : 0.f;
  }
  __syncthreads();
  int f0 = (t & 63) * 2;
  int rg = t >> 6;  // 4 row groups of 8
  float2 bv = *(const float2*)&bias[f0];
  float a0[8], a1[8];
#pragma unroll
  for (int r = 0; r < 8; ++r) { a0[r] = bv.x; a1[r] = bv.y; }
  for (int k = 0; k < HID; ++k) {
    float2 wv = *(const float2*)&ws[k * HID + f0];
#pragma unroll
    for (int r = 0; r < 8; ++r) {
      float xv = xs[(rg * 8 + r) * HID + k];  // wave-uniform -> LDS broadcast
      a0[r] += xv * wv.x;
      a1[r] += xv * wv.y;
    }
  }
  float s0 = 0, s1 = 0, q0 = 0, q1 = 0;
#pragma unroll
  for (int r = 0; r < 8; ++r) {
    int row = r0 + rg * 8 + r;
    if (row < N_NODES_C) {
      float v0 = a0[r], v1 = a1[r];
      if (RELU) { v0 = fmaxf(v0, 0.f); v1 = fmaxf(v1, 0.f); }
      *(float2*)&out[(size_t)row * HID + f0] = make_float2(v0, v1);
      if (STATS) { s0 += v0; s1 += v1; q0 += v0 * v0; q1 += v1 * v1; }
    }
  }
  if (STATS) {
    __syncthreads();
    float* red = xs;  // reuse
    red[rg * 256 + f0] = s0;
    red[rg * 256 + f0 + 1] = s1;
    red[1024 + rg * 256 + f0] = q0;
    red[1024 + rg * 256 + f0 + 1] = q1;
    __syncthreads();
    if (t < HID) {
      float s = red[t] + red[256 + t] + red[512 + t] + red[768 + t];
      atomicAdd(&gsum[t], s);
    } else {
      int f = t - HID;
      float q = red[1024 + f] + red[1280 + f] + red[1536 + f] + red[1792 + f];
      atomicAdd(&gsumsq[f], q);
    }
  }
}

__global__ void k_bn_finalize(const float* __restrict__ gsum, const float* __restrict__ gsumsq,
                              const float* __restrict__ gamma, const float* __restrict__ beta,
                              float* __restrict__ scale, float* __restrict__ shift) {
  int f = threadIdx.x;  // 128
  float mean = gsum[f] * (1.f / N_NODES_C);
  float var = gsumsq[f] * (1.f / N_NODES_C) - mean * mean;
  float inv = rsqrtf(var + BN_EPS_C);
  float sc = gamma[f] * inv;
  scale[f] = sc;
  shift[f] = beta[f] - mean * sc;
}

__global__ __launch_bounds__(256)
void k_bn_relu(const float* __restrict__ t2, const float* __restrict__ scale,
               const float* __restrict__ shift, float* __restrict__ h) {
  __shared__ float sc[HID], sh[HID];
  int t = threadIdx.x;
  if (t < HID) { sc[t] = scale[t]; sh[t] = shift[t]; }
  __syncthreads();
  size_t idx = ((size_t)blockIdx.x * 256 + t) * 4;
  if (idx < (size_t)N_NODES_C * HID) {
    float4 v = *(const float4*)&t2[idx];
    int f = (int)(idx & 127);
    v.x = fmaxf(v.x * sc[f] + sh[f], 0.f);
    v.y = fmaxf(v.y * sc[f + 1] + sh[f + 1], 0.f);
    v.z = fmaxf(v.z * sc[f + 2] + sh[f + 2], 0.f);
    v.w = fmaxf(v.w * sc[f + 3] + sh[f + 3], 0.f);
    *(float4*)&h[idx] = v;
  }
}

// ---------------- pool: g = segment_sum(h, batch) ; batch is sorted ---------
__global__ __launch_bounds__(128)
void k_pool(const float* __restrict__ h, const int* __restrict__ batch,
            float* __restrict__ g) {
  int t = threadIdx.x;
  int n0 = blockIdx.x * 64;
  if (n0 >= N_NODES_C) return;
  int end = min(n0 + 64, N_NODES_C);
  int cur = batch[n0];
  float acc = 0.f;
  for (int n = n0; n < end; ++n) {
    int b = batch[n];
    if (b != cur) {
      atomicAdd(&g[cur * HID + t], acc);
      acc = 0.f;
      cur = b;
    }
    acc += h[(size_t)n * HID + t];
  }
  atomicAdd(&g[cur * HID + t], acc);
}

// ---------------- head: relu(g@w1+b1)@w2+b2 ----------------
__global__ __launch_bounds__(128)
void k_head(const float* __restrict__ g, const float* __restrict__ w1,
            const float* __restrict__ b1, const float* __restrict__ w2,
            const float* __restrict__ b2, float* __restrict__ out) {
  __shared__ float gs[HID];
  __shared__ float red[HID * 2];
  int gi = blockIdx.x, t = threadIdx.x;
  gs[t] = g[gi * HID + t];
  __syncthreads();
  float acc = b1[t];
#pragma unroll 8
  for (int k = 0; k < HID; ++k) acc += gs[k] * w1[k * HID + t];
  float hid = fmaxf(acc, 0.f);
  red[t * 2] = hid * w2[t * 2];
  red[t * 2 + 1] = hid * w2[t * 2 + 1];
  __syncthreads();
  for (int s = 64; s > 0; s >>= 1) {
    if (t < s) { red[t * 2] += red[(t + s) * 2]; red[t * 2 + 1] += red[(t + s) * 2 + 1]; }
    __syncthreads();
  }
  if (t == 0) {
    out[gi * 2] = red[0] + b2[0];
    out[gi * 2 + 1] = red[1] + b2[1];
  }
}

extern "C" void kernel_launch(void* const* d_in, const int* in_sizes, int n_in,
                              void* d_out, int out_size, void* d_ws, size_t ws_size,
                              hipStream_t stream) {
  const float* x      = (const float*)d_in[0];
  const int*   eidx   = (const int*)d_in[1];
  const float* eattr  = (const float*)d_in[2];
  const int*   batch  = (const int*)d_in[3];
  const float* node_w = (const float*)d_in[4];
  const float* node_b = (const float*)d_in[5];
  const float* edge_w = (const float*)d_in[6];
  const float* edge_b = (const float*)d_in[7];
  const float* mlp_w1 = (const float*)d_in[8];
  const float* mlp_b1 = (const float*)d_in[9];
  const float* mlp_w2 = (const float*)d_in[10];
  const float* mlp_b2 = (const float*)d_in[11];
  const float* bn_g   = (const float*)d_in[12];
  const float* bn_b   = (const float*)d_in[13];
  const float* hw1    = (const float*)d_in[14];
  const float* hb1    = (const float*)d_in[15];
  const float* hw2    = (const float*)d_in[16];
  const float* hb2    = (const float*)d_in[17];
  const int* srcArr = eidx;
  const int* dstArr = eidx + N_EDGES_C;

  char* wsp = (char*)d_ws;
  size_t off = 0;
  auto alloc = [&](size_t bytes) {
    void* p = wsp + off;
    off += (bytes + 255) & ~(size_t)255;
    return p;
  };
  float* h      = (float*)alloc((size_t)N_NODES_C * HID * 4);  // 25.6 MB
  float* bufA   = (float*)alloc((size_t)N_NODES_C * HID * 4);  // 25.6 MB
  float* bufB   = (float*)alloc((size_t)N_NODES_C * HID * 4);  // 25.6 MB
  int* row_ptr  = (int*)alloc((N_NODES_C + 1) * 4);
  int* cnt_cur  = (int*)alloc(N_NODES_C * 4);
  int* perm     = (int*)alloc((size_t)N_EDGES_C * 4);
  float* gsum   = (float*)alloc(HID * 4);
  float* gsumsq = (float*)alloc(HID * 4);
  float* scale  = (float*)alloc(HID * 4);
  float* shift  = (float*)alloc(HID * 4);
  float* g      = (float*)alloc((size_t)N_GRAPHS_C * HID * 4);

  hipMemsetAsync(cnt_cur, 0, N_NODES_C * 4, stream);
  hipMemsetAsync(g, 0, (size_t)N_GRAPHS_C * HID * 4, stream);

  k_node_encode<<<(N_NODES_C + 7) / 8, 128, 0, stream>>>(x, node_w, node_b, h);
  k_histogram<<<(N_EDGES_C + 255) / 256, 256, 0, stream>>>(dstArr, cnt_cur);
  k_scan<<<1, 1024, 0, stream>>>(cnt_cur, row_ptr);
  k_bucket<<<(N_EDGES_C + 255) / 256, 256, 0, stream>>>(dstArr, cnt_cur, perm);

  for (int l = 0; l < 3; ++l) {
    k_aggregate<<<(N_NODES_C + 3) / 4, 256, 0, stream>>>(h, eattr, edge_w, edge_b,
                                                         srcArr, perm, row_ptr, bufA);
    k_gemm128<true, false><<<(N_NODES_C + 31) / 32, 256, 0, stream>>>(
        bufA, mlp_w1 + (size_t)l * HID * HID, mlp_b1 + l * HID, bufB, nullptr, nullptr);
    hipMemsetAsync(gsum, 0, HID * 4, stream);
    hipMemsetAsync(gsumsq, 0, HID * 4, stream);
    k_gemm128<false, true><<<(N_NODES_C + 31) / 32, 256, 0, stream>>>(
        bufB, mlp_w2 + (size_t)l * HID * HID, mlp_b2 + l * HID, bufA, gsum, gsumsq);
    k_bn_finalize<<<1, HID, 0, stream>>>(gsum, gsumsq, bn_g + l * HID, bn_b + l * HID,
                                         scale, shift);
    k_bn_relu<<<(N_NODES_C * HID / 4 + 255) / 256, 256, 0, stream>>>(bufA, scale, shift, h);
  }
  k_pool<<<(N_NODES_C + 63) / 64, 128, 0, stream>>>(h, batch, g);
  k_head<<<N_GRAPHS_C, 128, 0, stream>>>(g, hw1, hb1, hw2, hb2, (float*)d_out);
}

// Round 2
// 1171.524 us; speedup vs baseline: 1.0492x; 1.0492x over previous
//
#include <hip/hip_runtime.h>

#define N_NODES_C 50000
#define N_EDGES_C 600000
#define NODE_DIM_C 64
#define EDGE_DIM_C 16
#define HID 128
#define N_GRAPHS_C 256
#define BN_EPS_C 1e-5f

// ---------------- node encoder: h = x @ node_w + node_b ----------------
__global__ __launch_bounds__(128)
void k_node_encode(const float* __restrict__ x, const float* __restrict__ w,
                   const float* __restrict__ b, float* __restrict__ h) {
  __shared__ float ws[NODE_DIM_C * HID];   // 32 KB
  __shared__ float xs[8][NODE_DIM_C];      // 2 KB
  int t = threadIdx.x;
  for (int i = t; i < NODE_DIM_C * HID; i += 128) ws[i] = w[i];
  int n0 = blockIdx.x * 8;
  for (int i = t; i < 8 * NODE_DIM_C; i += 128) {
    int r = i >> 6, c = i & 63;
    int n = n0 + r;
    xs[r][c] = (n < N_NODES_C) ? x[(size_t)n * NODE_DIM_C + c] : 0.f;
  }
  __syncthreads();
  float bias = b[t];
  for (int r = 0; r < 8; ++r) {
    int n = n0 + r;
    if (n >= N_NODES_C) return;
    float acc = bias;
#pragma unroll
    for (int k = 0; k < NODE_DIM_C; ++k) acc += xs[r][k] * ws[k * HID + t];
    h[(size_t)n * HID + t] = acc;
  }
}

// ---------------- CSR build (counting sort by dst) ----------------
__global__ __launch_bounds__(256)
void k_histogram(const int* __restrict__ dst, int* __restrict__ counts) {
  int e = blockIdx.x * 256 + threadIdx.x;
  if (e < N_EDGES_C) atomicAdd(&counts[dst[e]], 1);
}

__global__ __launch_bounds__(1024)
void k_scan(int* cnt, int* row_ptr) {
  __shared__ int sums[1024];
  int t = threadIdx.x;
  const int CH = (N_NODES_C + 1023) / 1024;  // 49
  int base = t * CH;
  int s = 0;
  for (int i = 0; i < CH; ++i) {
    int idx = base + i;
    if (idx < N_NODES_C) s += cnt[idx];
  }
  sums[t] = s;
  __syncthreads();
  for (int d = 1; d < 1024; d <<= 1) {
    int v = (t >= d) ? sums[t - d] : 0;
    __syncthreads();
    sums[t] += v;
    __syncthreads();
  }
  int run = sums[t] - s;
  for (int i = 0; i < CH; ++i) {
    int idx = base + i;
    if (idx < N_NODES_C) {
      int c = cnt[idx];
      row_ptr[idx] = run;
      cnt[idx] = run;
      run += c;
    }
  }
  if (t == 1023) row_ptr[N_NODES_C] = sums[1023];
}

__global__ __launch_bounds__(256)
void k_bucket(const int* __restrict__ dst, int* __restrict__ cursor,
              int* __restrict__ perm) {
  int e = blockIdx.x * 256 + threadIdx.x;
  if (e < N_EDGES_C) {
    int p = atomicAdd(&cursor[dst[e]], 1);
    perm[p] = e;
  }
}

// ---- gather pass: src_perm[i] = src[perm[i]], eattr_perm[i] = eattr[perm[i]]
__global__ __launch_bounds__(256)
void k_permute(const int* __restrict__ perm, const int* __restrict__ srcArr,
               const float* __restrict__ eattr, int* __restrict__ src_perm,
               float4* __restrict__ eattr_perm) {
  int i = blockIdx.x * 256 + threadIdx.x;
  if (i >= N_EDGES_C) return;
  int e = perm[i];
  src_perm[i] = srcArr[e];
  const float4* a = (const float4*)(eattr + (size_t)e * EDGE_DIM_C);
  float4 A0 = a[0], A1 = a[1], A2 = a[2], A3 = a[3];
  float4* o = eattr_perm + (size_t)i * 4;
  o[0] = A0; o[1] = A1; o[2] = A2; o[3] = A3;
}

// -------- aggregate: z[n] = h[n] + sum_{e: dst=n} relu(h[src_e] + ea_e) -----
// one wave per node, feature-parallel (2 floats/lane), edges unrolled x2 with
// batched src prefetch; edge-encoder (16->128) computed on the fly.
__global__ __launch_bounds__(256)
void k_aggregate(const float* __restrict__ h, const float4* __restrict__ eattr_p,
                 const float* __restrict__ ew, const float* __restrict__ ebias,
                 const int* __restrict__ src_p, const int* __restrict__ row_ptr,
                 float* __restrict__ z) {
  int t = threadIdx.x;
  int lane = t & 63;
  int wave = t >> 6;
  int node = blockIdx.x * 4 + wave;
  if (node >= N_NODES_C) return;
  int f0 = lane * 2;
  float w0[EDGE_DIM_C], w1[EDGE_DIM_C];
#pragma unroll
  for (int k = 0; k < EDGE_DIM_C; ++k) {
    float2 wv = *(const float2*)&ew[k * HID + f0];
    w0[k] = wv.x; w1[k] = wv.y;
  }
  float2 bv = *(const float2*)&ebias[f0];
  float2 hv = *(const float2*)&h[(size_t)node * HID + f0];
  float acc0 = hv.x, acc1 = hv.y;
  int beg = row_ptr[node], end = row_ptr[node + 1];

  for (int b = beg; b < end; b += 64) {
    int nb = min(64, end - b);
    // one parallel round trip for up to 64 edge sources
    int s_l = (lane < nb) ? src_p[b + lane] : 0;
    int j = 0;
    for (; j + 2 <= nb; j += 2) {
      int s0 = __shfl(s_l, j);
      int s1 = __shfl(s_l, j + 1);
      const float4* A = eattr_p + (size_t)(b + j) * 4;
      float4 A0 = A[0], A1 = A[1], A2 = A[2], A3 = A[3];
      float4 C0 = A[4], C1 = A[5], C2 = A[6], C3 = A[7];
      float2 h0 = *(const float2*)&h[(size_t)s0 * HID + f0];
      float2 h1 = *(const float2*)&h[(size_t)s1 * HID + f0];
      float a[16] = {A0.x, A0.y, A0.z, A0.w, A1.x, A1.y, A1.z, A1.w,
                     A2.x, A2.y, A2.z, A2.w, A3.x, A3.y, A3.z, A3.w};
      float c[16] = {C0.x, C0.y, C0.z, C0.w, C1.x, C1.y, C1.z, C1.w,
                     C2.x, C2.y, C2.z, C2.w, C3.x, C3.y, C3.z, C3.w};
      float m0 = bv.x + h0.x, m1 = bv.y + h0.y;
      float n0 = bv.x + h1.x, n1 = bv.y + h1.y;
#pragma unroll
      for (int k = 0; k < EDGE_DIM_C; ++k) {
        m0 += a[k] * w0[k]; m1 += a[k] * w1[k];
        n0 += c[k] * w0[k]; n1 += c[k] * w1[k];
      }
      acc0 += fmaxf(m0, 0.f) + fmaxf(n0, 0.f);
      acc1 += fmaxf(m1, 0.f) + fmaxf(n1, 0.f);
    }
    if (j < nb) {  // tail edge
      int s0 = __shfl(s_l, j);
      const float4* A = eattr_p + (size_t)(b + j) * 4;
      float4 A0 = A[0], A1 = A[1], A2 = A[2], A3 = A[3];
      float2 h0 = *(const float2*)&h[(size_t)s0 * HID + f0];
      float a[16] = {A0.x, A0.y, A0.z, A0.w, A1.x, A1.y, A1.z, A1.w,
                     A2.x, A2.y, A2.z, A2.w, A3.x, A3.y, A3.z, A3.w};
      float m0 = bv.x + h0.x, m1 = bv.y + h0.y;
#pragma unroll
      for (int k = 0; k < EDGE_DIM_C; ++k) { m0 += a[k] * w0[k]; m1 += a[k] * w1[k]; }
      acc0 += fmaxf(m0, 0.f);
      acc1 += fmaxf(m1, 0.f);
    }
  }
  *(float2*)&z[(size_t)node * HID + f0] = make_float2(acc0, acc1);
}

// ------------- [50000,128] @ [128,128] + bias (opt relu, opt BN stats) -------
template <bool RELU, bool STATS>
__global__ __launch_bounds__(256)
void k_gemm128(const float* __restrict__ in, const float* __restrict__ W,
               const float* __restrict__ bias, float* __restrict__ out,
               float* __restrict__ gsum, float* __restrict__ gsumsq) {
  __shared__ float ws[HID * HID];  // 64 KB
  __shared__ float xs[32 * HID];   // 16 KB
  int t = threadIdx.x;
  for (int i = t; i < HID * HID; i += 256) ws[i] = W[i];
  int r0 = blockIdx.x * 32;
  for (int i = t; i < 32 * HID; i += 256) {
    int r = i >> 7, c = i & 127;
    int rr = r0 + r;
    xs[i] = (rr < N_NODES_C) ? in[(size_t)rr * HID + c] : 0.f;
  }
  __syncthreads();
  int f0 = (t & 63) * 2;
  int rg = t >> 6;
  float2 bv = *(const float2*)&bias[f0];
  float a0[8], a1[8];
#pragma unroll
  for (int r = 0; r < 8; ++r) { a0[r] = bv.x; a1[r] = bv.y; }
  for (int k = 0; k < HID; ++k) {
    float2 wv = *(const float2*)&ws[k * HID + f0];
#pragma unroll
    for (int r = 0; r < 8; ++r) {
      float xv = xs[(rg * 8 + r) * HID + k];
      a0[r] += xv * wv.x;
      a1[r] += xv * wv.y;
    }
  }
  float s0 = 0, s1 = 0, q0 = 0, q1 = 0;
#pragma unroll
  for (int r = 0; r < 8; ++r) {
    int row = r0 + rg * 8 + r;
    if (row < N_NODES_C) {
      float v0 = a0[r], v1 = a1[r];
      if (RELU) { v0 = fmaxf(v0, 0.f); v1 = fmaxf(v1, 0.f); }
      *(float2*)&out[(size_t)row * HID + f0] = make_float2(v0, v1);
      if (STATS) { s0 += v0; s1 += v1; q0 += v0 * v0; q1 += v1 * v1; }
    }
  }
  if (STATS) {
    __syncthreads();
    float* red = xs;
    red[rg * 256 + f0] = s0;
    red[rg * 256 + f0 + 1] = s1;
    red[1024 + rg * 256 + f0] = q0;
    red[1024 + rg * 256 + f0 + 1] = q1;
    __syncthreads();
    if (t < HID) {
      float s = red[t] + red[256 + t] + red[512 + t] + red[768 + t];
      atomicAdd(&gsum[t], s);
    } else {
      int f = t - HID;
      float q = red[1024 + f] + red[1280 + f] + red[1536 + f] + red[1792 + f];
      atomicAdd(&gsumsq[f], q);
    }
  }
}

__global__ void k_bn_finalize(const float* __restrict__ gsum, const float* __restrict__ gsumsq,
                              const float* __restrict__ gamma, const float* __restrict__ beta,
                              float* __restrict__ scale, float* __restrict__ shift) {
  int f = threadIdx.x;  // 128
  float mean = gsum[f] * (1.f / N_NODES_C);
  float var = gsumsq[f] * (1.f / N_NODES_C) - mean * mean;
  float inv = rsqrtf(var + BN_EPS_C);
  float sc = gamma[f] * inv;
  scale[f] = sc;
  shift[f] = beta[f] - mean * sc;
}

__global__ __launch_bounds__(256)
void k_bn_relu(const float* __restrict__ t2, const float* __restrict__ scale,
               const float* __restrict__ shift, float* __restrict__ h) {
  __shared__ float sc[HID], sh[HID];
  int t = threadIdx.x;
  if (t < HID) { sc[t] = scale[t]; sh[t] = shift[t]; }
  __syncthreads();
  size_t idx = ((size_t)blockIdx.x * 256 + t) * 4;
  if (idx < (size_t)N_NODES_C * HID) {
    float4 v = *(const float4*)&t2[idx];
    int f = (int)(idx & 127);
    v.x = fmaxf(v.x * sc[f] + sh[f], 0.f);
    v.y = fmaxf(v.y * sc[f + 1] + sh[f + 1], 0.f);
    v.z = fmaxf(v.z * sc[f + 2] + sh[f + 2], 0.f);
    v.w = fmaxf(v.w * sc[f + 3] + sh[f + 3], 0.f);
    *(float4*)&h[idx] = v;
  }
}

// ---------------- pool: g = segment_sum(h, batch) ; batch is sorted ---------
__global__ __launch_bounds__(128)
void k_pool(const float* __restrict__ h, const int* __restrict__ batch,
            float* __restrict__ g) {
  int t = threadIdx.x;
  int n0 = blockIdx.x * 64;
  if (n0 >= N_NODES_C) return;
  int end = min(n0 + 64, N_NODES_C);
  int cur = batch[n0];
  float acc = 0.f;
  for (int n = n0; n < end; ++n) {
    int b = batch[n];
    if (b != cur) {
      atomicAdd(&g[cur * HID + t], acc);
      acc = 0.f;
      cur = b;
    }
    acc += h[(size_t)n * HID + t];
  }
  atomicAdd(&g[cur * HID + t], acc);
}

// ---------------- head: relu(g@w1+b1)@w2+b2 ----------------
__global__ __launch_bounds__(128)
void k_head(const float* __restrict__ g, const float* __restrict__ w1,
            const float* __restrict__ b1, const float* __restrict__ w2,
            const float* __restrict__ b2, float* __restrict__ out) {
  __shared__ float gs[HID];
  __shared__ float red[HID * 2];
  int gi = blockIdx.x, t = threadIdx.x;
  gs[t] = g[gi * HID + t];
  __syncthreads();
  float acc = b1[t];
#pragma unroll 8
  for (int k = 0; k < HID; ++k) acc += gs[k] * w1[k * HID + t];
  float hid = fmaxf(acc, 0.f);
  red[t * 2] = hid * w2[t * 2];
  red[t * 2 + 1] = hid * w2[t * 2 + 1];
  __syncthreads();
  for (int s = 64; s > 0; s >>= 1) {
    if (t < s) { red[t * 2] += red[(t + s) * 2]; red[t * 2 + 1] += red[(t + s) * 2 + 1]; }
    __syncthreads();
  }
  if (t == 0) {
    out[gi * 2] = red[0] + b2[0];
    out[gi * 2 + 1] = red[1] + b2[1];
  }
}

extern "C" void kernel_launch(void* const* d_in, const int* in_sizes, int n_in,
                              void* d_out, int out_size, void* d_ws, size_t ws_size,
                              hipStream_t stream) {
  const float* x      = (const float*)d_in[0];
  const int*   eidx   = (const int*)d_in[1];
  const float* eattr  = (const float*)d_in[2];
  const int*   batch  = (const int*)d_in[3];
  const float* node_w = (const float*)d_in[4];
  const float* node_b = (const float*)d_in[5];
  const float* edge_w = (const float*)d_in[6];
  const float* edge_b = (const float*)d_in[7];
  const float* mlp_w1 = (const float*)d_in[8];
  const float* mlp_b1 = (const float*)d_in[9];
  const float* mlp_w2 = (const float*)d_in[10];
  const float* mlp_b2 = (const float*)d_in[11];
  const float* bn_g   = (const float*)d_in[12];
  const float* bn_b   = (const float*)d_in[13];
  const float* hw1    = (const float*)d_in[14];
  const float* hb1    = (const float*)d_in[15];
  const float* hw2    = (const float*)d_in[16];
  const float* hb2    = (const float*)d_in[17];
  const int* srcArr = eidx;
  const int* dstArr = eidx + N_EDGES_C;

  char* wsp = (char*)d_ws;
  size_t off = 0;
  auto alloc = [&](size_t bytes) {
    void* p = wsp + off;
    off += (bytes + 255) & ~(size_t)255;
    return p;
  };
  float* h        = (float*)alloc((size_t)N_NODES_C * HID * 4);  // 25.6 MB
  float* bufA     = (float*)alloc((size_t)N_NODES_C * HID * 4);  // 25.6 MB
  float* bufB     = (float*)alloc((size_t)N_NODES_C * HID * 4);  // 25.6 MB
  int* row_ptr    = (int*)alloc((N_NODES_C + 1) * 4);
  int* cnt_cur    = (int*)alloc(N_NODES_C * 4);
  int* perm       = (int*)alloc((size_t)N_EDGES_C * 4);
  int* src_perm   = (int*)alloc((size_t)N_EDGES_C * 4);
  float4* eattr_p = (float4*)alloc((size_t)N_EDGES_C * EDGE_DIM_C * 4);  // 38.4 MB
  float* gsum     = (float*)alloc(HID * 4);
  float* gsumsq   = (float*)alloc(HID * 4);
  float* scale    = (float*)alloc(HID * 4);
  float* shift    = (float*)alloc(HID * 4);
  float* g        = (float*)alloc((size_t)N_GRAPHS_C * HID * 4);

  hipMemsetAsync(cnt_cur, 0, N_NODES_C * 4, stream);
  hipMemsetAsync(g, 0, (size_t)N_GRAPHS_C * HID * 4, stream);

  k_node_encode<<<(N_NODES_C + 7) / 8, 128, 0, stream>>>(x, node_w, node_b, h);
  k_histogram<<<(N_EDGES_C + 255) / 256, 256, 0, stream>>>(dstArr, cnt_cur);
  k_scan<<<1, 1024, 0, stream>>>(cnt_cur, row_ptr);
  k_bucket<<<(N_EDGES_C + 255) / 256, 256, 0, stream>>>(dstArr, cnt_cur, perm);
  k_permute<<<(N_EDGES_C + 255) / 256, 256, 0, stream>>>(perm, srcArr, eattr,
                                                         src_perm, eattr_p);

  for (int l = 0; l < 3; ++l) {
    k_aggregate<<<(N_NODES_C + 3) / 4, 256, 0, stream>>>(h, eattr_p, edge_w, edge_b,
                                                         src_perm, row_ptr, bufA);
    k_gemm128<true, false><<<(N_NODES_C + 31) / 32, 256, 0, stream>>>(
        bufA, mlp_w1 + (size_t)l * HID * HID, mlp_b1 + l * HID, bufB, nullptr, nullptr);
    hipMemsetAsync(gsum, 0, HID * 4, stream);
    hipMemsetAsync(gsumsq, 0, HID * 4, stream);
    k_gemm128<false, true><<<(N_NODES_C + 31) / 32, 256, 0, stream>>>(
        bufB, mlp_w2 + (size_t)l * HID * HID, mlp_b2 + l * HID, bufA, gsum, gsumsq);
    k_bn_finalize<<<1, HID, 0, stream>>>(gsum, gsumsq, bn_g + l * HID, bn_b + l * HID,
                                         scale, shift);
    k_bn_relu<<<(N_NODES_C * HID / 4 + 255) / 256, 256, 0, stream>>>(bufA, scale, shift, h);
  }
  k_pool<<<(N_NODES_C + 63) / 64, 128, 0, stream>>>(h, batch, g);
  k_head<<<N_GRAPHS_C, 128, 0, stream>>>(g, hw1, hb1, hw2, hb2, (float*)d_out);
}

// Round 3
// 985.272 us; speedup vs baseline: 1.2476x; 1.1890x over previous
//
#include <hip/hip_runtime.h>

#define N_NODES_C 50000
#define N_EDGES_C 600000
#define NODE_DIM_C 64
#define EDGE_DIM_C 16
#define HID 128
#define N_GRAPHS_C 256
#define BN_EPS_C 1e-5f

typedef short bf16x8 __attribute__((ext_vector_type(8)));
typedef float f32x4 __attribute__((ext_vector_type(4)));
typedef unsigned short ushort_t;

__device__ __forceinline__ unsigned short f2bf(float f) {
  union { float f; unsigned u; } v; v.f = f;
  unsigned r = (v.u + 0x7fffu + ((v.u >> 16) & 1u)) >> 16;
  return (unsigned short)r;
}

// ---------------- node encoder: h = x @ node_w + node_b (fp32) ----------------
__global__ __launch_bounds__(128)
void k_node_encode(const float* __restrict__ x, const float* __restrict__ w,
                   const float* __restrict__ b, float* __restrict__ h) {
  __shared__ float ws[NODE_DIM_C * HID];   // 32 KB
  __shared__ float xs[8][NODE_DIM_C];
  int t = threadIdx.x;
  for (int i = t; i < NODE_DIM_C * HID; i += 128) ws[i] = w[i];
  int n0 = blockIdx.x * 8;
  for (int i = t; i < 8 * NODE_DIM_C; i += 128) {
    int r = i >> 6, c = i & 63;
    int n = n0 + r;
    xs[r][c] = (n < N_NODES_C) ? x[(size_t)n * NODE_DIM_C + c] : 0.f;
  }
  __syncthreads();
  float bias = b[t];
  for (int r = 0; r < 8; ++r) {
    int n = n0 + r;
    if (n >= N_NODES_C) return;
    float acc = bias;
#pragma unroll
    for (int k = 0; k < NODE_DIM_C; ++k) acc += xs[r][k] * ws[k * HID + t];
    h[(size_t)n * HID + t] = acc;
  }
}

// ------- weight prep: wT[m][n*128+k] = bf16(W_m[k*128+n]), 6 matrices -------
__global__ __launch_bounds__(256)
void k_prep_w(const float* __restrict__ w1, const float* __restrict__ w2,
              unsigned short* __restrict__ wT) {
  int m = blockIdx.x;  // 0..5
  const float* src = (m < 3) ? (w1 + (size_t)m * HID * HID)
                             : (w2 + (size_t)(m - 3) * HID * HID);
  unsigned short* dst = wT + (size_t)m * HID * HID;
  for (int i = threadIdx.x; i < HID * HID; i += 256) {
    int n = i >> 7, k = i & 127;
    dst[n * HID + k] = f2bf(src[k * HID + n]);
  }
}

// ---------------- CSR build (counting sort by dst) ----------------
__global__ __launch_bounds__(256)
void k_histogram(const int* __restrict__ dst, int* __restrict__ counts) {
  int e = blockIdx.x * 256 + threadIdx.x;
  if (e < N_EDGES_C) atomicAdd(&counts[dst[e]], 1);
}

__global__ __launch_bounds__(1024)
void k_scan(int* cnt, int* row_ptr) {
  __shared__ int sums[1024];
  int t = threadIdx.x;
  const int CH = (N_NODES_C + 1023) / 1024;  // 49
  int base = t * CH;
  int s = 0;
  for (int i = 0; i < CH; ++i) {
    int idx = base + i;
    if (idx < N_NODES_C) s += cnt[idx];
  }
  sums[t] = s;
  __syncthreads();
  for (int d = 1; d < 1024; d <<= 1) {
    int v = (t >= d) ? sums[t - d] : 0;
    __syncthreads();
    sums[t] += v;
    __syncthreads();
  }
  int run = sums[t] - s;
  for (int i = 0; i < CH; ++i) {
    int idx = base + i;
    if (idx < N_NODES_C) {
      int c = cnt[idx];
      row_ptr[idx] = run;
      cnt[idx] = run;
      run += c;
    }
  }
  if (t == 1023) row_ptr[N_NODES_C] = sums[1023];
}

__global__ __launch_bounds__(256)
void k_bucket(const int* __restrict__ dst, int* __restrict__ cursor,
              int* __restrict__ perm) {
  int e = blockIdx.x * 256 + threadIdx.x;
  if (e < N_EDGES_C) {
    int p = atomicAdd(&cursor[dst[e]], 1);
    perm[p] = e;
  }
}

__global__ __launch_bounds__(256)
void k_permute(const int* __restrict__ perm, const int* __restrict__ srcArr,
               const float* __restrict__ eattr, int* __restrict__ src_perm,
               float4* __restrict__ eattr_perm) {
  int i = blockIdx.x * 256 + threadIdx.x;
  if (i >= N_EDGES_C) return;
  int e = perm[i];
  src_perm[i] = srcArr[e];
  const float4* a = (const float4*)(eattr + (size_t)e * EDGE_DIM_C);
  float4 A0 = a[0], A1 = a[1], A2 = a[2], A3 = a[3];
  float4* o = eattr_perm + (size_t)i * 4;
  o[0] = A0; o[1] = A1; o[2] = A2; o[3] = A3;
}

// -------- aggregate: z[n] = h[n] + sum_{e: dst=n} relu(h[src_e] + ea_e) -----
// one wave per node, 2 feats/lane; edges x4 unrolled; output bf16
__global__ __launch_bounds__(256)
void k_aggregate(const float* __restrict__ h, const float4* __restrict__ eattr_p,
                 const float* __restrict__ ew, const float* __restrict__ ebias,
                 const int* __restrict__ src_p, const int* __restrict__ row_ptr,
                 unsigned short* __restrict__ z) {
  int t = threadIdx.x;
  int lane = t & 63;
  int wave = t >> 6;
  int node = blockIdx.x * 4 + wave;
  if (node >= N_NODES_C) return;
  int f0 = lane * 2;
  float w0[EDGE_DIM_C], w1[EDGE_DIM_C];
#pragma unroll
  for (int k = 0; k < EDGE_DIM_C; ++k) {
    float2 wv = *(const float2*)&ew[k * HID + f0];
    w0[k] = wv.x; w1[k] = wv.y;
  }
  float2 bv = *(const float2*)&ebias[f0];
  float2 hv = *(const float2*)&h[(size_t)node * HID + f0];
  float acc0 = hv.x, acc1 = hv.y;
  int beg = row_ptr[node], end = row_ptr[node + 1];

  for (int b = beg; b < end; b += 64) {
    int nb = min(64, end - b);
    int s_l = (lane < nb) ? src_p[b + lane] : 0;
    int j = 0;
    for (; j + 4 <= nb; j += 4) {
      int s0 = __shfl(s_l, j), s1 = __shfl(s_l, j + 1);
      int s2 = __shfl(s_l, j + 2), s3 = __shfl(s_l, j + 3);
      float2 h0 = *(const float2*)&h[(size_t)s0 * HID + f0];
      float2 h1 = *(const float2*)&h[(size_t)s1 * HID + f0];
      float2 h2 = *(const float2*)&h[(size_t)s2 * HID + f0];
      float2 h3 = *(const float2*)&h[(size_t)s3 * HID + f0];
      const float4* A = eattr_p + (size_t)(b + j) * 4;
      float4 A0 = A[0], A1 = A[1], A2 = A[2], A3 = A[3];
      float4 B0 = A[4], B1 = A[5], B2 = A[6], B3 = A[7];
      float4 C0 = A[8], C1 = A[9], C2 = A[10], C3 = A[11];
      float4 D0 = A[12], D1 = A[13], D2 = A[14], D3 = A[15];
      float a[16] = {A0.x, A0.y, A0.z, A0.w, A1.x, A1.y, A1.z, A1.w,
                     A2.x, A2.y, A2.z, A2.w, A3.x, A3.y, A3.z, A3.w};
      float bb[16] = {B0.x, B0.y, B0.z, B0.w, B1.x, B1.y, B1.z, B1.w,
                      B2.x, B2.y, B2.z, B2.w, B3.x, B3.y, B3.z, B3.w};
      float c[16] = {C0.x, C0.y, C0.z, C0.w, C1.x, C1.y, C1.z, C1.w,
                     C2.x, C2.y, C2.z, C2.w, C3.x, C3.y, C3.z, C3.w};
      float d[16] = {D0.x, D0.y, D0.z, D0.w, D1.x, D1.y, D1.z, D1.w,
                     D2.x, D2.y, D2.z, D2.w, D3.x, D3.y, D3.z, D3.w};
      float m0 = bv.x + h0.x, m1 = bv.y + h0.y;
      float n0 = bv.x + h1.x, n1 = bv.y + h1.y;
      float p0 = bv.x + h2.x, p1 = bv.y + h2.y;
      float q0 = bv.x + h3.x, q1 = bv.y + h3.y;
#pragma unroll
      for (int k = 0; k < EDGE_DIM_C; ++k) {
        m0 += a[k] * w0[k];  m1 += a[k] * w1[k];
        n0 += bb[k] * w0[k]; n1 += bb[k] * w1[k];
        p0 += c[k] * w0[k];  p1 += c[k] * w1[k];
        q0 += d[k] * w0[k];  q1 += d[k] * w1[k];
      }
      acc0 += fmaxf(m0, 0.f) + fmaxf(n0, 0.f) + fmaxf(p0, 0.f) + fmaxf(q0, 0.f);
      acc1 += fmaxf(m1, 0.f) + fmaxf(n1, 0.f) + fmaxf(p1, 0.f) + fmaxf(q1, 0.f);
    }
    for (; j < nb; ++j) {
      int s0 = __shfl(s_l, j);
      const float4* A = eattr_p + (size_t)(b + j) * 4;
      float4 A0 = A[0], A1 = A[1], A2 = A[2], A3 = A[3];
      float2 h0 = *(const float2*)&h[(size_t)s0 * HID + f0];
      float a[16] = {A0.x, A0.y, A0.z, A0.w, A1.x, A1.y, A1.z, A1.w,
                     A2.x, A2.y, A2.z, A2.w, A3.x, A3.y, A3.z, A3.w};
      float m0 = bv.x + h0.x, m1 = bv.y + h0.y;
#pragma unroll
      for (int k = 0; k < EDGE_DIM_C; ++k) { m0 += a[k] * w0[k]; m1 += a[k] * w1[k]; }
      acc0 += fmaxf(m0, 0.f);
      acc1 += fmaxf(m1, 0.f);
    }
  }
  unsigned int packed = (unsigned int)f2bf(acc0) | ((unsigned int)f2bf(acc1) << 16);
  *(unsigned int*)&z[(size_t)node * HID + f0] = packed;
}

// ---------- MFMA GEMM: [50000,128](bf16) @ W^T[128,128](bf16) + bias --------
// 128x128 tile per block, K=128 fully LDS-resident, 4 waves, each wave 32 rows.
// wT layout: [n][k] so B-fragment loads are contiguous.
template <bool RELU, bool BF16OUT>
__global__ __launch_bounds__(256)
void k_gemm_mfma(const unsigned short* __restrict__ in,
                 const unsigned short* __restrict__ wT,
                 const float* __restrict__ bias,
                 unsigned short* __restrict__ outb, float* __restrict__ outf) {
  const int LDA = HID + 8;  // pad 8 bf16 -> +16B per row, breaks bank aliasing
  __shared__ unsigned short a_lds[128 * LDA];  // 34 KB
  __shared__ unsigned short w_lds[128 * LDA];  // 34 KB
  int t = threadIdx.x;
  int row0 = blockIdx.x * 128;
  {
    int r = t >> 4, chunk = t & 15;
#pragma unroll
    for (int it = 0; it < 8; ++it) {
      int row = it * 16 + r;
      int grow = row0 + row;
      uint4 va = (grow < N_NODES_C)
                     ? ((const uint4*)(in + (size_t)grow * HID))[chunk]
                     : make_uint4(0, 0, 0, 0);
      *(uint4*)&a_lds[row * LDA + chunk * 8] = va;
      uint4 vw = ((const uint4*)(wT + (size_t)row * HID))[chunk];
      *(uint4*)&w_lds[row * LDA + chunk * 8] = vw;
    }
  }
  __syncthreads();

  int lane = t & 63;
  int w = t >> 6;
  int l15 = lane & 15;
  int q = lane >> 4;

  f32x4 acc[2][8];
#pragma unroll
  for (int rt = 0; rt < 2; ++rt)
#pragma unroll
    for (int nt = 0; nt < 8; ++nt) acc[rt][nt] = (f32x4)0.f;

#pragma unroll
  for (int kk = 0; kk < 4; ++kk) {
    int k0 = kk * 32;
    bf16x8 af[2];
#pragma unroll
    for (int rt = 0; rt < 2; ++rt) {
      int arow = w * 32 + rt * 16 + l15;
      af[rt] = *(const bf16x8*)&a_lds[arow * LDA + k0 + q * 8];
    }
#pragma unroll
    for (int nt = 0; nt < 8; ++nt) {
      int brow = nt * 16 + l15;
      bf16x8 bf = *(const bf16x8*)&w_lds[brow * LDA + k0 + q * 8];
#pragma unroll
      for (int rt = 0; rt < 2; ++rt)
        acc[rt][nt] = __builtin_amdgcn_mfma_f32_16x16x32_bf16(af[rt], bf, acc[rt][nt], 0, 0, 0);
    }
  }

  // epilogue: D row=(lane>>4)*4+i, col=lane&15  [m89-verified]
#pragma unroll
  for (int nt = 0; nt < 8; ++nt) {
    int gcol = nt * 16 + l15;
    float bv = bias[gcol];
#pragma unroll
    for (int rt = 0; rt < 2; ++rt) {
#pragma unroll
      for (int i = 0; i < 4; ++i) {
        int grow = row0 + w * 32 + rt * 16 + q * 4 + i;
        if (grow < N_NODES_C) {
          float v = acc[rt][nt][i] + bv;
          if (RELU) v = fmaxf(v, 0.f);
          if (BF16OUT)
            outb[(size_t)grow * HID + gcol] = f2bf(v);
          else
            outf[(size_t)grow * HID + gcol] = v;
        }
      }
    }
  }
}

// ------------- column stats over t2 [50000,128] fp32 -> gsum, gsumsq --------
__global__ __launch_bounds__(256)
void k_colstats(const float* __restrict__ t2, float* __restrict__ gsum,
                float* __restrict__ gsumsq) {
  __shared__ float4 ls[256], lq[256];
  int t = threadIdx.x;
  int cg = t & 31;   // 4 cols each
  int rs = t >> 5;   // 8 row-slices
  int base = blockIdx.x * 512;
  float4 s = make_float4(0, 0, 0, 0), qq = make_float4(0, 0, 0, 0);
  for (int r = rs; r < 512; r += 8) {
    int row = base + r;
    if (row < N_NODES_C) {
      float4 v = ((const float4*)t2)[(size_t)row * 32 + cg];
      s.x += v.x; s.y += v.y; s.z += v.z; s.w += v.w;
      qq.x += v.x * v.x; qq.y += v.y * v.y; qq.z += v.z * v.z; qq.w += v.w * v.w;
    }
  }
  ls[t] = s; lq[t] = qq;
  __syncthreads();
  if (rs == 0) {
#pragma unroll
    for (int i = 1; i < 8; ++i) {
      float4 a = ls[i * 32 + cg], b = lq[i * 32 + cg];
      s.x += a.x; s.y += a.y; s.z += a.z; s.w += a.w;
      qq.x += b.x; qq.y += b.y; qq.z += b.z; qq.w += b.w;
    }
    atomicAdd(&gsum[cg * 4 + 0], s.x);
    atomicAdd(&gsum[cg * 4 + 1], s.y);
    atomicAdd(&gsum[cg * 4 + 2], s.z);
    atomicAdd(&gsum[cg * 4 + 3], s.w);
    atomicAdd(&gsumsq[cg * 4 + 0], qq.x);
    atomicAdd(&gsumsq[cg * 4 + 1], qq.y);
    atomicAdd(&gsumsq[cg * 4 + 2], qq.z);
    atomicAdd(&gsumsq[cg * 4 + 3], qq.w);
  }
}

__global__ void k_bn_finalize(const float* __restrict__ gsum, const float* __restrict__ gsumsq,
                              const float* __restrict__ gamma, const float* __restrict__ beta,
                              float* __restrict__ scale, float* __restrict__ shift) {
  int f = threadIdx.x;  // 128
  float mean = gsum[f] * (1.f / N_NODES_C);
  float var = gsumsq[f] * (1.f / N_NODES_C) - mean * mean;
  float inv = rsqrtf(var + BN_EPS_C);
  float sc = gamma[f] * inv;
  scale[f] = sc;
  shift[f] = beta[f] - mean * sc;
}

__global__ __launch_bounds__(256)
void k_bn_relu(const float* __restrict__ t2, const float* __restrict__ scale,
               const float* __restrict__ shift, float* __restrict__ h) {
  __shared__ float sc[HID], sh[HID];
  int t = threadIdx.x;
  if (t < HID) { sc[t] = scale[t]; sh[t] = shift[t]; }
  __syncthreads();
  size_t idx = ((size_t)blockIdx.x * 256 + t) * 4;
  if (idx < (size_t)N_NODES_C * HID) {
    float4 v = *(const float4*)&t2[idx];
    int f = (int)(idx & 127);
    v.x = fmaxf(v.x * sc[f] + sh[f], 0.f);
    v.y = fmaxf(v.y * sc[f + 1] + sh[f + 1], 0.f);
    v.z = fmaxf(v.z * sc[f + 2] + sh[f + 2], 0.f);
    v.w = fmaxf(v.w * sc[f + 3] + sh[f + 3], 0.f);
    *(float4*)&h[idx] = v;
  }
}

// ---------------- pool: g = segment_sum(h, batch) ; batch is sorted ---------
__global__ __launch_bounds__(128)
void k_pool(const float* __restrict__ h, const int* __restrict__ batch,
            float* __restrict__ g) {
  int t = threadIdx.x;
  int n0 = blockIdx.x * 64;
  if (n0 >= N_NODES_C) return;
  int end = min(n0 + 64, N_NODES_C);
  int cur = batch[n0];
  float acc = 0.f;
  for (int n = n0; n < end; ++n) {
    int b = batch[n];
    if (b != cur) {
      atomicAdd(&g[cur * HID + t], acc);
      acc = 0.f;
      cur = b;
    }
    acc += h[(size_t)n * HID + t];
  }
  atomicAdd(&g[cur * HID + t], acc);
}

// ---------------- head: relu(g@w1+b1)@w2+b2 ----------------
__global__ __launch_bounds__(128)
void k_head(const float* __restrict__ g, const float* __restrict__ w1,
            const float* __restrict__ b1, const float* __restrict__ w2,
            const float* __restrict__ b2, float* __restrict__ out) {
  __shared__ float gs[HID];
  __shared__ float red[HID * 2];
  int gi = blockIdx.x, t = threadIdx.x;
  gs[t] = g[gi * HID + t];
  __syncthreads();
  float acc = b1[t];
#pragma unroll 8
  for (int k = 0; k < HID; ++k) acc += gs[k] * w1[k * HID + t];
  float hid = fmaxf(acc, 0.f);
  red[t * 2] = hid * w2[t * 2];
  red[t * 2 + 1] = hid * w2[t * 2 + 1];
  __syncthreads();
  for (int s = 64; s > 0; s >>= 1) {
    if (t < s) { red[t * 2] += red[(t + s) * 2]; red[t * 2 + 1] += red[(t + s) * 2 + 1]; }
    __syncthreads();
  }
  if (t == 0) {
    out[gi * 2] = red[0] + b2[0];
    out[gi * 2 + 1] = red[1] + b2[1];
  }
}

extern "C" void kernel_launch(void* const* d_in, const int* in_sizes, int n_in,
                              void* d_out, int out_size, void* d_ws, size_t ws_size,
                              hipStream_t stream) {
  const float* x      = (const float*)d_in[0];
  const int*   eidx   = (const int*)d_in[1];
  const float* eattr  = (const float*)d_in[2];
  const int*   batch  = (const int*)d_in[3];
  const float* node_w = (const float*)d_in[4];
  const float* node_b = (const float*)d_in[5];
  const float* edge_w = (const float*)d_in[6];
  const float* edge_b = (const float*)d_in[7];
  const float* mlp_w1 = (const float*)d_in[8];
  const float* mlp_b1 = (const float*)d_in[9];
  const float* mlp_w2 = (const float*)d_in[10];
  const float* mlp_b2 = (const float*)d_in[11];
  const float* bn_g   = (const float*)d_in[12];
  const float* bn_b   = (const float*)d_in[13];
  const float* hw1    = (const float*)d_in[14];
  const float* hb1    = (const float*)d_in[15];
  const float* hw2    = (const float*)d_in[16];
  const float* hb2    = (const float*)d_in[17];
  const int* srcArr = eidx;
  const int* dstArr = eidx + N_EDGES_C;

  char* wsp = (char*)d_ws;
  size_t off = 0;
  auto alloc = [&](size_t bytes) {
    void* p = wsp + off;
    off += (bytes + 255) & ~(size_t)255;
    return p;
  };
  float* h             = (float*)alloc((size_t)N_NODES_C * HID * 4);   // 25.6 MB
  unsigned short* zbf  = (unsigned short*)alloc((size_t)N_NODES_C * HID * 2);  // 12.8 MB
  unsigned short* t1bf = (unsigned short*)alloc((size_t)N_NODES_C * HID * 2);  // 12.8 MB
  float* t2f           = (float*)alloc((size_t)N_NODES_C * HID * 4);   // 25.6 MB
  unsigned short* wT   = (unsigned short*)alloc((size_t)6 * HID * HID * 2);    // 192 KB
  int* row_ptr   = (int*)alloc((N_NODES_C + 1) * 4);
  int* cnt_cur   = (int*)alloc(N_NODES_C * 4);
  int* perm      = (int*)alloc((size_t)N_EDGES_C * 4);
  int* src_perm  = (int*)alloc((size_t)N_EDGES_C * 4);
  float4* eattr_p = (float4*)alloc((size_t)N_EDGES_C * EDGE_DIM_C * 4);  // 38.4 MB
  float* gsum    = (float*)alloc(HID * 4);
  float* gsumsq  = (float*)alloc(HID * 4);
  float* scale   = (float*)alloc(HID * 4);
  float* shift   = (float*)alloc(HID * 4);
  float* g       = (float*)alloc((size_t)N_GRAPHS_C * HID * 4);

  hipMemsetAsync(cnt_cur, 0, N_NODES_C * 4, stream);
  hipMemsetAsync(g, 0, (size_t)N_GRAPHS_C * HID * 4, stream);

  k_node_encode<<<(N_NODES_C + 7) / 8, 128, 0, stream>>>(x, node_w, node_b, h);
  k_prep_w<<<6, 256, 0, stream>>>(mlp_w1, mlp_w2, wT);
  k_histogram<<<(N_EDGES_C + 255) / 256, 256, 0, stream>>>(dstArr, cnt_cur);
  k_scan<<<1, 1024, 0, stream>>>(cnt_cur, row_ptr);
  k_bucket<<<(N_EDGES_C + 255) / 256, 256, 0, stream>>>(dstArr, cnt_cur, perm);
  k_permute<<<(N_EDGES_C + 255) / 256, 256, 0, stream>>>(perm, srcArr, eattr,
                                                         src_perm, eattr_p);

  const int GB = (N_NODES_C + 127) / 128;  // 391
  for (int l = 0; l < 3; ++l) {
    k_aggregate<<<(N_NODES_C + 3) / 4, 256, 0, stream>>>(h, eattr_p, edge_w, edge_b,
                                                         src_perm, row_ptr, zbf);
    k_gemm_mfma<true, true><<<GB, 256, 0, stream>>>(
        zbf, wT + (size_t)l * HID * HID, mlp_b1 + l * HID, t1bf, nullptr);
    k_gemm_mfma<false, false><<<GB, 256, 0, stream>>>(
        t1bf, wT + (size_t)(3 + l) * HID * HID, mlp_b2 + l * HID, nullptr, t2f);
    hipMemsetAsync(gsum, 0, HID * 4, stream);
    hipMemsetAsync(gsumsq, 0, HID * 4, stream);
    k_colstats<<<(N_NODES_C + 511) / 512, 256, 0, stream>>>(t2f, gsum, gsumsq);
    k_bn_finalize<<<1, HID, 0, stream>>>(gsum, gsumsq, bn_g + l * HID, bn_b + l * HID,
                                         scale, shift);
    k_bn_relu<<<(N_NODES_C * HID / 4 + 255) / 256, 256, 0, stream>>>(t2f, scale, shift, h);
  }
  k_pool<<<(N_NODES_C + 63) / 64, 128, 0, stream>>>(h, batch, g);
  k_head<<<N_GRAPHS_C, 128, 0, stream>>>(g, hw1, hb1, hw2, hb2, (float*)d_out);
}

// Round 4
// 846.769 us; speedup vs baseline: 1.4516x; 1.1636x over previous
//
#include <hip/hip_runtime.h>

#define N_NODES_C 50000
#define N_EDGES_C 600000
#define NODE_DIM_C 64
#define EDGE_DIM_C 16
#define HID 128
#define N_GRAPHS_C 256
#define BN_EPS_C 1e-5f
#define SCAN_NBLK ((N_NODES_C + 255) / 256)  // 196

typedef short bf16x8 __attribute__((ext_vector_type(8)));
typedef float f32x4 __attribute__((ext_vector_type(4)));

__device__ __forceinline__ unsigned short f2bf(float f) {
  union { float f; unsigned u; } v; v.f = f;
  unsigned r = (v.u + 0x7fffu + ((v.u >> 16) & 1u)) >> 16;
  return (unsigned short)r;
}

// packed pair of bf16 (lo = feat f0, hi = feat f0+1) -> two floats
__device__ __forceinline__ float2 bfp2f(unsigned u) {
  union { unsigned u; float f; } lo, hi;
  lo.u = u << 16;
  hi.u = u & 0xffff0000u;
  return make_float2(lo.f, hi.f);
}

// ---------------- node encoder: h = x @ node_w + node_b (fp32) ----------------
__global__ __launch_bounds__(128)
void k_node_encode(const float* __restrict__ x, const float* __restrict__ w,
                   const float* __restrict__ b, float* __restrict__ h) {
  __shared__ float ws[NODE_DIM_C * HID];   // 32 KB
  __shared__ float xs[8][NODE_DIM_C];
  int t = threadIdx.x;
  for (int i = t; i < NODE_DIM_C * HID; i += 128) ws[i] = w[i];
  int n0 = blockIdx.x * 8;
  for (int i = t; i < 8 * NODE_DIM_C; i += 128) {
    int r = i >> 6, c = i & 63;
    int n = n0 + r;
    xs[r][c] = (n < N_NODES_C) ? x[(size_t)n * NODE_DIM_C + c] : 0.f;
  }
  __syncthreads();
  float bias = b[t];
  for (int r = 0; r < 8; ++r) {
    int n = n0 + r;
    if (n >= N_NODES_C) return;
    float acc = bias;
#pragma unroll
    for (int k = 0; k < NODE_DIM_C; ++k) acc += xs[r][k] * ws[k * HID + t];
    h[(size_t)n * HID + t] = acc;
  }
}

// ------- weight prep: wT[m][n*128+k] = bf16(W_m[k*128+n]), 6 matrices -------
__global__ __launch_bounds__(256)
void k_prep_w(const float* __restrict__ w1, const float* __restrict__ w2,
              unsigned short* __restrict__ wT) {
  int m = blockIdx.x;  // 0..5
  const float* src = (m < 3) ? (w1 + (size_t)m * HID * HID)
                             : (w2 + (size_t)(m - 3) * HID * HID);
  unsigned short* dst = wT + (size_t)m * HID * HID;
  for (int i = threadIdx.x; i < HID * HID; i += 256) {
    int n = i >> 7, k = i & 127;
    dst[n * HID + k] = f2bf(src[k * HID + n]);
  }
}

// ---------------- CSR build (counting sort by dst) ----------------
__global__ __launch_bounds__(256)
void k_histogram(const int* __restrict__ dst, int* __restrict__ counts) {
  int e = blockIdx.x * 256 + threadIdx.x;
  if (e < N_EDGES_C) atomicAdd(&counts[dst[e]], 1);
}

// --- parallel scan, stage 1: per-block (256 nodes) sums ---
__global__ __launch_bounds__(256)
void k_blocksum(const int* __restrict__ cnt, int* __restrict__ partial) {
  __shared__ int ls[4];
  int t = threadIdx.x;
  int i = blockIdx.x * 256 + t;
  int v = (i < N_NODES_C) ? cnt[i] : 0;
#pragma unroll
  for (int o = 32; o > 0; o >>= 1) v += __shfl_down(v, o, 64);
  if ((t & 63) == 0) ls[t >> 6] = v;
  __syncthreads();
  if (t == 0) partial[blockIdx.x] = ls[0] + ls[1] + ls[2] + ls[3];
}

// --- stage 2: exclusive scan of the 196 block sums (1 block) ---
__global__ __launch_bounds__(256)
void k_scanpartials(const int* __restrict__ partial, int* __restrict__ partial_off) {
  __shared__ int s[256];
  int t = threadIdx.x;
  int v = (t < SCAN_NBLK) ? partial[t] : 0;
  s[t] = v;
  __syncthreads();
  for (int d = 1; d < 256; d <<= 1) {
    int x = (t >= d) ? s[t - d] : 0;
    __syncthreads();
    s[t] += x;
    __syncthreads();
  }
  if (t < SCAN_NBLK) partial_off[t] = s[t] - v;
}

// --- stage 3: per-block exclusive scan + offset -> row_ptr & cursor init ---
__global__ __launch_bounds__(256)
void k_apply(int* __restrict__ cnt_cursor, const int* __restrict__ partial_off,
             int* __restrict__ row_ptr) {
  __shared__ int s[256];
  int t = threadIdx.x;
  int i = blockIdx.x * 256 + t;
  int v = (i < N_NODES_C) ? cnt_cursor[i] : 0;
  s[t] = v;
  __syncthreads();
  for (int d = 1; d < 256; d <<= 1) {
    int x = (t >= d) ? s[t - d] : 0;
    __syncthreads();
    s[t] += x;
    __syncthreads();
  }
  int excl = s[t] - v + partial_off[blockIdx.x];
  if (i < N_NODES_C) {
    row_ptr[i] = excl;
    cnt_cursor[i] = excl;  // becomes the bucket cursor
  }
  if (i == 0) row_ptr[N_NODES_C] = N_EDGES_C;
}

__global__ __launch_bounds__(256)
void k_bucket(const int* __restrict__ dst, const int* __restrict__ srcArr,
              int* __restrict__ cursor, int* __restrict__ perm,
              int* __restrict__ src_perm) {
  int e = blockIdx.x * 256 + threadIdx.x;
  if (e < N_EDGES_C) {
    int p = atomicAdd(&cursor[dst[e]], 1);
    perm[p] = e;
    src_perm[p] = srcArr[e];
  }
}

// ---- edge encoder, computed ONCE (layer-invariant): ea[i] = eattr[perm[i]]@ew + eb
// output bf16 packed pairs; one wave per edge slot, grid-stride, 2-edge unroll
__global__ __launch_bounds__(256)
void k_edge_encode(const int* __restrict__ perm, const float* __restrict__ eattr,
                   const float* __restrict__ ew, const float* __restrict__ ebias,
                   unsigned* __restrict__ ea_out) {
  int t = threadIdx.x;
  int lane = t & 63;
  int wv = blockIdx.x * 4 + (t >> 6);
  int nw = gridDim.x * 4;
  int f0 = lane * 2;
  float w0[EDGE_DIM_C], w1[EDGE_DIM_C];
#pragma unroll
  for (int k = 0; k < EDGE_DIM_C; ++k) {
    float2 wvv = *(const float2*)&ew[k * HID + f0];
    w0[k] = wvv.x; w1[k] = wvv.y;
  }
  float2 bv = *(const float2*)&ebias[f0];
  for (int i = wv; i < N_EDGES_C; i += 2 * nw) {
    int i2 = i + nw;
    bool has2 = (i2 < N_EDGES_C);
    int e1 = perm[i];
    int e2 = has2 ? perm[i2] : e1;
    const float4* p1 = (const float4*)(eattr + (size_t)e1 * EDGE_DIM_C);
    const float4* p2 = (const float4*)(eattr + (size_t)e2 * EDGE_DIM_C);
    float4 A0 = p1[0], A1 = p1[1], A2 = p1[2], A3 = p1[3];
    float4 B0 = p2[0], B1 = p2[1], B2 = p2[2], B3 = p2[3];
    float a[16] = {A0.x, A0.y, A0.z, A0.w, A1.x, A1.y, A1.z, A1.w,
                   A2.x, A2.y, A2.z, A2.w, A3.x, A3.y, A3.z, A3.w};
    float c[16] = {B0.x, B0.y, B0.z, B0.w, B1.x, B1.y, B1.z, B1.w,
                   B2.x, B2.y, B2.z, B2.w, B3.x, B3.y, B3.z, B3.w};
    float m0 = bv.x, m1 = bv.y, n0 = bv.x, n1 = bv.y;
#pragma unroll
    for (int k = 0; k < EDGE_DIM_C; ++k) {
      m0 += a[k] * w0[k]; m1 += a[k] * w1[k];
      n0 += c[k] * w0[k]; n1 += c[k] * w1[k];
    }
    ea_out[(size_t)i * 64 + lane] =
        (unsigned)f2bf(m0) | ((unsigned)f2bf(m1) << 16);
    if (has2)
      ea_out[(size_t)i2 * 64 + lane] =
          (unsigned)f2bf(n0) | ((unsigned)f2bf(n1) << 16);
  }
}

// -------- aggregate: z[n] = h[n] + sum_{e: dst=n} relu(h[src_e] + ea_e) -----
// one wave per node, 2 feats/lane; ea precomputed bf16; edges x4 unrolled
__global__ __launch_bounds__(256)
void k_aggregate(const float* __restrict__ h, const unsigned* __restrict__ ea,
                 const int* __restrict__ src_p, const int* __restrict__ row_ptr,
                 unsigned short* __restrict__ z) {
  int t = threadIdx.x;
  int lane = t & 63;
  int wave = t >> 6;
  int node = blockIdx.x * 4 + wave;
  if (node >= N_NODES_C) return;
  int f0 = lane * 2;
  float2 hv = *(const float2*)&h[(size_t)node * HID + f0];
  float acc0 = hv.x, acc1 = hv.y;
  int beg = row_ptr[node], end = row_ptr[node + 1];

  for (int b = beg; b < end; b += 64) {
    int nb = min(64, end - b);
    int s_l = (lane < nb) ? src_p[b + lane] : 0;
    int j = 0;
    for (; j + 4 <= nb; j += 4) {
      int s0 = __shfl(s_l, j), s1 = __shfl(s_l, j + 1);
      int s2 = __shfl(s_l, j + 2), s3 = __shfl(s_l, j + 3);
      float2 h0 = *(const float2*)&h[(size_t)s0 * HID + f0];
      float2 h1 = *(const float2*)&h[(size_t)s1 * HID + f0];
      float2 h2 = *(const float2*)&h[(size_t)s2 * HID + f0];
      float2 h3 = *(const float2*)&h[(size_t)s3 * HID + f0];
      unsigned u0 = ea[(size_t)(b + j) * 64 + lane];
      unsigned u1 = ea[(size_t)(b + j + 1) * 64 + lane];
      unsigned u2 = ea[(size_t)(b + j + 2) * 64 + lane];
      unsigned u3 = ea[(size_t)(b + j + 3) * 64 + lane];
      float2 e0 = bfp2f(u0), e1 = bfp2f(u1), e2 = bfp2f(u2), e3 = bfp2f(u3);
      acc0 += fmaxf(h0.x + e0.x, 0.f) + fmaxf(h1.x + e1.x, 0.f) +
              fmaxf(h2.x + e2.x, 0.f) + fmaxf(h3.x + e3.x, 0.f);
      acc1 += fmaxf(h0.y + e0.y, 0.f) + fmaxf(h1.y + e1.y, 0.f) +
              fmaxf(h2.y + e2.y, 0.f) + fmaxf(h3.y + e3.y, 0.f);
    }
    for (; j < nb; ++j) {
      int s0 = __shfl(s_l, j);
      float2 h0 = *(const float2*)&h[(size_t)s0 * HID + f0];
      float2 e0 = bfp2f(ea[(size_t)(b + j) * 64 + lane]);
      acc0 += fmaxf(h0.x + e0.x, 0.f);
      acc1 += fmaxf(h0.y + e0.y, 0.f);
    }
  }
  unsigned packed = (unsigned)f2bf(acc0) | ((unsigned)f2bf(acc1) << 16);
  *(unsigned*)&z[(size_t)node * HID + f0] = packed;
}

// ---------- MFMA GEMM: [50000,128](bf16) @ W^T[128,128](bf16) + bias --------
template <bool RELU, bool BF16OUT>
__global__ __launch_bounds__(256)
void k_gemm_mfma(const unsigned short* __restrict__ in,
                 const unsigned short* __restrict__ wT,
                 const float* __restrict__ bias,
                 unsigned short* __restrict__ outb, float* __restrict__ outf) {
  const int LDA = HID + 8;
  __shared__ unsigned short a_lds[128 * LDA];
  __shared__ unsigned short w_lds[128 * LDA];
  int t = threadIdx.x;
  int row0 = blockIdx.x * 128;
  {
    int r = t >> 4, chunk = t & 15;
#pragma unroll
    for (int it = 0; it < 8; ++it) {
      int row = it * 16 + r;
      int grow = row0 + row;
      uint4 va = (grow < N_NODES_C)
                     ? ((const uint4*)(in + (size_t)grow * HID))[chunk]
                     : make_uint4(0, 0, 0, 0);
      *(uint4*)&a_lds[row * LDA + chunk * 8] = va;
      uint4 vw = ((const uint4*)(wT + (size_t)row * HID))[chunk];
      *(uint4*)&w_lds[row * LDA + chunk * 8] = vw;
    }
  }
  __syncthreads();

  int lane = t & 63;
  int w = t >> 6;
  int l15 = lane & 15;
  int q = lane >> 4;

  f32x4 acc[2][8];
#pragma unroll
  for (int rt = 0; rt < 2; ++rt)
#pragma unroll
    for (int nt = 0; nt < 8; ++nt) acc[rt][nt] = (f32x4)0.f;

#pragma unroll
  for (int kk = 0; kk < 4; ++kk) {
    int k0 = kk * 32;
    bf16x8 af[2];
#pragma unroll
    for (int rt = 0; rt < 2; ++rt) {
      int arow = w * 32 + rt * 16 + l15;
      af[rt] = *(const bf16x8*)&a_lds[arow * LDA + k0 + q * 8];
    }
#pragma unroll
    for (int nt = 0; nt < 8; ++nt) {
      int brow = nt * 16 + l15;
      bf16x8 bf = *(const bf16x8*)&w_lds[brow * LDA + k0 + q * 8];
#pragma unroll
      for (int rt = 0; rt < 2; ++rt)
        acc[rt][nt] = __builtin_amdgcn_mfma_f32_16x16x32_bf16(af[rt], bf, acc[rt][nt], 0, 0, 0);
    }
  }

#pragma unroll
  for (int nt = 0; nt < 8; ++nt) {
    int gcol = nt * 16 + l15;
    float bv = bias[gcol];
#pragma unroll
    for (int rt = 0; rt < 2; ++rt) {
#pragma unroll
      for (int i = 0; i < 4; ++i) {
        int grow = row0 + w * 32 + rt * 16 + q * 4 + i;
        if (grow < N_NODES_C) {
          float v = acc[rt][nt][i] + bv;
          if (RELU) v = fmaxf(v, 0.f);
          if (BF16OUT)
            outb[(size_t)grow * HID + gcol] = f2bf(v);
          else
            outf[(size_t)grow * HID + gcol] = v;
        }
      }
    }
  }
}

// ------------- column stats over t2 [50000,128] fp32 -> gsum, gsumsq --------
__global__ __launch_bounds__(256)
void k_colstats(const float* __restrict__ t2, float* __restrict__ gsum,
                float* __restrict__ gsumsq) {
  __shared__ float4 ls[256], lq[256];
  int t = threadIdx.x;
  int cg = t & 31;
  int rs = t >> 5;
  int base = blockIdx.x * 512;
  float4 s = make_float4(0, 0, 0, 0), qq = make_float4(0, 0, 0, 0);
  for (int r = rs; r < 512; r += 8) {
    int row = base + r;
    if (row < N_NODES_C) {
      float4 v = ((const float4*)t2)[(size_t)row * 32 + cg];
      s.x += v.x; s.y += v.y; s.z += v.z; s.w += v.w;
      qq.x += v.x * v.x; qq.y += v.y * v.y; qq.z += v.z * v.z; qq.w += v.w * v.w;
    }
  }
  ls[t] = s; lq[t] = qq;
  __syncthreads();
  if (rs == 0) {
#pragma unroll
    for (int i = 1; i < 8; ++i) {
      float4 a = ls[i * 32 + cg], b = lq[i * 32 + cg];
      s.x += a.x; s.y += a.y; s.z += a.z; s.w += a.w;
      qq.x += b.x; qq.y += b.y; qq.z += b.z; qq.w += b.w;
    }
    atomicAdd(&gsum[cg * 4 + 0], s.x);
    atomicAdd(&gsum[cg * 4 + 1], s.y);
    atomicAdd(&gsum[cg * 4 + 2], s.z);
    atomicAdd(&gsum[cg * 4 + 3], s.w);
    atomicAdd(&gsumsq[cg * 4 + 0], qq.x);
    atomicAdd(&gsumsq[cg * 4 + 1], qq.y);
    atomicAdd(&gsumsq[cg * 4 + 2], qq.z);
    atomicAdd(&gsumsq[cg * 4 + 3], qq.w);
  }
}

__global__ void k_bn_finalize(const float* __restrict__ gsum, const float* __restrict__ gsumsq,
                              const float* __restrict__ gamma, const float* __restrict__ beta,
                              float* __restrict__ scale, float* __restrict__ shift) {
  int f = threadIdx.x;  // 128
  float mean = gsum[f] * (1.f / N_NODES_C);
  float var = gsumsq[f] * (1.f / N_NODES_C) - mean * mean;
  float inv = rsqrtf(var + BN_EPS_C);
  float sc = gamma[f] * inv;
  scale[f] = sc;
  shift[f] = beta[f] - mean * sc;
}

__global__ __launch_bounds__(256)
void k_bn_relu(const float* __restrict__ t2, const float* __restrict__ scale,
               const float* __restrict__ shift, float* __restrict__ h) {
  __shared__ float sc[HID], sh[HID];
  int t = threadIdx.x;
  if (t < HID) { sc[t] = scale[t]; sh[t] = shift[t]; }
  __syncthreads();
  size_t idx = ((size_t)blockIdx.x * 256 + t) * 4;
  if (idx < (size_t)N_NODES_C * HID) {
    float4 v = *(const float4*)&t2[idx];
    int f = (int)(idx & 127);
    v.x = fmaxf(v.x * sc[f] + sh[f], 0.f);
    v.y = fmaxf(v.y * sc[f + 1] + sh[f + 1], 0.f);
    v.z = fmaxf(v.z * sc[f + 2] + sh[f + 2], 0.f);
    v.w = fmaxf(v.w * sc[f + 3] + sh[f + 3], 0.f);
    *(float4*)&h[idx] = v;
  }
}

// ---------------- pool: g = segment_sum(h, batch) ; batch is sorted ---------
__global__ __launch_bounds__(128)
void k_pool(const float* __restrict__ h, const int* __restrict__ batch,
            float* __restrict__ g) {
  int t = threadIdx.x;
  int n0 = blockIdx.x * 64;
  if (n0 >= N_NODES_C) return;
  int end = min(n0 + 64, N_NODES_C);
  int cur = batch[n0];
  float acc = 0.f;
  for (int n = n0; n < end; ++n) {
    int b = batch[n];
    if (b != cur) {
      atomicAdd(&g[cur * HID + t], acc);
      acc = 0.f;
      cur = b;
    }
    acc += h[(size_t)n * HID + t];
  }
  atomicAdd(&g[cur * HID + t], acc);
}

// ---------------- head: relu(g@w1+b1)@w2+b2 ----------------
__global__ __launch_bounds__(128)
void k_head(const float* __restrict__ g, const float* __restrict__ w1,
            const float* __restrict__ b1, const float* __restrict__ w2,
            const float* __restrict__ b2, float* __restrict__ out) {
  __shared__ float gs[HID];
  __shared__ float red[HID * 2];
  int gi = blockIdx.x, t = threadIdx.x;
  gs[t] = g[gi * HID + t];
  __syncthreads();
  float acc = b1[t];
#pragma unroll 8
  for (int k = 0; k < HID; ++k) acc += gs[k] * w1[k * HID + t];
  float hid = fmaxf(acc, 0.f);
  red[t * 2] = hid * w2[t * 2];
  red[t * 2 + 1] = hid * w2[t * 2 + 1];
  __syncthreads();
  for (int s = 64; s > 0; s >>= 1) {
    if (t < s) { red[t * 2] += red[(t + s) * 2]; red[t * 2 + 1] += red[(t + s) * 2 + 1]; }
    __syncthreads();
  }
  if (t == 0) {
    out[gi * 2] = red[0] + b2[0];
    out[gi * 2 + 1] = red[1] + b2[1];
  }
}

extern "C" void kernel_launch(void* const* d_in, const int* in_sizes, int n_in,
                              void* d_out, int out_size, void* d_ws, size_t ws_size,
                              hipStream_t stream) {
  const float* x      = (const float*)d_in[0];
  const int*   eidx   = (const int*)d_in[1];
  const float* eattr  = (const float*)d_in[2];
  const int*   batch  = (const int*)d_in[3];
  const float* node_w = (const float*)d_in[4];
  const float* node_b = (const float*)d_in[5];
  const float* edge_w = (const float*)d_in[6];
  const float* edge_b = (const float*)d_in[7];
  const float* mlp_w1 = (const float*)d_in[8];
  const float* mlp_b1 = (const float*)d_in[9];
  const float* mlp_w2 = (const float*)d_in[10];
  const float* mlp_b2 = (const float*)d_in[11];
  const float* bn_g   = (const float*)d_in[12];
  const float* bn_b   = (const float*)d_in[13];
  const float* hw1    = (const float*)d_in[14];
  const float* hb1    = (const float*)d_in[15];
  const float* hw2    = (const float*)d_in[16];
  const float* hb2    = (const float*)d_in[17];
  const int* srcArr = eidx;
  const int* dstArr = eidx + N_EDGES_C;

  char* wsp = (char*)d_ws;
  size_t off = 0;
  auto alloc = [&](size_t bytes) {
    void* p = wsp + off;
    off += (bytes + 255) & ~(size_t)255;
    return p;
  };
  float* h             = (float*)alloc((size_t)N_NODES_C * HID * 4);            // 25.6 MB
  unsigned short* zbf  = (unsigned short*)alloc((size_t)N_NODES_C * HID * 2);   // 12.8 MB
  unsigned short* t1bf = (unsigned short*)alloc((size_t)N_NODES_C * HID * 2);   // 12.8 MB
  float* t2f           = (float*)alloc((size_t)N_NODES_C * HID * 4);            // 25.6 MB
  unsigned* ea         = (unsigned*)alloc((size_t)N_EDGES_C * 64 * 4);          // 153.6 MB
  unsigned short* wT   = (unsigned short*)alloc((size_t)6 * HID * HID * 2);     // 192 KB
  int* row_ptr   = (int*)alloc((N_NODES_C + 1) * 4);
  int* cnt_cur   = (int*)alloc(N_NODES_C * 4);
  int* perm      = (int*)alloc((size_t)N_EDGES_C * 4);
  int* src_perm  = (int*)alloc((size_t)N_EDGES_C * 4);
  int* partial   = (int*)alloc(256 * 4);
  int* partial_off = (int*)alloc(256 * 4);
  float* gsum    = (float*)alloc(HID * 4);
  float* gsumsq  = (float*)alloc(HID * 4);
  float* scale   = (float*)alloc(HID * 4);
  float* shift   = (float*)alloc(HID * 4);
  float* g       = (float*)alloc((size_t)N_GRAPHS_C * HID * 4);

  hipMemsetAsync(cnt_cur, 0, N_NODES_C * 4, stream);
  hipMemsetAsync(g, 0, (size_t)N_GRAPHS_C * HID * 4, stream);

  k_node_encode<<<(N_NODES_C + 7) / 8, 128, 0, stream>>>(x, node_w, node_b, h);
  k_prep_w<<<6, 256, 0, stream>>>(mlp_w1, mlp_w2, wT);
  k_histogram<<<(N_EDGES_C + 255) / 256, 256, 0, stream>>>(dstArr, cnt_cur);
  k_blocksum<<<SCAN_NBLK, 256, 0, stream>>>(cnt_cur, partial);
  k_scanpartials<<<1, 256, 0, stream>>>(partial, partial_off);
  k_apply<<<SCAN_NBLK, 256, 0, stream>>>(cnt_cur, partial_off, row_ptr);
  k_bucket<<<(N_EDGES_C + 255) / 256, 256, 0, stream>>>(dstArr, srcArr, cnt_cur,
                                                        perm, src_perm);
  k_edge_encode<<<1024, 256, 0, stream>>>(perm, eattr, edge_w, edge_b, ea);

  const int GB = (N_NODES_C + 127) / 128;  // 391
  for (int l = 0; l < 3; ++l) {
    k_aggregate<<<(N_NODES_C + 3) / 4, 256, 0, stream>>>(h, ea, src_perm, row_ptr, zbf);
    k_gemm_mfma<true, true><<<GB, 256, 0, stream>>>(
        zbf, wT + (size_t)l * HID * HID, mlp_b1 + l * HID, t1bf, nullptr);
    k_gemm_mfma<false, false><<<GB, 256, 0, stream>>>(
        t1bf, wT + (size_t)(3 + l) * HID * HID, mlp_b2 + l * HID, nullptr, t2f);
    hipMemsetAsync(gsum, 0, HID * 4, stream);
    hipMemsetAsync(gsumsq, 0, HID * 4, stream);
    k_colstats<<<(N_NODES_C + 511) / 512, 256, 0, stream>>>(t2f, gsum, gsumsq);
    k_bn_finalize<<<1, HID, 0, stream>>>(gsum, gsumsq, bn_g + l * HID, bn_b + l * HID,
                                         scale, shift);
    k_bn_relu<<<(N_NODES_C * HID / 4 + 255) / 256, 256, 0, stream>>>(t2f, scale, shift, h);
  }
  k_pool<<<(N_NODES_C + 63) / 64, 128, 0, stream>>>(h, batch, g);
  k_head<<<N_GRAPHS_C, 128, 0, stream>>>(g, hw1, hb1, hw2, hb2, (float*)d_out);
}

// Round 5
// 714.496 us; speedup vs baseline: 1.7204x; 1.1851x over previous
//
#include <hip/hip_runtime.h>

#define N_NODES_C 50000
#define N_EDGES_C 600000
#define NODE_DIM_C 64
#define EDGE_DIM_C 16
#define HID 128
#define N_GRAPHS_C 256
#define BN_EPS_C 1e-5f
#define SCAN_NBLK ((N_NODES_C + 255) / 256)  // 196

typedef short bf16x8 __attribute__((ext_vector_type(8)));
typedef float f32x4 __attribute__((ext_vector_type(4)));

__device__ __forceinline__ unsigned short f2bf(float f) {
  union { float f; unsigned u; } v; v.f = f;
  unsigned r = (v.u + 0x7fffu + ((v.u >> 16) & 1u)) >> 16;
  return (unsigned short)r;
}

// packed pair of bf16 (lo = feat f0, hi = feat f0+1) -> two floats
__device__ __forceinline__ float2 bfp2f(unsigned u) {
  union { unsigned u; float f; } lo, hi;
  lo.u = u << 16;
  hi.u = u & 0xffff0000u;
  return make_float2(lo.f, hi.f);
}

__device__ __forceinline__ float bf2f(unsigned short s) {
  union { unsigned u; float f; } v;
  v.u = ((unsigned)s) << 16;
  return v.f;
}

// ------------ node encoder: h = bf16(x @ node_w + node_b) ------------
__global__ __launch_bounds__(128)
void k_node_encode(const float* __restrict__ x, const float* __restrict__ w,
                   const float* __restrict__ b, unsigned short* __restrict__ h) {
  __shared__ float ws[NODE_DIM_C * HID];   // 32 KB
  __shared__ float xs[8][NODE_DIM_C];
  int t = threadIdx.x;
  for (int i = t; i < NODE_DIM_C * HID; i += 128) ws[i] = w[i];
  int n0 = blockIdx.x * 8;
  for (int i = t; i < 8 * NODE_DIM_C; i += 128) {
    int r = i >> 6, c = i & 63;
    int n = n0 + r;
    xs[r][c] = (n < N_NODES_C) ? x[(size_t)n * NODE_DIM_C + c] : 0.f;
  }
  __syncthreads();
  float bias = b[t];
  for (int r = 0; r < 8; ++r) {
    int n = n0 + r;
    if (n >= N_NODES_C) return;
    float acc = bias;
#pragma unroll
    for (int k = 0; k < NODE_DIM_C; ++k) acc += xs[r][k] * ws[k * HID + t];
    h[(size_t)n * HID + t] = f2bf(acc);
  }
}

// ------- weight prep: wT[m][n*128+k] = bf16(W_m[k*128+n]), 6 matrices -------
__global__ __launch_bounds__(256)
void k_prep_w(const float* __restrict__ w1, const float* __restrict__ w2,
              unsigned short* __restrict__ wT) {
  int m = blockIdx.x;  // 0..5
  const float* src = (m < 3) ? (w1 + (size_t)m * HID * HID)
                             : (w2 + (size_t)(m - 3) * HID * HID);
  unsigned short* dst = wT + (size_t)m * HID * HID;
  for (int i = threadIdx.x; i < HID * HID; i += 256) {
    int n = i >> 7, k = i & 127;
    dst[n * HID + k] = f2bf(src[k * HID + n]);
  }
}

// ---------------- CSR build (counting sort by dst) ----------------
__global__ __launch_bounds__(256)
void k_histogram(const int* __restrict__ dst, int* __restrict__ counts) {
  int e = blockIdx.x * 256 + threadIdx.x;
  if (e < N_EDGES_C) atomicAdd(&counts[dst[e]], 1);
}

__global__ __launch_bounds__(256)
void k_blocksum(const int* __restrict__ cnt, int* __restrict__ partial) {
  __shared__ int ls[4];
  int t = threadIdx.x;
  int i = blockIdx.x * 256 + t;
  int v = (i < N_NODES_C) ? cnt[i] : 0;
#pragma unroll
  for (int o = 32; o > 0; o >>= 1) v += __shfl_down(v, o, 64);
  if ((t & 63) == 0) ls[t >> 6] = v;
  __syncthreads();
  if (t == 0) partial[blockIdx.x] = ls[0] + ls[1] + ls[2] + ls[3];
}

__global__ __launch_bounds__(256)
void k_scanpartials(const int* __restrict__ partial, int* __restrict__ partial_off) {
  __shared__ int s[256];
  int t = threadIdx.x;
  int v = (t < SCAN_NBLK) ? partial[t] : 0;
  s[t] = v;
  __syncthreads();
  for (int d = 1; d < 256; d <<= 1) {
    int x = (t >= d) ? s[t - d] : 0;
    __syncthreads();
    s[t] += x;
    __syncthreads();
  }
  if (t < SCAN_NBLK) partial_off[t] = s[t] - v;
}

__global__ __launch_bounds__(256)
void k_apply(int* __restrict__ cnt_cursor, const int* __restrict__ partial_off,
             int* __restrict__ row_ptr) {
  __shared__ int s[256];
  int t = threadIdx.x;
  int i = blockIdx.x * 256 + t;
  int v = (i < N_NODES_C) ? cnt_cursor[i] : 0;
  s[t] = v;
  __syncthreads();
  for (int d = 1; d < 256; d <<= 1) {
    int x = (t >= d) ? s[t - d] : 0;
    __syncthreads();
    s[t] += x;
    __syncthreads();
  }
  int excl = s[t] - v + partial_off[blockIdx.x];
  if (i < N_NODES_C) {
    row_ptr[i] = excl;
    cnt_cursor[i] = excl;
  }
  if (i == 0) row_ptr[N_NODES_C] = N_EDGES_C;
}

__global__ __launch_bounds__(256)
void k_bucket(const int* __restrict__ dst, const int* __restrict__ srcArr,
              int* __restrict__ cursor, int* __restrict__ perm,
              int* __restrict__ src_perm) {
  int e = blockIdx.x * 256 + threadIdx.x;
  if (e < N_EDGES_C) {
    int p = atomicAdd(&cursor[dst[e]], 1);
    perm[p] = e;
    src_perm[p] = srcArr[e];
  }
}

// ---- edge encoder (layer-invariant, computed once):
// ea[i] = bf16(eattr[perm[i]] @ ew + eb), packed pairs, CSR edge order
__global__ __launch_bounds__(256)
void k_edge_encode(const int* __restrict__ perm, const float* __restrict__ eattr,
                   const float* __restrict__ ew, const float* __restrict__ ebias,
                   unsigned* __restrict__ ea_out) {
  int t = threadIdx.x;
  int lane = t & 63;
  int wv = blockIdx.x * 4 + (t >> 6);
  int nw = gridDim.x * 4;
  int f0 = lane * 2;
  float w0[EDGE_DIM_C], w1[EDGE_DIM_C];
#pragma unroll
  for (int k = 0; k < EDGE_DIM_C; ++k) {
    float2 wvv = *(const float2*)&ew[k * HID + f0];
    w0[k] = wvv.x; w1[k] = wvv.y;
  }
  float2 bv = *(const float2*)&ebias[f0];
  for (int i = wv; i < N_EDGES_C; i += 2 * nw) {
    int i2 = i + nw;
    bool has2 = (i2 < N_EDGES_C);
    int e1 = perm[i];
    int e2 = has2 ? perm[i2] : e1;
    const float4* p1 = (const float4*)(eattr + (size_t)e1 * EDGE_DIM_C);
    const float4* p2 = (const float4*)(eattr + (size_t)e2 * EDGE_DIM_C);
    float4 A0 = p1[0], A1 = p1[1], A2 = p1[2], A3 = p1[3];
    float4 B0 = p2[0], B1 = p2[1], B2 = p2[2], B3 = p2[3];
    float a[16] = {A0.x, A0.y, A0.z, A0.w, A1.x, A1.y, A1.z, A1.w,
                   A2.x, A2.y, A2.z, A2.w, A3.x, A3.y, A3.z, A3.w};
    float c[16] = {B0.x, B0.y, B0.z, B0.w, B1.x, B1.y, B1.z, B1.w,
                   B2.x, B2.y, B2.z, B2.w, B3.x, B3.y, B3.z, B3.w};
    float m0 = bv.x, m1 = bv.y, n0 = bv.x, n1 = bv.y;
#pragma unroll
    for (int k = 0; k < EDGE_DIM_C; ++k) {
      m0 += a[k] * w0[k]; m1 += a[k] * w1[k];
      n0 += c[k] * w0[k]; n1 += c[k] * w1[k];
    }
    ea_out[(size_t)i * 64 + lane] =
        (unsigned)f2bf(m0) | ((unsigned)f2bf(m1) << 16);
    if (has2)
      ea_out[(size_t)i2 * 64 + lane] =
          (unsigned)f2bf(n0) | ((unsigned)f2bf(n1) << 16);
  }
}

// -------- aggregate: z[n] = h[n] + sum_{e: dst=n} relu(h[src_e] + ea_e) -----
// one wave per node, 2 feats/lane; h and ea both packed bf16; edges x4 unrolled
// src indices read via same-address broadcast loads (no shfl in the chain)
__global__ __launch_bounds__(256)
void k_aggregate(const unsigned* __restrict__ h32, const unsigned* __restrict__ ea,
                 const int* __restrict__ src_p, const int* __restrict__ row_ptr,
                 unsigned short* __restrict__ z) {
  int t = threadIdx.x;
  int lane = t & 63;
  int wave = t >> 6;
  int node = blockIdx.x * 4 + wave;
  if (node >= N_NODES_C) return;
  float2 base = bfp2f(h32[(size_t)node * 64 + lane]);
  float acc0 = base.x, acc1 = base.y;
  int beg = row_ptr[node], end = row_ptr[node + 1];
  int j = beg;
  for (; j + 4 <= end; j += 4) {
    int s0 = src_p[j], s1 = src_p[j + 1], s2 = src_p[j + 2], s3 = src_p[j + 3];
    unsigned g0 = h32[(size_t)s0 * 64 + lane];
    unsigned g1 = h32[(size_t)s1 * 64 + lane];
    unsigned g2 = h32[(size_t)s2 * 64 + lane];
    unsigned g3 = h32[(size_t)s3 * 64 + lane];
    unsigned u0 = ea[(size_t)j * 64 + lane];
    unsigned u1 = ea[(size_t)(j + 1) * 64 + lane];
    unsigned u2 = ea[(size_t)(j + 2) * 64 + lane];
    unsigned u3 = ea[(size_t)(j + 3) * 64 + lane];
    float2 a0 = bfp2f(g0), a1 = bfp2f(g1), a2 = bfp2f(g2), a3 = bfp2f(g3);
    float2 e0 = bfp2f(u0), e1 = bfp2f(u1), e2 = bfp2f(u2), e3 = bfp2f(u3);
    acc0 += fmaxf(a0.x + e0.x, 0.f) + fmaxf(a1.x + e1.x, 0.f) +
            fmaxf(a2.x + e2.x, 0.f) + fmaxf(a3.x + e3.x, 0.f);
    acc1 += fmaxf(a0.y + e0.y, 0.f) + fmaxf(a1.y + e1.y, 0.f) +
            fmaxf(a2.y + e2.y, 0.f) + fmaxf(a3.y + e3.y, 0.f);
  }
  for (; j < end; ++j) {
    int s0 = src_p[j];
    float2 a0 = bfp2f(h32[(size_t)s0 * 64 + lane]);
    float2 e0 = bfp2f(ea[(size_t)j * 64 + lane]);
    acc0 += fmaxf(a0.x + e0.x, 0.f);
    acc1 += fmaxf(a0.y + e0.y, 0.f);
  }
  unsigned packed = (unsigned)f2bf(acc0) | ((unsigned)f2bf(acc1) << 16);
  *(unsigned*)&z[(size_t)node * HID + lane * 2] = packed;
}

// ---------- MFMA GEMM: [50000,128](bf16) @ W^T[128,128](bf16) + bias --------
// STATS: fused BN column sums/sumsq via LDS reduce + atomics
template <bool RELU, bool BF16OUT, bool STATS>
__global__ __launch_bounds__(256)
void k_gemm_mfma(const unsigned short* __restrict__ in,
                 const unsigned short* __restrict__ wT,
                 const float* __restrict__ bias,
                 unsigned short* __restrict__ outb, float* __restrict__ outf,
                 float* __restrict__ gsum, float* __restrict__ gsumsq) {
  const int LDA = HID + 8;
  __shared__ unsigned short a_lds[128 * LDA];  // 34 KB (reused for stats reduce)
  __shared__ unsigned short w_lds[128 * LDA];
  int t = threadIdx.x;
  int row0 = blockIdx.x * 128;
  {
    int r = t >> 4, chunk = t & 15;
#pragma unroll
    for (int it = 0; it < 8; ++it) {
      int row = it * 16 + r;
      int grow = row0 + row;
      uint4 va = (grow < N_NODES_C)
                     ? ((const uint4*)(in + (size_t)grow * HID))[chunk]
                     : make_uint4(0, 0, 0, 0);
      *(uint4*)&a_lds[row * LDA + chunk * 8] = va;
      uint4 vw = ((const uint4*)(wT + (size_t)row * HID))[chunk];
      *(uint4*)&w_lds[row * LDA + chunk * 8] = vw;
    }
  }
  __syncthreads();

  int lane = t & 63;
  int w = t >> 6;
  int l15 = lane & 15;
  int q = lane >> 4;

  f32x4 acc[2][8];
#pragma unroll
  for (int rt = 0; rt < 2; ++rt)
#pragma unroll
    for (int nt = 0; nt < 8; ++nt) acc[rt][nt] = (f32x4)0.f;

#pragma unroll
  for (int kk = 0; kk < 4; ++kk) {
    int k0 = kk * 32;
    bf16x8 af[2];
#pragma unroll
    for (int rt = 0; rt < 2; ++rt) {
      int arow = w * 32 + rt * 16 + l15;
      af[rt] = *(const bf16x8*)&a_lds[arow * LDA + k0 + q * 8];
    }
#pragma unroll
    for (int nt = 0; nt < 8; ++nt) {
      int brow = nt * 16 + l15;
      bf16x8 bf = *(const bf16x8*)&w_lds[brow * LDA + k0 + q * 8];
#pragma unroll
      for (int rt = 0; rt < 2; ++rt)
        acc[rt][nt] = __builtin_amdgcn_mfma_f32_16x16x32_bf16(af[rt], bf, acc[rt][nt], 0, 0, 0);
    }
  }

  float sp[8], qp[8];
#pragma unroll
  for (int nt = 0; nt < 8; ++nt) { sp[nt] = 0.f; qp[nt] = 0.f; }

#pragma unroll
  for (int nt = 0; nt < 8; ++nt) {
    int gcol = nt * 16 + l15;
    float bv = bias[gcol];
#pragma unroll
    for (int rt = 0; rt < 2; ++rt) {
#pragma unroll
      for (int i = 0; i < 4; ++i) {
        int grow = row0 + w * 32 + rt * 16 + q * 4 + i;
        bool ok = (grow < N_NODES_C);
        float v = acc[rt][nt][i] + bv;
        if (RELU) v = fmaxf(v, 0.f);
        if (ok) {
          if (BF16OUT)
            outb[(size_t)grow * HID + gcol] = f2bf(v);
          else
            outf[(size_t)grow * HID + gcol] = v;
        }
        if (STATS) {
          float c = ok ? v : 0.f;
          sp[nt] += c;
          qp[nt] += c * c;
        }
      }
    }
  }

  if (STATS) {
    __syncthreads();  // done reading a_lds for MFMA; reuse as reduce scratch
    float* sred = (float*)a_lds;        // [128][16]
    float* qred = sred + 128 * 16;      // [128][16]
    int slot = w * 4 + q;
#pragma unroll
    for (int nt = 0; nt < 8; ++nt) {
      int gcol = nt * 16 + l15;
      sred[gcol * 16 + slot] = sp[nt];
      qred[gcol * 16 + slot] = qp[nt];
    }
    __syncthreads();
    if (t < 128) {
      float s = 0.f;
#pragma unroll
      for (int i = 0; i < 16; ++i) s += sred[t * 16 + i];
      atomicAdd(&gsum[t], s);
    } else {
      int f = t - 128;
      float s = 0.f;
#pragma unroll
      for (int i = 0; i < 16; ++i) s += qred[f * 16 + i];
      atomicAdd(&gsumsq[f], s);
    }
  }
}

__global__ void k_bn_finalize(const float* __restrict__ gsum, const float* __restrict__ gsumsq,
                              const float* __restrict__ gamma, const float* __restrict__ beta,
                              float* __restrict__ scale, float* __restrict__ shift) {
  int f = threadIdx.x;  // 128
  float mean = gsum[f] * (1.f / N_NODES_C);
  float var = gsumsq[f] * (1.f / N_NODES_C) - mean * mean;
  float inv = rsqrtf(var + BN_EPS_C);
  float sc = gamma[f] * inv;
  scale[f] = sc;
  shift[f] = beta[f] - mean * sc;
}

// BN + relu: reads t2 fp32, writes h bf16 packed
__global__ __launch_bounds__(256)
void k_bn_relu(const float* __restrict__ t2, const float* __restrict__ scale,
               const float* __restrict__ shift, unsigned short* __restrict__ h) {
  __shared__ float sc[HID], sh[HID];
  int t = threadIdx.x;
  if (t < HID) { sc[t] = scale[t]; sh[t] = shift[t]; }
  __syncthreads();
  size_t idx = ((size_t)blockIdx.x * 256 + t) * 4;
  if (idx < (size_t)N_NODES_C * HID) {
    float4 v = *(const float4*)&t2[idx];
    int f = (int)(idx & 127);
    float r0 = fmaxf(v.x * sc[f] + sh[f], 0.f);
    float r1 = fmaxf(v.y * sc[f + 1] + sh[f + 1], 0.f);
    float r2 = fmaxf(v.z * sc[f + 2] + sh[f + 2], 0.f);
    float r3 = fmaxf(v.w * sc[f + 3] + sh[f + 3], 0.f);
    uint2 o;
    o.x = (unsigned)f2bf(r0) | ((unsigned)f2bf(r1) << 16);
    o.y = (unsigned)f2bf(r2) | ((unsigned)f2bf(r3) << 16);
    *(uint2*)&h[idx] = o;
  }
}

// ---------------- pool: g = segment_sum(h, batch) ; batch is sorted ---------
__global__ __launch_bounds__(128)
void k_pool(const unsigned short* __restrict__ h, const int* __restrict__ batch,
            float* __restrict__ g) {
  int t = threadIdx.x;
  int n0 = blockIdx.x * 64;
  if (n0 >= N_NODES_C) return;
  int end = min(n0 + 64, N_NODES_C);
  int cur = batch[n0];
  float acc = 0.f;
  for (int n = n0; n < end; ++n) {
    int b = batch[n];
    if (b != cur) {
      atomicAdd(&g[cur * HID + t], acc);
      acc = 0.f;
      cur = b;
    }
    acc += bf2f(h[(size_t)n * HID + t]);
  }
  atomicAdd(&g[cur * HID + t], acc);
}

// ---------------- head: relu(g@w1+b1)@w2+b2 ----------------
__global__ __launch_bounds__(128)
void k_head(const float* __restrict__ g, const float* __restrict__ w1,
            const float* __restrict__ b1, const float* __restrict__ w2,
            const float* __restrict__ b2, float* __restrict__ out) {
  __shared__ float gs[HID];
  __shared__ float red[HID * 2];
  int gi = blockIdx.x, t = threadIdx.x;
  gs[t] = g[gi * HID + t];
  __syncthreads();
  float acc = b1[t];
#pragma unroll 8
  for (int k = 0; k < HID; ++k) acc += gs[k] * w1[k * HID + t];
  float hid = fmaxf(acc, 0.f);
  red[t * 2] = hid * w2[t * 2];
  red[t * 2 + 1] = hid * w2[t * 2 + 1];
  __syncthreads();
  for (int s = 64; s > 0; s >>= 1) {
    if (t < s) { red[t * 2] += red[(t + s) * 2]; red[t * 2 + 1] += red[(t + s) * 2 + 1]; }
    __syncthreads();
  }
  if (t == 0) {
    out[gi * 2] = red[0] + b2[0];
    out[gi * 2 + 1] = red[1] + b2[1];
  }
}

extern "C" void kernel_launch(void* const* d_in, const int* in_sizes, int n_in,
                              void* d_out, int out_size, void* d_ws, size_t ws_size,
                              hipStream_t stream) {
  const float* x      = (const float*)d_in[0];
  const int*   eidx   = (const int*)d_in[1];
  const float* eattr  = (const float*)d_in[2];
  const int*   batch  = (const int*)d_in[3];
  const float* node_w = (const float*)d_in[4];
  const float* node_b = (const float*)d_in[5];
  const float* edge_w = (const float*)d_in[6];
  const float* edge_b = (const float*)d_in[7];
  const float* mlp_w1 = (const float*)d_in[8];
  const float* mlp_b1 = (const float*)d_in[9];
  const float* mlp_w2 = (const float*)d_in[10];
  const float* mlp_b2 = (const float*)d_in[11];
  const float* bn_g   = (const float*)d_in[12];
  const float* bn_b   = (const float*)d_in[13];
  const float* hw1    = (const float*)d_in[14];
  const float* hb1    = (const float*)d_in[15];
  const float* hw2    = (const float*)d_in[16];
  const float* hb2    = (const float*)d_in[17];
  const int* srcArr = eidx;
  const int* dstArr = eidx + N_EDGES_C;

  char* wsp = (char*)d_ws;
  size_t off = 0;
  auto alloc = [&](size_t bytes) {
    void* p = wsp + off;
    off += (bytes + 255) & ~(size_t)255;
    return p;
  };
  unsigned short* h    = (unsigned short*)alloc((size_t)N_NODES_C * HID * 2);   // 12.8 MB
  unsigned short* zbf  = (unsigned short*)alloc((size_t)N_NODES_C * HID * 2);   // 12.8 MB
  unsigned short* t1bf = (unsigned short*)alloc((size_t)N_NODES_C * HID * 2);   // 12.8 MB
  float* t2f           = (float*)alloc((size_t)N_NODES_C * HID * 4);            // 25.6 MB
  unsigned* ea         = (unsigned*)alloc((size_t)N_EDGES_C * 64 * 4);          // 153.6 MB
  unsigned short* wT   = (unsigned short*)alloc((size_t)6 * HID * HID * 2);     // 192 KB
  int* row_ptr   = (int*)alloc((N_NODES_C + 1) * 4);
  int* cnt_cur   = (int*)alloc(N_NODES_C * 4);
  int* perm      = (int*)alloc((size_t)N_EDGES_C * 4);
  int* src_perm  = (int*)alloc((size_t)N_EDGES_C * 4);
  int* partial   = (int*)alloc(256 * 4);
  int* partial_off = (int*)alloc(256 * 4);
  float* gsum    = (float*)alloc(HID * 4);
  float* gsumsq  = (float*)alloc(HID * 4);
  float* scale   = (float*)alloc(HID * 4);
  float* shift   = (float*)alloc(HID * 4);
  float* g       = (float*)alloc((size_t)N_GRAPHS_C * HID * 4);

  hipMemsetAsync(cnt_cur, 0, N_NODES_C * 4, stream);
  hipMemsetAsync(g, 0, (size_t)N_GRAPHS_C * HID * 4, stream);

  k_node_encode<<<(N_NODES_C + 7) / 8, 128, 0, stream>>>(x, node_w, node_b, h);
  k_prep_w<<<6, 256, 0, stream>>>(mlp_w1, mlp_w2, wT);
  k_histogram<<<(N_EDGES_C + 255) / 256, 256, 0, stream>>>(dstArr, cnt_cur);
  k_blocksum<<<SCAN_NBLK, 256, 0, stream>>>(cnt_cur, partial);
  k_scanpartials<<<1, 256, 0, stream>>>(partial, partial_off);
  k_apply<<<SCAN_NBLK, 256, 0, stream>>>(cnt_cur, partial_off, row_ptr);
  k_bucket<<<(N_EDGES_C + 255) / 256, 256, 0, stream>>>(dstArr, srcArr, cnt_cur,
                                                        perm, src_perm);
  k_edge_encode<<<2048, 256, 0, stream>>>(perm, eattr, edge_w, edge_b, ea);

  const int GB = (N_NODES_C + 127) / 128;  // 391
  for (int l = 0; l < 3; ++l) {
    k_aggregate<<<(N_NODES_C + 3) / 4, 256, 0, stream>>>((const unsigned*)h, ea,
                                                         src_perm, row_ptr, zbf);
    k_gemm_mfma<true, true, false><<<GB, 256, 0, stream>>>(
        zbf, wT + (size_t)l * HID * HID, mlp_b1 + l * HID, t1bf, nullptr,
        nullptr, nullptr);
    hipMemsetAsync(gsum, 0, HID * 4, stream);
    hipMemsetAsync(gsumsq, 0, HID * 4, stream);
    k_gemm_mfma<false, false, true><<<GB, 256, 0, stream>>>(
        t1bf, wT + (size_t)(3 + l) * HID * HID, mlp_b2 + l * HID, nullptr, t2f,
        gsum, gsumsq);
    k_bn_finalize<<<1, HID, 0, stream>>>(gsum, gsumsq, bn_g + l * HID, bn_b + l * HID,
                                         scale, shift);
    k_bn_relu<<<(N_NODES_C * HID / 4 + 255) / 256, 256, 0, stream>>>(t2f, scale, shift, h);
  }
  k_pool<<<(N_NODES_C + 63) / 64, 128, 0, stream>>>(h, batch, g);
  k_head<<<N_GRAPHS_C, 128, 0, stream>>>(g, hw1, hb1, hw2, hb2, (float*)d_out);
}

// Round 6
// 635.190 us; speedup vs baseline: 1.9352x; 1.1249x over previous
//
#include <hip/hip_runtime.h>

#define N_NODES_C 50000
#define N_EDGES_C 600000
#define NODE_DIM_C 64
#define EDGE_DIM_C 16
#define HID 128
#define N_GRAPHS_C 256
#define BN_EPS_C 1e-5f
#define SCAN_NBLK ((N_NODES_C + 255) / 256)  // 196

typedef short bf16x8 __attribute__((ext_vector_type(8)));
typedef float f32x4 __attribute__((ext_vector_type(4)));

__device__ __forceinline__ unsigned short f2bf(float f) {
  union { float f; unsigned u; } v; v.f = f;
  unsigned r = (v.u + 0x7fffu + ((v.u >> 16) & 1u)) >> 16;
  return (unsigned short)r;
}

// packed pair of bf16 (lo = feat f0, hi = feat f0+1) -> two floats
__device__ __forceinline__ float2 bfp2f(unsigned u) {
  union { unsigned u; float f; } lo, hi;
  lo.u = u << 16;
  hi.u = u & 0xffff0000u;
  return make_float2(lo.f, hi.f);
}

__device__ __forceinline__ float bf2f(unsigned short s) {
  union { unsigned u; float f; } v;
  v.u = ((unsigned)s) << 16;
  return v.f;
}

// ------------ node encoder: h = bf16(x @ node_w + node_b) ------------
__global__ __launch_bounds__(128)
void k_node_encode(const float* __restrict__ x, const float* __restrict__ w,
                   const float* __restrict__ b, unsigned short* __restrict__ h) {
  __shared__ float ws[NODE_DIM_C * HID];   // 32 KB
  __shared__ float xs[8][NODE_DIM_C];
  int t = threadIdx.x;
  for (int i = t; i < NODE_DIM_C * HID; i += 128) ws[i] = w[i];
  int n0 = blockIdx.x * 8;
  for (int i = t; i < 8 * NODE_DIM_C; i += 128) {
    int r = i >> 6, c = i & 63;
    int n = n0 + r;
    xs[r][c] = (n < N_NODES_C) ? x[(size_t)n * NODE_DIM_C + c] : 0.f;
  }
  __syncthreads();
  float bias = b[t];
  for (int r = 0; r < 8; ++r) {
    int n = n0 + r;
    if (n >= N_NODES_C) return;
    float acc = bias;
#pragma unroll
    for (int k = 0; k < NODE_DIM_C; ++k) acc += xs[r][k] * ws[k * HID + t];
    h[(size_t)n * HID + t] = f2bf(acc);
  }
}

// ------- weight prep: wT[m][n*128+k] = bf16(W_m[k*128+n]), 6 matrices -------
__global__ __launch_bounds__(256)
void k_prep_w(const float* __restrict__ w1, const float* __restrict__ w2,
              unsigned short* __restrict__ wT) {
  int m = blockIdx.x;  // 0..5
  const float* src = (m < 3) ? (w1 + (size_t)m * HID * HID)
                             : (w2 + (size_t)(m - 3) * HID * HID);
  unsigned short* dst = wT + (size_t)m * HID * HID;
  for (int i = threadIdx.x; i < HID * HID; i += 256) {
    int n = i >> 7, k = i & 127;
    dst[n * HID + k] = f2bf(src[k * HID + n]);
  }
}

// ---------------- CSR build (counting sort by dst) ----------------
__global__ __launch_bounds__(256)
void k_histogram(const int* __restrict__ dst, int* __restrict__ counts) {
  int e = blockIdx.x * 256 + threadIdx.x;
  if (e < N_EDGES_C) atomicAdd(&counts[dst[e]], 1);
}

__global__ __launch_bounds__(256)
void k_blocksum(const int* __restrict__ cnt, int* __restrict__ partial) {
  __shared__ int ls[4];
  int t = threadIdx.x;
  int i = blockIdx.x * 256 + t;
  int v = (i < N_NODES_C) ? cnt[i] : 0;
#pragma unroll
  for (int o = 32; o > 0; o >>= 1) v += __shfl_down(v, o, 64);
  if ((t & 63) == 0) ls[t >> 6] = v;
  __syncthreads();
  if (t == 0) partial[blockIdx.x] = ls[0] + ls[1] + ls[2] + ls[3];
}

__global__ __launch_bounds__(256)
void k_scanpartials(const int* __restrict__ partial, int* __restrict__ partial_off) {
  __shared__ int s[256];
  int t = threadIdx.x;
  int v = (t < SCAN_NBLK) ? partial[t] : 0;
  s[t] = v;
  __syncthreads();
  for (int d = 1; d < 256; d <<= 1) {
    int x = (t >= d) ? s[t - d] : 0;
    __syncthreads();
    s[t] += x;
    __syncthreads();
  }
  if (t < SCAN_NBLK) partial_off[t] = s[t] - v;
}

__global__ __launch_bounds__(256)
void k_apply(int* __restrict__ cnt_cursor, const int* __restrict__ partial_off,
             int* __restrict__ row_ptr) {
  __shared__ int s[256];
  int t = threadIdx.x;
  int i = blockIdx.x * 256 + t;
  int v = (i < N_NODES_C) ? cnt_cursor[i] : 0;
  s[t] = v;
  __syncthreads();
  for (int d = 1; d < 256; d <<= 1) {
    int x = (t >= d) ? s[t - d] : 0;
    __syncthreads();
    s[t] += x;
    __syncthreads();
  }
  int excl = s[t] - v + partial_off[blockIdx.x];
  if (i < N_NODES_C) {
    row_ptr[i] = excl;
    cnt_cursor[i] = excl;
  }
  if (i == 0) row_ptr[N_NODES_C] = N_EDGES_C;
}

__global__ __launch_bounds__(256)
void k_bucket(const int* __restrict__ dst, const int* __restrict__ srcArr,
              int* __restrict__ cursor, int* __restrict__ perm,
              int* __restrict__ src_perm) {
  int e = blockIdx.x * 256 + threadIdx.x;
  if (e < N_EDGES_C) {
    int p = atomicAdd(&cursor[dst[e]], 1);
    perm[p] = e;
    src_perm[p] = srcArr[e];
  }
}

// ---- edge encoder via MFMA (layer-invariant, computed once):
// ea[i] = bf16(eattr[perm[i]] @ ew + eb) in CSR edge order.
// Block = 128 edges; parallel LDS gather; K padded 16->32; coalesced store.
#define EE_LDW 40  // padded row stride (shorts) for A/W tiles: breaks bank aliasing
__global__ __launch_bounds__(256)
void k_edge_encode(const int* __restrict__ perm, const float* __restrict__ eattr,
                   const float* __restrict__ ew, const float* __restrict__ ebias,
                   unsigned short* __restrict__ ea16) {
  __shared__ unsigned short smem[128 * 128];  // 32 KB; overlays: A, W, then OUT
  unsigned short* a_lds = smem;               // [128][EE_LDW]
  unsigned short* w_lds = smem + 128 * EE_LDW;
  int t = threadIdx.x;
  int EB = blockIdx.x * 128;

  // stage W: ew[k*128+n] -> w_lds[n*EE_LDW + k], zero k=16..31
  for (int i = t; i < 128 * 16; i += 256) {
    int n = i >> 4, k = i & 15;
    w_lds[n * EE_LDW + k] = f2bf(ew[k * HID + n]);
    w_lds[n * EE_LDW + 16 + k] = 0;
  }
  // stage A: 2 threads per edge, 8 floats each; zero k=16..31
  {
    int edge = t >> 1, half = t & 1;
    int gi = EB + edge;
    float4 v0 = make_float4(0, 0, 0, 0), v1 = v0;
    if (gi < N_EDGES_C) {
      int e = perm[gi];
      const float4* p = (const float4*)(eattr + (size_t)e * EDGE_DIM_C + half * 8);
      v0 = p[0];
      v1 = p[1];
    }
    unsigned short* ar = a_lds + edge * EE_LDW + half * 8;
    ar[0] = f2bf(v0.x); ar[1] = f2bf(v0.y); ar[2] = f2bf(v0.z); ar[3] = f2bf(v0.w);
    ar[4] = f2bf(v1.x); ar[5] = f2bf(v1.y); ar[6] = f2bf(v1.z); ar[7] = f2bf(v1.w);
    unsigned short* az = a_lds + edge * EE_LDW + 16 + half * 8;
    az[0] = 0; az[1] = 0; az[2] = 0; az[3] = 0;
    az[4] = 0; az[5] = 0; az[6] = 0; az[7] = 0;
  }
  __syncthreads();

  int lane = t & 63;
  int w = t >> 6;
  int l15 = lane & 15;
  int q = lane >> 4;

  f32x4 acc[2][8];
  {
    bf16x8 af[2];
#pragma unroll
    for (int rt = 0; rt < 2; ++rt) {
      int arow = w * 32 + rt * 16 + l15;
      af[rt] = *(const bf16x8*)&a_lds[arow * EE_LDW + q * 8];
    }
#pragma unroll
    for (int nt = 0; nt < 8; ++nt) {
      bf16x8 bf = *(const bf16x8*)&w_lds[(nt * 16 + l15) * EE_LDW + q * 8];
#pragma unroll
      for (int rt = 0; rt < 2; ++rt)
        acc[rt][nt] = __builtin_amdgcn_mfma_f32_16x16x32_bf16(
            af[rt], bf, (f32x4)0.f, 0, 0, 0);
    }
  }
  __syncthreads();  // done reading A/W; smem becomes the output tile [128][128]

#pragma unroll
  for (int nt = 0; nt < 8; ++nt) {
    int col = nt * 16 + l15;
    float bv = ebias[col];
#pragma unroll
    for (int rt = 0; rt < 2; ++rt) {
#pragma unroll
      for (int i = 0; i < 4; ++i) {
        int row = w * 32 + rt * 16 + q * 4 + i;
        smem[row * 128 + col] = f2bf(acc[rt][nt][i] + bv);
      }
    }
  }
  __syncthreads();

  int valid = min(128, N_EDGES_C - EB);
  const uint4* src = (const uint4*)smem;
  uint4* dst = (uint4*)(ea16 + (size_t)EB * 128);
  for (int i = t; i < valid * 16; i += 256) dst[i] = src[i];
}

// -------- aggregate: z[n] = h[n] + sum_{e: dst=n} relu(h[src_e] + ea_e) -----
// one wave per node, 2 feats/lane; h and ea both packed bf16; edges x8 unrolled
__global__ __launch_bounds__(256)
void k_aggregate(const unsigned* __restrict__ h32, const unsigned* __restrict__ ea,
                 const int* __restrict__ src_p, const int* __restrict__ row_ptr,
                 unsigned short* __restrict__ z) {
  int t = threadIdx.x;
  int lane = t & 63;
  int wave = t >> 6;
  int node = blockIdx.x * 4 + wave;
  if (node >= N_NODES_C) return;
  float2 base = bfp2f(h32[(size_t)node * 64 + lane]);
  float acc0 = base.x, acc1 = base.y;
  int beg = row_ptr[node], end = row_ptr[node + 1];
  int j = beg;
  for (; j + 8 <= end; j += 8) {
    int s0 = src_p[j],     s1 = src_p[j + 1], s2 = src_p[j + 2], s3 = src_p[j + 3];
    int s4 = src_p[j + 4], s5 = src_p[j + 5], s6 = src_p[j + 6], s7 = src_p[j + 7];
    unsigned g0 = h32[(size_t)s0 * 64 + lane];
    unsigned g1 = h32[(size_t)s1 * 64 + lane];
    unsigned g2 = h32[(size_t)s2 * 64 + lane];
    unsigned g3 = h32[(size_t)s3 * 64 + lane];
    unsigned g4 = h32[(size_t)s4 * 64 + lane];
    unsigned g5 = h32[(size_t)s5 * 64 + lane];
    unsigned g6 = h32[(size_t)s6 * 64 + lane];
    unsigned g7 = h32[(size_t)s7 * 64 + lane];
    unsigned u0 = ea[(size_t)j * 64 + lane];
    unsigned u1 = ea[(size_t)(j + 1) * 64 + lane];
    unsigned u2 = ea[(size_t)(j + 2) * 64 + lane];
    unsigned u3 = ea[(size_t)(j + 3) * 64 + lane];
    unsigned u4 = ea[(size_t)(j + 4) * 64 + lane];
    unsigned u5 = ea[(size_t)(j + 5) * 64 + lane];
    unsigned u6 = ea[(size_t)(j + 6) * 64 + lane];
    unsigned u7 = ea[(size_t)(j + 7) * 64 + lane];
    float2 a0 = bfp2f(g0), a1 = bfp2f(g1), a2 = bfp2f(g2), a3 = bfp2f(g3);
    float2 a4 = bfp2f(g4), a5 = bfp2f(g5), a6 = bfp2f(g6), a7 = bfp2f(g7);
    float2 e0 = bfp2f(u0), e1 = bfp2f(u1), e2 = bfp2f(u2), e3 = bfp2f(u3);
    float2 e4 = bfp2f(u4), e5 = bfp2f(u5), e6 = bfp2f(u6), e7 = bfp2f(u7);
    acc0 += fmaxf(a0.x + e0.x, 0.f) + fmaxf(a1.x + e1.x, 0.f) +
            fmaxf(a2.x + e2.x, 0.f) + fmaxf(a3.x + e3.x, 0.f) +
            fmaxf(a4.x + e4.x, 0.f) + fmaxf(a5.x + e5.x, 0.f) +
            fmaxf(a6.x + e6.x, 0.f) + fmaxf(a7.x + e7.x, 0.f);
    acc1 += fmaxf(a0.y + e0.y, 0.f) + fmaxf(a1.y + e1.y, 0.f) +
            fmaxf(a2.y + e2.y, 0.f) + fmaxf(a3.y + e3.y, 0.f) +
            fmaxf(a4.y + e4.y, 0.f) + fmaxf(a5.y + e5.y, 0.f) +
            fmaxf(a6.y + e6.y, 0.f) + fmaxf(a7.y + e7.y, 0.f);
  }
  for (; j + 4 <= end; j += 4) {
    int s0 = src_p[j], s1 = src_p[j + 1], s2 = src_p[j + 2], s3 = src_p[j + 3];
    unsigned g0 = h32[(size_t)s0 * 64 + lane];
    unsigned g1 = h32[(size_t)s1 * 64 + lane];
    unsigned g2 = h32[(size_t)s2 * 64 + lane];
    unsigned g3 = h32[(size_t)s3 * 64 + lane];
    unsigned u0 = ea[(size_t)j * 64 + lane];
    unsigned u1 = ea[(size_t)(j + 1) * 64 + lane];
    unsigned u2 = ea[(size_t)(j + 2) * 64 + lane];
    unsigned u3 = ea[(size_t)(j + 3) * 64 + lane];
    float2 a0 = bfp2f(g0), a1 = bfp2f(g1), a2 = bfp2f(g2), a3 = bfp2f(g3);
    float2 e0 = bfp2f(u0), e1 = bfp2f(u1), e2 = bfp2f(u2), e3 = bfp2f(u3);
    acc0 += fmaxf(a0.x + e0.x, 0.f) + fmaxf(a1.x + e1.x, 0.f) +
            fmaxf(a2.x + e2.x, 0.f) + fmaxf(a3.x + e3.x, 0.f);
    acc1 += fmaxf(a0.y + e0.y, 0.f) + fmaxf(a1.y + e1.y, 0.f) +
            fmaxf(a2.y + e2.y, 0.f) + fmaxf(a3.y + e3.y, 0.f);
  }
  for (; j < end; ++j) {
    int s0 = src_p[j];
    float2 a0 = bfp2f(h32[(size_t)s0 * 64 + lane]);
    float2 e0 = bfp2f(ea[(size_t)j * 64 + lane]);
    acc0 += fmaxf(a0.x + e0.x, 0.f);
    acc1 += fmaxf(a0.y + e0.y, 0.f);
  }
  unsigned packed = (unsigned)f2bf(acc0) | ((unsigned)f2bf(acc1) << 16);
  *(unsigned*)&z[(size_t)node * HID + lane * 2] = packed;
}

// ---------- MFMA GEMM: [50000,128](bf16) @ W^T[128,128](bf16) + bias --------
// STATS: fused BN column sums/sumsq via LDS reduce + atomics
template <bool RELU, bool BF16OUT, bool STATS>
__global__ __launch_bounds__(256)
void k_gemm_mfma(const unsigned short* __restrict__ in,
                 const unsigned short* __restrict__ wT,
                 const float* __restrict__ bias,
                 unsigned short* __restrict__ outb, float* __restrict__ outf,
                 float* __restrict__ gsum, float* __restrict__ gsumsq) {
  const int LDA = HID + 8;
  __shared__ unsigned short a_lds[128 * LDA];  // 34 KB (reused for stats reduce)
  __shared__ unsigned short w_lds[128 * LDA];
  int t = threadIdx.x;
  int row0 = blockIdx.x * 128;
  {
    int r = t >> 4, chunk = t & 15;
#pragma unroll
    for (int it = 0; it < 8; ++it) {
      int row = it * 16 + r;
      int grow = row0 + row;
      uint4 va = (grow < N_NODES_C)
                     ? ((const uint4*)(in + (size_t)grow * HID))[chunk]
                     : make_uint4(0, 0, 0, 0);
      *(uint4*)&a_lds[row * LDA + chunk * 8] = va;
      uint4 vw = ((const uint4*)(wT + (size_t)row * HID))[chunk];
      *(uint4*)&w_lds[row * LDA + chunk * 8] = vw;
    }
  }
  __syncthreads();

  int lane = t & 63;
  int w = t >> 6;
  int l15 = lane & 15;
  int q = lane >> 4;

  f32x4 acc[2][8];
#pragma unroll
  for (int rt = 0; rt < 2; ++rt)
#pragma unroll
    for (int nt = 0; nt < 8; ++nt) acc[rt][nt] = (f32x4)0.f;

#pragma unroll
  for (int kk = 0; kk < 4; ++kk) {
    int k0 = kk * 32;
    bf16x8 af[2];
#pragma unroll
    for (int rt = 0; rt < 2; ++rt) {
      int arow = w * 32 + rt * 16 + l15;
      af[rt] = *(const bf16x8*)&a_lds[arow * LDA + k0 + q * 8];
    }
#pragma unroll
    for (int nt = 0; nt < 8; ++nt) {
      int brow = nt * 16 + l15;
      bf16x8 bf = *(const bf16x8*)&w_lds[brow * LDA + k0 + q * 8];
#pragma unroll
      for (int rt = 0; rt < 2; ++rt)
        acc[rt][nt] = __builtin_amdgcn_mfma_f32_16x16x32_bf16(af[rt], bf, acc[rt][nt], 0, 0, 0);
    }
  }

  float sp[8], qp[8];
#pragma unroll
  for (int nt = 0; nt < 8; ++nt) { sp[nt] = 0.f; qp[nt] = 0.f; }

#pragma unroll
  for (int nt = 0; nt < 8; ++nt) {
    int gcol = nt * 16 + l15;
    float bv = bias[gcol];
#pragma unroll
    for (int rt = 0; rt < 2; ++rt) {
#pragma unroll
      for (int i = 0; i < 4; ++i) {
        int grow = row0 + w * 32 + rt * 16 + q * 4 + i;
        bool ok = (grow < N_NODES_C);
        float v = acc[rt][nt][i] + bv;
        if (RELU) v = fmaxf(v, 0.f);
        if (ok) {
          if (BF16OUT)
            outb[(size_t)grow * HID + gcol] = f2bf(v);
          else
            outf[(size_t)grow * HID + gcol] = v;
        }
        if (STATS) {
          float c = ok ? v : 0.f;
          sp[nt] += c;
          qp[nt] += c * c;
        }
      }
    }
  }

  if (STATS) {
    __syncthreads();
    float* sred = (float*)a_lds;        // [128][16]
    float* qred = sred + 128 * 16;
    int slot = w * 4 + q;
#pragma unroll
    for (int nt = 0; nt < 8; ++nt) {
      int gcol = nt * 16 + l15;
      sred[gcol * 16 + slot] = sp[nt];
      qred[gcol * 16 + slot] = qp[nt];
    }
    __syncthreads();
    if (t < 128) {
      float s = 0.f;
#pragma unroll
      for (int i = 0; i < 16; ++i) s += sred[t * 16 + i];
      atomicAdd(&gsum[t], s);
    } else {
      int f = t - 128;
      float s = 0.f;
#pragma unroll
      for (int i = 0; i < 16; ++i) s += qred[f * 16 + i];
      atomicAdd(&gsumsq[f], s);
    }
  }
}

__global__ void k_bn_finalize(const float* __restrict__ gsum, const float* __restrict__ gsumsq,
                              const float* __restrict__ gamma, const float* __restrict__ beta,
                              float* __restrict__ scale, float* __restrict__ shift) {
  int f = threadIdx.x;  // 128
  float mean = gsum[f] * (1.f / N_NODES_C);
  float var = gsumsq[f] * (1.f / N_NODES_C) - mean * mean;
  float inv = rsqrtf(var + BN_EPS_C);
  float sc = gamma[f] * inv;
  scale[f] = sc;
  shift[f] = beta[f] - mean * sc;
}

// BN + relu: reads t2 fp32, writes h bf16 packed
__global__ __launch_bounds__(256)
void k_bn_relu(const float* __restrict__ t2, const float* __restrict__ scale,
               const float* __restrict__ shift, unsigned short* __restrict__ h) {
  __shared__ float sc[HID], sh[HID];
  int t = threadIdx.x;
  if (t < HID) { sc[t] = scale[t]; sh[t] = shift[t]; }
  __syncthreads();
  size_t idx = ((size_t)blockIdx.x * 256 + t) * 4;
  if (idx < (size_t)N_NODES_C * HID) {
    float4 v = *(const float4*)&t2[idx];
    int f = (int)(idx & 127);
    float r0 = fmaxf(v.x * sc[f] + sh[f], 0.f);
    float r1 = fmaxf(v.y * sc[f + 1] + sh[f + 1], 0.f);
    float r2 = fmaxf(v.z * sc[f + 2] + sh[f + 2], 0.f);
    float r3 = fmaxf(v.w * sc[f + 3] + sh[f + 3], 0.f);
    uint2 o;
    o.x = (unsigned)f2bf(r0) | ((unsigned)f2bf(r1) << 16);
    o.y = (unsigned)f2bf(r2) | ((unsigned)f2bf(r3) << 16);
    *(uint2*)&h[idx] = o;
  }
}

// ---------------- pool: g = segment_sum(h, batch) ; batch is sorted ---------
__global__ __launch_bounds__(128)
void k_pool(const unsigned short* __restrict__ h, const int* __restrict__ batch,
            float* __restrict__ g) {
  int t = threadIdx.x;
  int n0 = blockIdx.x * 64;
  if (n0 >= N_NODES_C) return;
  int end = min(n0 + 64, N_NODES_C);
  int cur = batch[n0];
  float acc = 0.f;
  for (int n = n0; n < end; ++n) {
    int b = batch[n];
    if (b != cur) {
      atomicAdd(&g[cur * HID + t], acc);
      acc = 0.f;
      cur = b;
    }
    acc += bf2f(h[(size_t)n * HID + t]);
  }
  atomicAdd(&g[cur * HID + t], acc);
}

// ---------------- head: relu(g@w1+b1)@w2+b2 ----------------
__global__ __launch_bounds__(128)
void k_head(const float* __restrict__ g, const float* __restrict__ w1,
            const float* __restrict__ b1, const float* __restrict__ w2,
            const float* __restrict__ b2, float* __restrict__ out) {
  __shared__ float gs[HID];
  __shared__ float red[HID * 2];
  int gi = blockIdx.x, t = threadIdx.x;
  gs[t] = g[gi * HID + t];
  __syncthreads();
  float acc = b1[t];
#pragma unroll 8
  for (int k = 0; k < HID; ++k) acc += gs[k] * w1[k * HID + t];
  float hid = fmaxf(acc, 0.f);
  red[t * 2] = hid * w2[t * 2];
  red[t * 2 + 1] = hid * w2[t * 2 + 1];
  __syncthreads();
  for (int s = 64; s > 0; s >>= 1) {
    if (t < s) { red[t * 2] += red[(t + s) * 2]; red[t * 2 + 1] += red[(t + s) * 2 + 1]; }
    __syncthreads();
  }
  if (t == 0) {
    out[gi * 2] = red[0] + b2[0];
    out[gi * 2 + 1] = red[1] + b2[1];
  }
}

extern "C" void kernel_launch(void* const* d_in, const int* in_sizes, int n_in,
                              void* d_out, int out_size, void* d_ws, size_t ws_size,
                              hipStream_t stream) {
  const float* x      = (const float*)d_in[0];
  const int*   eidx   = (const int*)d_in[1];
  const float* eattr  = (const float*)d_in[2];
  const int*   batch  = (const int*)d_in[3];
  const float* node_w = (const float*)d_in[4];
  const float* node_b = (const float*)d_in[5];
  const float* edge_w = (const float*)d_in[6];
  const float* edge_b = (const float*)d_in[7];
  const float* mlp_w1 = (const float*)d_in[8];
  const float* mlp_b1 = (const float*)d_in[9];
  const float* mlp_w2 = (const float*)d_in[10];
  const float* mlp_b2 = (const float*)d_in[11];
  const float* bn_g   = (const float*)d_in[12];
  const float* bn_b   = (const float*)d_in[13];
  const float* hw1    = (const float*)d_in[14];
  const float* hb1    = (const float*)d_in[15];
  const float* hw2    = (const float*)d_in[16];
  const float* hb2    = (const float*)d_in[17];
  const int* srcArr = eidx;
  const int* dstArr = eidx + N_EDGES_C;

  char* wsp = (char*)d_ws;
  size_t off = 0;
  auto alloc = [&](size_t bytes) {
    void* p = wsp + off;
    off += (bytes + 255) & ~(size_t)255;
    return p;
  };
  unsigned short* h    = (unsigned short*)alloc((size_t)N_NODES_C * HID * 2);   // 12.8 MB
  unsigned short* zbf  = (unsigned short*)alloc((size_t)N_NODES_C * HID * 2);   // 12.8 MB
  unsigned short* t1bf = (unsigned short*)alloc((size_t)N_NODES_C * HID * 2);   // 12.8 MB
  float* t2f           = (float*)alloc((size_t)N_NODES_C * HID * 4);            // 25.6 MB
  unsigned short* ea16 = (unsigned short*)alloc((size_t)N_EDGES_C * HID * 2);   // 153.6 MB
  unsigned short* wT   = (unsigned short*)alloc((size_t)6 * HID * HID * 2);     // 192 KB
  int* row_ptr   = (int*)alloc((N_NODES_C + 1) * 4);
  int* cnt_cur   = (int*)alloc(N_NODES_C * 4);
  int* perm      = (int*)alloc((size_t)N_EDGES_C * 4);
  int* src_perm  = (int*)alloc((size_t)N_EDGES_C * 4);
  int* partial   = (int*)alloc(256 * 4);
  int* partial_off = (int*)alloc(256 * 4);
  float* gsum    = (float*)alloc(HID * 4);
  float* gsumsq  = (float*)alloc(HID * 4);
  float* scale   = (float*)alloc(HID * 4);
  float* shift   = (float*)alloc(HID * 4);
  float* g       = (float*)alloc((size_t)N_GRAPHS_C * HID * 4);

  hipMemsetAsync(cnt_cur, 0, N_NODES_C * 4, stream);
  hipMemsetAsync(g, 0, (size_t)N_GRAPHS_C * HID * 4, stream);

  k_node_encode<<<(N_NODES_C + 7) / 8, 128, 0, stream>>>(x, node_w, node_b, h);
  k_prep_w<<<6, 256, 0, stream>>>(mlp_w1, mlp_w2, wT);
  k_histogram<<<(N_EDGES_C + 255) / 256, 256, 0, stream>>>(dstArr, cnt_cur);
  k_blocksum<<<SCAN_NBLK, 256, 0, stream>>>(cnt_cur, partial);
  k_scanpartials<<<1, 256, 0, stream>>>(partial, partial_off);
  k_apply<<<SCAN_NBLK, 256, 0, stream>>>(cnt_cur, partial_off, row_ptr);
  k_bucket<<<(N_EDGES_C + 255) / 256, 256, 0, stream>>>(dstArr, srcArr, cnt_cur,
                                                        perm, src_perm);
  k_edge_encode<<<(N_EDGES_C + 127) / 128, 256, 0, stream>>>(perm, eattr, edge_w,
                                                             edge_b, ea16);

  const int GB = (N_NODES_C + 127) / 128;  // 391
  for (int l = 0; l < 3; ++l) {
    k_aggregate<<<(N_NODES_C + 3) / 4, 256, 0, stream>>>((const unsigned*)h,
                                                         (const unsigned*)ea16,
                                                         src_perm, row_ptr, zbf);
    k_gemm_mfma<true, true, false><<<GB, 256, 0, stream>>>(
        zbf, wT + (size_t)l * HID * HID, mlp_b1 + l * HID, t1bf, nullptr,
        nullptr, nullptr);
    hipMemsetAsync(gsum, 0, HID * 4, stream);
    hipMemsetAsync(gsumsq, 0, HID * 4, stream);
    k_gemm_mfma<false, false, true><<<GB, 256, 0, stream>>>(
        t1bf, wT + (size_t)(3 + l) * HID * HID, mlp_b2 + l * HID, nullptr, t2f,
        gsum, gsumsq);
    k_bn_finalize<<<1, HID, 0, stream>>>(gsum, gsumsq, bn_g + l * HID, bn_b + l * HID,
                                         scale, shift);
    k_bn_relu<<<(N_NODES_C * HID / 4 + 255) / 256, 256, 0, stream>>>(t2f, scale, shift, h);
  }
  k_pool<<<(N_NODES_C + 63) / 64, 128, 0, stream>>>(h, batch, g);
  k_head<<<N_GRAPHS_C, 128, 0, stream>>>(g, hw1, hb1, hw2, hb2, (float*)d_out);
}

// Round 7
// 585.879 us; speedup vs baseline: 2.0980x; 1.0842x over previous
//
#include <hip/hip_runtime.h>

#define N_NODES_C 50000
#define N_EDGES_C 600000
#define NODE_DIM_C 64
#define EDGE_DIM_C 16
#define HID 128
#define N_GRAPHS_C 256
#define BN_EPS_C 1e-5f
#define SCAN_NBLK ((N_NODES_C + 255) / 256)  // 196

typedef short bf16x8 __attribute__((ext_vector_type(8)));
typedef float f32x4 __attribute__((ext_vector_type(4)));

__device__ __forceinline__ unsigned short f2bf(float f) {
  union { float f; unsigned u; } v; v.f = f;
  unsigned r = (v.u + 0x7fffu + ((v.u >> 16) & 1u)) >> 16;
  return (unsigned short)r;
}

__device__ __forceinline__ float2 bfp2f(unsigned u) {
  union { unsigned u; float f; } lo, hi;
  lo.u = u << 16;
  hi.u = u & 0xffff0000u;
  return make_float2(lo.f, hi.f);
}

// ---------------- x -> bf16 conversion ----------------
__global__ __launch_bounds__(256)
void k_x2bf(const float* __restrict__ x, unsigned short* __restrict__ xb) {
  size_t i = ((size_t)blockIdx.x * 256 + threadIdx.x) * 4;
  if (i < (size_t)N_NODES_C * NODE_DIM_C) {
    float4 v = *(const float4*)&x[i];
    uint2 o;
    o.x = (unsigned)f2bf(v.x) | ((unsigned)f2bf(v.y) << 16);
    o.y = (unsigned)f2bf(v.z) | ((unsigned)f2bf(v.w) << 16);
    *(uint2*)&xb[i] = o;
  }
}

// ------- weight prep: 6 MLP mats -> wT[m][n*128+k]; node_w -> nwT[n*64+k] ---
__global__ __launch_bounds__(256)
void k_prep_w(const float* __restrict__ w1, const float* __restrict__ w2,
              const float* __restrict__ nodew, unsigned short* __restrict__ wT) {
  int m = blockIdx.x;  // 0..6
  if (m < 6) {
    const float* src = (m < 3) ? (w1 + (size_t)m * HID * HID)
                               : (w2 + (size_t)(m - 3) * HID * HID);
    unsigned short* dst = wT + (size_t)m * HID * HID;
    for (int i = threadIdx.x; i < HID * HID; i += 256) {
      int n = i >> 7, k = i & 127;
      dst[n * HID + k] = f2bf(src[k * HID + n]);
    }
  } else {
    unsigned short* dst = wT + (size_t)6 * HID * HID;  // [128][64]
    for (int i = threadIdx.x; i < HID * NODE_DIM_C; i += 256) {
      int n = i >> 6, k = i & 63;
      dst[n * NODE_DIM_C + k] = f2bf(nodew[k * HID + n]);
    }
  }
}

// ------- node encoder via MFMA: h = bf16(x_bf @ node_w + node_b), K=64 ------
__global__ __launch_bounds__(256)
void k_node_mfma(const unsigned short* __restrict__ xb,
                 const unsigned short* __restrict__ nwT,
                 const float* __restrict__ bias, unsigned short* __restrict__ h) {
  const int LD = NODE_DIM_C + 8;  // 72
  __shared__ unsigned short a_lds[128 * LD];  // 18 KB
  __shared__ unsigned short w_lds[128 * LD];  // 18 KB
  int t = threadIdx.x;
  int row0 = blockIdx.x * 128;
  {
    int r = t >> 3, c = t & 7;  // 32 rows/iter, 8 chunks of 8 shorts
#pragma unroll
    for (int it = 0; it < 4; ++it) {
      int row = it * 32 + r;
      int grow = row0 + row;
      uint4 va = (grow < N_NODES_C)
                     ? ((const uint4*)(xb + (size_t)grow * NODE_DIM_C))[c]
                     : make_uint4(0, 0, 0, 0);
      *(uint4*)&a_lds[row * LD + c * 8] = va;
      uint4 vw = ((const uint4*)(nwT + (size_t)row * NODE_DIM_C))[c];
      *(uint4*)&w_lds[row * LD + c * 8] = vw;
    }
  }
  __syncthreads();

  int lane = t & 63;
  int w = t >> 6;
  int l15 = lane & 15;
  int q = lane >> 4;

  f32x4 acc[2][8];
#pragma unroll
  for (int rt = 0; rt < 2; ++rt)
#pragma unroll
    for (int nt = 0; nt < 8; ++nt) acc[rt][nt] = (f32x4)0.f;

#pragma unroll
  for (int kk = 0; kk < 2; ++kk) {
    int k0 = kk * 32;
    bf16x8 af[2];
#pragma unroll
    for (int rt = 0; rt < 2; ++rt) {
      int arow = w * 32 + rt * 16 + l15;
      af[rt] = *(const bf16x8*)&a_lds[arow * LD + k0 + q * 8];
    }
#pragma unroll
    for (int nt = 0; nt < 8; ++nt) {
      bf16x8 bf = *(const bf16x8*)&w_lds[(nt * 16 + l15) * LD + k0 + q * 8];
#pragma unroll
      for (int rt = 0; rt < 2; ++rt)
        acc[rt][nt] = __builtin_amdgcn_mfma_f32_16x16x32_bf16(af[rt], bf, acc[rt][nt], 0, 0, 0);
    }
  }

#pragma unroll
  for (int nt = 0; nt < 8; ++nt) {
    int gcol = nt * 16 + l15;
    float bv = bias[gcol];
#pragma unroll
    for (int rt = 0; rt < 2; ++rt) {
#pragma unroll
      for (int i = 0; i < 4; ++i) {
        int grow = row0 + w * 32 + rt * 16 + q * 4 + i;
        if (grow < N_NODES_C) h[(size_t)grow * HID + gcol] = f2bf(acc[rt][nt][i] + bv);
      }
    }
  }
}

// ---------------- CSR build (counting sort by dst) ----------------
__global__ __launch_bounds__(256)
void k_histogram(const int* __restrict__ dst, int* __restrict__ counts) {
  int e = blockIdx.x * 256 + threadIdx.x;
  if (e < N_EDGES_C) atomicAdd(&counts[dst[e]], 1);
}

__global__ __launch_bounds__(256)
void k_blocksum(const int* __restrict__ cnt, int* __restrict__ partial) {
  __shared__ int ls[4];
  int t = threadIdx.x;
  int i = blockIdx.x * 256 + t;
  int v = (i < N_NODES_C) ? cnt[i] : 0;
#pragma unroll
  for (int o = 32; o > 0; o >>= 1) v += __shfl_down(v, o, 64);
  if ((t & 63) == 0) ls[t >> 6] = v;
  __syncthreads();
  if (t == 0) partial[blockIdx.x] = ls[0] + ls[1] + ls[2] + ls[3];
}

__global__ __launch_bounds__(256)
void k_scanpartials(const int* __restrict__ partial, int* __restrict__ partial_off) {
  __shared__ int s[256];
  int t = threadIdx.x;
  int v = (t < SCAN_NBLK) ? partial[t] : 0;
  s[t] = v;
  __syncthreads();
  for (int d = 1; d < 256; d <<= 1) {
    int x = (t >= d) ? s[t - d] : 0;
    __syncthreads();
    s[t] += x;
    __syncthreads();
  }
  if (t < SCAN_NBLK) partial_off[t] = s[t] - v;
}

__global__ __launch_bounds__(256)
void k_apply(int* __restrict__ cnt_cursor, const int* __restrict__ partial_off,
             int* __restrict__ row_ptr) {
  __shared__ int s[256];
  int t = threadIdx.x;
  int i = blockIdx.x * 256 + t;
  int v = (i < N_NODES_C) ? cnt_cursor[i] : 0;
  s[t] = v;
  __syncthreads();
  for (int d = 1; d < 256; d <<= 1) {
    int x = (t >= d) ? s[t - d] : 0;
    __syncthreads();
    s[t] += x;
    __syncthreads();
  }
  int excl = s[t] - v + partial_off[blockIdx.x];
  if (i < N_NODES_C) {
    row_ptr[i] = excl;
    cnt_cursor[i] = excl;
  }
  if (i == 0) row_ptr[N_NODES_C] = N_EDGES_C;
}

__global__ __launch_bounds__(256)
void k_bucket(const int* __restrict__ dst, const int* __restrict__ srcArr,
              int* __restrict__ cursor, int* __restrict__ perm,
              int* __restrict__ src_perm) {
  int e = blockIdx.x * 256 + threadIdx.x;
  if (e < N_EDGES_C) {
    int p = atomicAdd(&cursor[dst[e]], 1);
    perm[p] = e;
    src_perm[p] = srcArr[e];
  }
}

// ---- edge encoder via MFMA (layer-invariant, computed once):
// ea[i] = bf16(eattr[perm[i]] @ ew + eb) in CSR edge order.
#define EE_LDW 40
__global__ __launch_bounds__(256)
void k_edge_encode(const int* __restrict__ perm, const float* __restrict__ eattr,
                   const float* __restrict__ ew, const float* __restrict__ ebias,
                   unsigned short* __restrict__ ea16) {
  __shared__ unsigned short smem[128 * 128];  // 32 KB; overlays: A, W, then OUT
  unsigned short* a_lds = smem;               // [128][EE_LDW]
  unsigned short* w_lds = smem + 128 * EE_LDW;
  int t = threadIdx.x;
  int EB = blockIdx.x * 128;

  for (int i = t; i < 128 * 16; i += 256) {
    int n = i >> 4, k = i & 15;
    w_lds[n * EE_LDW + k] = f2bf(ew[k * HID + n]);
    w_lds[n * EE_LDW + 16 + k] = 0;
  }
  {
    int edge = t >> 1, half = t & 1;
    int gi = EB + edge;
    float4 v0 = make_float4(0, 0, 0, 0), v1 = v0;
    if (gi < N_EDGES_C) {
      int e = perm[gi];
      const float4* p = (const float4*)(eattr + (size_t)e * EDGE_DIM_C + half * 8);
      v0 = p[0];
      v1 = p[1];
    }
    unsigned short* ar = a_lds + edge * EE_LDW + half * 8;
    ar[0] = f2bf(v0.x); ar[1] = f2bf(v0.y); ar[2] = f2bf(v0.z); ar[3] = f2bf(v0.w);
    ar[4] = f2bf(v1.x); ar[5] = f2bf(v1.y); ar[6] = f2bf(v1.z); ar[7] = f2bf(v1.w);
    unsigned short* az = a_lds + edge * EE_LDW + 16 + half * 8;
    az[0] = 0; az[1] = 0; az[2] = 0; az[3] = 0;
    az[4] = 0; az[5] = 0; az[6] = 0; az[7] = 0;
  }
  __syncthreads();

  int lane = t & 63;
  int w = t >> 6;
  int l15 = lane & 15;
  int q = lane >> 4;

  f32x4 acc[2][8];
  {
    bf16x8 af[2];
#pragma unroll
    for (int rt = 0; rt < 2; ++rt) {
      int arow = w * 32 + rt * 16 + l15;
      af[rt] = *(const bf16x8*)&a_lds[arow * EE_LDW + q * 8];
    }
#pragma unroll
    for (int nt = 0; nt < 8; ++nt) {
      bf16x8 bf = *(const bf16x8*)&w_lds[(nt * 16 + l15) * EE_LDW + q * 8];
#pragma unroll
      for (int rt = 0; rt < 2; ++rt)
        acc[rt][nt] = __builtin_amdgcn_mfma_f32_16x16x32_bf16(
            af[rt], bf, (f32x4)0.f, 0, 0, 0);
    }
  }
  __syncthreads();

#pragma unroll
  for (int nt = 0; nt < 8; ++nt) {
    int col = nt * 16 + l15;
    float bv = ebias[col];
#pragma unroll
    for (int rt = 0; rt < 2; ++rt) {
#pragma unroll
      for (int i = 0; i < 4; ++i) {
        int row = w * 32 + rt * 16 + q * 4 + i;
        smem[row * 128 + col] = f2bf(acc[rt][nt][i] + bv);
      }
    }
  }
  __syncthreads();

  int valid = min(128, N_EDGES_C - EB);
  const uint4* src = (const uint4*)smem;
  uint4* dst = (uint4*)(ea16 + (size_t)EB * 128);
  for (int i = t; i < valid * 16; i += 256) dst[i] = src[i];
}

// -------- aggregate: z[n] = h[n] + sum_{e: dst=n} relu(h[src_e] + ea_e) -----
__global__ __launch_bounds__(256)
void k_aggregate(const unsigned* __restrict__ h32, const unsigned* __restrict__ ea,
                 const int* __restrict__ src_p, const int* __restrict__ row_ptr,
                 unsigned short* __restrict__ z) {
  int t = threadIdx.x;
  int lane = t & 63;
  int wave = t >> 6;
  int node = blockIdx.x * 4 + wave;
  if (node >= N_NODES_C) return;
  float2 base = bfp2f(h32[(size_t)node * 64 + lane]);
  float acc0 = base.x, acc1 = base.y;
  int beg = row_ptr[node], end = row_ptr[node + 1];
  int j = beg;
  for (; j + 8 <= end; j += 8) {
    int s0 = src_p[j],     s1 = src_p[j + 1], s2 = src_p[j + 2], s3 = src_p[j + 3];
    int s4 = src_p[j + 4], s5 = src_p[j + 5], s6 = src_p[j + 6], s7 = src_p[j + 7];
    unsigned g0 = h32[(size_t)s0 * 64 + lane];
    unsigned g1 = h32[(size_t)s1 * 64 + lane];
    unsigned g2 = h32[(size_t)s2 * 64 + lane];
    unsigned g3 = h32[(size_t)s3 * 64 + lane];
    unsigned g4 = h32[(size_t)s4 * 64 + lane];
    unsigned g5 = h32[(size_t)s5 * 64 + lane];
    unsigned g6 = h32[(size_t)s6 * 64 + lane];
    unsigned g7 = h32[(size_t)s7 * 64 + lane];
    unsigned u0 = ea[(size_t)j * 64 + lane];
    unsigned u1 = ea[(size_t)(j + 1) * 64 + lane];
    unsigned u2 = ea[(size_t)(j + 2) * 64 + lane];
    unsigned u3 = ea[(size_t)(j + 3) * 64 + lane];
    unsigned u4 = ea[(size_t)(j + 4) * 64 + lane];
    unsigned u5 = ea[(size_t)(j + 5) * 64 + lane];
    unsigned u6 = ea[(size_t)(j + 6) * 64 + lane];
    unsigned u7 = ea[(size_t)(j + 7) * 64 + lane];
    float2 a0 = bfp2f(g0), a1 = bfp2f(g1), a2 = bfp2f(g2), a3 = bfp2f(g3);
    float2 a4 = bfp2f(g4), a5 = bfp2f(g5), a6 = bfp2f(g6), a7 = bfp2f(g7);
    float2 e0 = bfp2f(u0), e1 = bfp2f(u1), e2 = bfp2f(u2), e3 = bfp2f(u3);
    float2 e4 = bfp2f(u4), e5 = bfp2f(u5), e6 = bfp2f(u6), e7 = bfp2f(u7);
    acc0 += fmaxf(a0.x + e0.x, 0.f) + fmaxf(a1.x + e1.x, 0.f) +
            fmaxf(a2.x + e2.x, 0.f) + fmaxf(a3.x + e3.x, 0.f) +
            fmaxf(a4.x + e4.x, 0.f) + fmaxf(a5.x + e5.x, 0.f) +
            fmaxf(a6.x + e6.x, 0.f) + fmaxf(a7.x + e7.x, 0.f);
    acc1 += fmaxf(a0.y + e0.y, 0.f) + fmaxf(a1.y + e1.y, 0.f) +
            fmaxf(a2.y + e2.y, 0.f) + fmaxf(a3.y + e3.y, 0.f) +
            fmaxf(a4.y + e4.y, 0.f) + fmaxf(a5.y + e5.y, 0.f) +
            fmaxf(a6.y + e6.y, 0.f) + fmaxf(a7.y + e7.y, 0.f);
  }
  for (; j + 4 <= end; j += 4) {
    int s0 = src_p[j], s1 = src_p[j + 1], s2 = src_p[j + 2], s3 = src_p[j + 3];
    unsigned g0 = h32[(size_t)s0 * 64 + lane];
    unsigned g1 = h32[(size_t)s1 * 64 + lane];
    unsigned g2 = h32[(size_t)s2 * 64 + lane];
    unsigned g3 = h32[(size_t)s3 * 64 + lane];
    unsigned u0 = ea[(size_t)j * 64 + lane];
    unsigned u1 = ea[(size_t)(j + 1) * 64 + lane];
    unsigned u2 = ea[(size_t)(j + 2) * 64 + lane];
    unsigned u3 = ea[(size_t)(j + 3) * 64 + lane];
    float2 a0 = bfp2f(g0), a1 = bfp2f(g1), a2 = bfp2f(g2), a3 = bfp2f(g3);
    float2 e0 = bfp2f(u0), e1 = bfp2f(u1), e2 = bfp2f(u2), e3 = bfp2f(u3);
    acc0 += fmaxf(a0.x + e0.x, 0.f) + fmaxf(a1.x + e1.x, 0.f) +
            fmaxf(a2.x + e2.x, 0.f) + fmaxf(a3.x + e3.x, 0.f);
    acc1 += fmaxf(a0.y + e0.y, 0.f) + fmaxf(a1.y + e1.y, 0.f) +
            fmaxf(a2.y + e2.y, 0.f) + fmaxf(a3.y + e3.y, 0.f);
  }
  for (; j < end; ++j) {
    int s0 = src_p[j];
    float2 a0 = bfp2f(h32[(size_t)s0 * 64 + lane]);
    float2 e0 = bfp2f(ea[(size_t)j * 64 + lane]);
    acc0 += fmaxf(a0.x + e0.x, 0.f);
    acc1 += fmaxf(a0.y + e0.y, 0.f);
  }
  unsigned packed = (unsigned)f2bf(acc0) | ((unsigned)f2bf(acc1) << 16);
  *(unsigned*)&z[(size_t)node * HID + lane * 2] = packed;
}

// ---------- MFMA GEMM: [50000,128](bf16) @ W^T[128,128](bf16) + bias --------
template <bool RELU, bool BF16OUT, bool STATS>
__global__ __launch_bounds__(256)
void k_gemm_mfma(const unsigned short* __restrict__ in,
                 const unsigned short* __restrict__ wT,
                 const float* __restrict__ bias,
                 unsigned short* __restrict__ outb, float* __restrict__ outf,
                 float* __restrict__ gsum, float* __restrict__ gsumsq) {
  const int LDA = HID + 8;
  __shared__ unsigned short a_lds[128 * LDA];
  __shared__ unsigned short w_lds[128 * LDA];
  int t = threadIdx.x;
  int row0 = blockIdx.x * 128;
  {
    int r = t >> 4, chunk = t & 15;
#pragma unroll
    for (int it = 0; it < 8; ++it) {
      int row = it * 16 + r;
      int grow = row0 + row;
      uint4 va = (grow < N_NODES_C)
                     ? ((const uint4*)(in + (size_t)grow * HID))[chunk]
                     : make_uint4(0, 0, 0, 0);
      *(uint4*)&a_lds[row * LDA + chunk * 8] = va;
      uint4 vw = ((const uint4*)(wT + (size_t)row * HID))[chunk];
      *(uint4*)&w_lds[row * LDA + chunk * 8] = vw;
    }
  }
  __syncthreads();

  int lane = t & 63;
  int w = t >> 6;
  int l15 = lane & 15;
  int q = lane >> 4;

  f32x4 acc[2][8];
#pragma unroll
  for (int rt = 0; rt < 2; ++rt)
#pragma unroll
    for (int nt = 0; nt < 8; ++nt) acc[rt][nt] = (f32x4)0.f;

#pragma unroll
  for (int kk = 0; kk < 4; ++kk) {
    int k0 = kk * 32;
    bf16x8 af[2];
#pragma unroll
    for (int rt = 0; rt < 2; ++rt) {
      int arow = w * 32 + rt * 16 + l15;
      af[rt] = *(const bf16x8*)&a_lds[arow * LDA + k0 + q * 8];
    }
#pragma unroll
    for (int nt = 0; nt < 8; ++nt) {
      int brow = nt * 16 + l15;
      bf16x8 bf = *(const bf16x8*)&w_lds[brow * LDA + k0 + q * 8];
#pragma unroll
      for (int rt = 0; rt < 2; ++rt)
        acc[rt][nt] = __builtin_amdgcn_mfma_f32_16x16x32_bf16(af[rt], bf, acc[rt][nt], 0, 0, 0);
    }
  }

  float sp[8], qp[8];
#pragma unroll
  for (int nt = 0; nt < 8; ++nt) { sp[nt] = 0.f; qp[nt] = 0.f; }

#pragma unroll
  for (int nt = 0; nt < 8; ++nt) {
    int gcol = nt * 16 + l15;
    float bv = bias[gcol];
#pragma unroll
    for (int rt = 0; rt < 2; ++rt) {
#pragma unroll
      for (int i = 0; i < 4; ++i) {
        int grow = row0 + w * 32 + rt * 16 + q * 4 + i;
        bool ok = (grow < N_NODES_C);
        float v = acc[rt][nt][i] + bv;
        if (RELU) v = fmaxf(v, 0.f);
        if (ok) {
          if (BF16OUT)
            outb[(size_t)grow * HID + gcol] = f2bf(v);
          else
            outf[(size_t)grow * HID + gcol] = v;
        }
        if (STATS) {
          float c = ok ? v : 0.f;
          sp[nt] += c;
          qp[nt] += c * c;
        }
      }
    }
  }

  if (STATS) {
    __syncthreads();
    float* sred = (float*)a_lds;        // [128][16]
    float* qred = sred + 128 * 16;
    int slot = w * 4 + q;
#pragma unroll
    for (int nt = 0; nt < 8; ++nt) {
      int gcol = nt * 16 + l15;
      sred[gcol * 16 + slot] = sp[nt];
      qred[gcol * 16 + slot] = qp[nt];
    }
    __syncthreads();
    if (t < 128) {
      float s = 0.f;
#pragma unroll
      for (int i = 0; i < 16; ++i) s += sred[t * 16 + i];
      atomicAdd(&gsum[t], s);
    } else {
      int f = t - 128;
      float s = 0.f;
#pragma unroll
      for (int i = 0; i < 16; ++i) s += qred[f * 16 + i];
      atomicAdd(&gsumsq[f], s);
    }
  }
}

__global__ void k_bn_finalize(const float* __restrict__ gsum, const float* __restrict__ gsumsq,
                              const float* __restrict__ gamma, const float* __restrict__ beta,
                              float* __restrict__ scale, float* __restrict__ shift) {
  int f = threadIdx.x;  // 128
  float mean = gsum[f] * (1.f / N_NODES_C);
  float var = gsumsq[f] * (1.f / N_NODES_C) - mean * mean;
  float inv = rsqrtf(var + BN_EPS_C);
  float sc = gamma[f] * inv;
  scale[f] = sc;
  shift[f] = beta[f] - mean * sc;
}

// BN + relu: reads t2 fp32, writes h bf16 packed (layers 0,1)
__global__ __launch_bounds__(256)
void k_bn_relu(const float* __restrict__ t2, const float* __restrict__ scale,
               const float* __restrict__ shift, unsigned short* __restrict__ h) {
  __shared__ float sc[HID], sh[HID];
  int t = threadIdx.x;
  if (t < HID) { sc[t] = scale[t]; sh[t] = shift[t]; }
  __syncthreads();
  size_t idx = ((size_t)blockIdx.x * 256 + t) * 4;
  if (idx < (size_t)N_NODES_C * HID) {
    float4 v = *(const float4*)&t2[idx];
    int f = (int)(idx & 127);
    float r0 = fmaxf(v.x * sc[f] + sh[f], 0.f);
    float r1 = fmaxf(v.y * sc[f + 1] + sh[f + 1], 0.f);
    float r2 = fmaxf(v.z * sc[f + 2] + sh[f + 2], 0.f);
    float r3 = fmaxf(v.w * sc[f + 3] + sh[f + 3], 0.f);
    uint2 o;
    o.x = (unsigned)f2bf(r0) | ((unsigned)f2bf(r1) << 16);
    o.y = (unsigned)f2bf(r2) | ((unsigned)f2bf(r3) << 16);
    *(uint2*)&h[idx] = o;
  }
}

// BN + relu + global_add_pool fused (last layer; h never materialized)
__global__ __launch_bounds__(128)
void k_bn_relu_pool(const float* __restrict__ t2, const float* __restrict__ scale,
                    const float* __restrict__ shift, const int* __restrict__ batch,
                    float* __restrict__ g) {
  int t = threadIdx.x;
  float sc = scale[t], sh = shift[t];
  int n0 = blockIdx.x * 64;
  if (n0 >= N_NODES_C) return;
  int end = min(n0 + 64, N_NODES_C);
  int cur = batch[n0];
  float acc = 0.f;
  for (int n = n0; n < end; ++n) {
    int b = batch[n];
    if (b != cur) {
      atomicAdd(&g[cur * HID + t], acc);
      acc = 0.f;
      cur = b;
    }
    acc += fmaxf(t2[(size_t)n * HID + t] * sc + sh, 0.f);
  }
  atomicAdd(&g[cur * HID + t], acc);
}

// ---------------- head: relu(g@w1+b1)@w2+b2 ----------------
__global__ __launch_bounds__(128)
void k_head(const float* __restrict__ g, const float* __restrict__ w1,
            const float* __restrict__ b1, const float* __restrict__ w2,
            const float* __restrict__ b2, float* __restrict__ out) {
  __shared__ float gs[HID];
  __shared__ float red[HID * 2];
  int gi = blockIdx.x, t = threadIdx.x;
  gs[t] = g[gi * HID + t];
  __syncthreads();
  float acc = b1[t];
#pragma unroll 8
  for (int k = 0; k < HID; ++k) acc += gs[k] * w1[k * HID + t];
  float hid = fmaxf(acc, 0.f);
  red[t * 2] = hid * w2[t * 2];
  red[t * 2 + 1] = hid * w2[t * 2 + 1];
  __syncthreads();
  for (int s = 64; s > 0; s >>= 1) {
    if (t < s) { red[t * 2] += red[(t + s) * 2]; red[t * 2 + 1] += red[(t + s) * 2 + 1]; }
    __syncthreads();
  }
  if (t == 0) {
    out[gi * 2] = red[0] + b2[0];
    out[gi * 2 + 1] = red[1] + b2[1];
  }
}

extern "C" void kernel_launch(void* const* d_in, const int* in_sizes, int n_in,
                              void* d_out, int out_size, void* d_ws, size_t ws_size,
                              hipStream_t stream) {
  const float* x      = (const float*)d_in[0];
  const int*   eidx   = (const int*)d_in[1];
  const float* eattr  = (const float*)d_in[2];
  const int*   batch  = (const int*)d_in[3];
  const float* node_w = (const float*)d_in[4];
  const float* node_b = (const float*)d_in[5];
  const float* edge_w = (const float*)d_in[6];
  const float* edge_b = (const float*)d_in[7];
  const float* mlp_w1 = (const float*)d_in[8];
  const float* mlp_b1 = (const float*)d_in[9];
  const float* mlp_w2 = (const float*)d_in[10];
  const float* mlp_b2 = (const float*)d_in[11];
  const float* bn_g   = (const float*)d_in[12];
  const float* bn_b   = (const float*)d_in[13];
  const float* hw1    = (const float*)d_in[14];
  const float* hb1    = (const float*)d_in[15];
  const float* hw2    = (const float*)d_in[16];
  const float* hb2    = (const float*)d_in[17];
  const int* srcArr = eidx;
  const int* dstArr = eidx + N_EDGES_C;

  char* wsp = (char*)d_ws;
  size_t off = 0;
  auto alloc = [&](size_t bytes) {
    void* p = wsp + off;
    off += (bytes + 255) & ~(size_t)255;
    return p;
  };
  unsigned short* h    = (unsigned short*)alloc((size_t)N_NODES_C * HID * 2);   // 12.8 MB
  unsigned short* zbf  = (unsigned short*)alloc((size_t)N_NODES_C * HID * 2);   // 12.8 MB
  unsigned short* t1bf = (unsigned short*)alloc((size_t)N_NODES_C * HID * 2);   // 12.8 MB
  float* t2f           = (float*)alloc((size_t)N_NODES_C * HID * 4);            // 25.6 MB
  unsigned short* ea16 = (unsigned short*)alloc((size_t)N_EDGES_C * HID * 2);   // 153.6 MB
  unsigned short* xb   = (unsigned short*)alloc((size_t)N_NODES_C * NODE_DIM_C * 2);  // 6.4 MB
  unsigned short* wT   = (unsigned short*)alloc(((size_t)6 * HID * HID + HID * NODE_DIM_C) * 2);
  int* row_ptr   = (int*)alloc((N_NODES_C + 1) * 4);
  int* cnt_cur   = (int*)alloc(N_NODES_C * 4);
  int* perm      = (int*)alloc((size_t)N_EDGES_C * 4);
  int* src_perm  = (int*)alloc((size_t)N_EDGES_C * 4);
  int* partial   = (int*)alloc(256 * 4);
  int* partial_off = (int*)alloc(256 * 4);
  float* gsum    = (float*)alloc(HID * 4);
  float* gsumsq  = (float*)alloc(HID * 4);
  float* scale   = (float*)alloc(HID * 4);
  float* shift   = (float*)alloc(HID * 4);
  float* g       = (float*)alloc((size_t)N_GRAPHS_C * HID * 4);
  unsigned short* nwT = wT + (size_t)6 * HID * HID;

  hipMemsetAsync(cnt_cur, 0, N_NODES_C * 4, stream);
  hipMemsetAsync(g, 0, (size_t)N_GRAPHS_C * HID * 4, stream);

  k_x2bf<<<(N_NODES_C * NODE_DIM_C / 4 + 255) / 256, 256, 0, stream>>>(x, xb);
  k_prep_w<<<7, 256, 0, stream>>>(mlp_w1, mlp_w2, node_w, wT);
  k_node_mfma<<<(N_NODES_C + 127) / 128, 256, 0, stream>>>(xb, nwT, node_b, h);
  k_histogram<<<(N_EDGES_C + 255) / 256, 256, 0, stream>>>(dstArr, cnt_cur);
  k_blocksum<<<SCAN_NBLK, 256, 0, stream>>>(cnt_cur, partial);
  k_scanpartials<<<1, 256, 0, stream>>>(partial, partial_off);
  k_apply<<<SCAN_NBLK, 256, 0, stream>>>(cnt_cur, partial_off, row_ptr);
  k_bucket<<<(N_EDGES_C + 255) / 256, 256, 0, stream>>>(dstArr, srcArr, cnt_cur,
                                                        perm, src_perm);
  k_edge_encode<<<(N_EDGES_C + 127) / 128, 256, 0, stream>>>(perm, eattr, edge_w,
                                                             edge_b, ea16);

  const int GB = (N_NODES_C + 127) / 128;  // 391
  for (int l = 0; l < 3; ++l) {
    k_aggregate<<<(N_NODES_C + 3) / 4, 256, 0, stream>>>((const unsigned*)h,
                                                         (const unsigned*)ea16,
                                                         src_perm, row_ptr, zbf);
    k_gemm_mfma<true, true, false><<<GB, 256, 0, stream>>>(
        zbf, wT + (size_t)l * HID * HID, mlp_b1 + l * HID, t1bf, nullptr,
        nullptr, nullptr);
    hipMemsetAsync(gsum, 0, HID * 4, stream);
    hipMemsetAsync(gsumsq, 0, HID * 4, stream);
    k_gemm_mfma<false, false, true><<<GB, 256, 0, stream>>>(
        t1bf, wT + (size_t)(3 + l) * HID * HID, mlp_b2 + l * HID, nullptr, t2f,
        gsum, gsumsq);
    k_bn_finalize<<<1, HID, 0, stream>>>(gsum, gsumsq, bn_g + l * HID, bn_b + l * HID,
                                         scale, shift);
    if (l < 2) {
      k_bn_relu<<<(N_NODES_C * HID / 4 + 255) / 256, 256, 0, stream>>>(t2f, scale,
                                                                       shift, h);
    } else {
      k_bn_relu_pool<<<(N_NODES_C + 63) / 64, 128, 0, stream>>>(t2f, scale, shift,
                                                                batch, g);
    }
  }
  k_head<<<N_GRAPHS_C, 128, 0, stream>>>(g, hw1, hb1, hw2, hb2, (float*)d_out);
}

// Round 8
// 574.789 us; speedup vs baseline: 2.1385x; 1.0193x over previous
//
#include <hip/hip_runtime.h>

#define N_NODES_C 50000
#define N_EDGES_C 600000
#define NODE_DIM_C 64
#define EDGE_DIM_C 16
#define HID 128
#define N_GRAPHS_C 256
#define BN_EPS_C 1e-5f
#define SCAN_NBLK ((N_NODES_C + 255) / 256)  // 196

typedef short bf16x8 __attribute__((ext_vector_type(8)));
typedef float f32x4 __attribute__((ext_vector_type(4)));

__device__ __forceinline__ unsigned short f2bf(float f) {
  union { float f; unsigned u; } v; v.f = f;
  unsigned r = (v.u + 0x7fffu + ((v.u >> 16) & 1u)) >> 16;
  return (unsigned short)r;
}

__device__ __forceinline__ float2 bfp2f(unsigned u) {
  union { unsigned u; float f; } lo, hi;
  lo.u = u << 16;
  hi.u = u & 0xffff0000u;
  return make_float2(lo.f, hi.f);
}

// ---------- x -> bf16 conversion; also zero-inits cnt_cur and g ----------
__global__ __launch_bounds__(256)
void k_x2bf(const float* __restrict__ x, unsigned short* __restrict__ xb,
            int* __restrict__ cnt, float* __restrict__ g) {
  int tid = blockIdx.x * 256 + threadIdx.x;
  size_t i = (size_t)tid * 4;
  if (i < (size_t)N_NODES_C * NODE_DIM_C) {
    float4 v = *(const float4*)&x[i];
    uint2 o;
    o.x = (unsigned)f2bf(v.x) | ((unsigned)f2bf(v.y) << 16);
    o.y = (unsigned)f2bf(v.z) | ((unsigned)f2bf(v.w) << 16);
    *(uint2*)&xb[i] = o;
  }
  if (tid < N_NODES_C) cnt[tid] = 0;
  if (tid < N_GRAPHS_C * HID) g[tid] = 0.f;
}

// ------- weight prep: 6 MLP mats -> wT[m][n*128+k]; node_w -> nwT[n*64+k] ---
__global__ __launch_bounds__(256)
void k_prep_w(const float* __restrict__ w1, const float* __restrict__ w2,
              const float* __restrict__ nodew, unsigned short* __restrict__ wT) {
  int m = blockIdx.x;  // 0..6
  if (m < 6) {
    const float* src = (m < 3) ? (w1 + (size_t)m * HID * HID)
                               : (w2 + (size_t)(m - 3) * HID * HID);
    unsigned short* dst = wT + (size_t)m * HID * HID;
    for (int i = threadIdx.x; i < HID * HID; i += 256) {
      int n = i >> 7, k = i & 127;
      dst[n * HID + k] = f2bf(src[k * HID + n]);
    }
  } else {
    unsigned short* dst = wT + (size_t)6 * HID * HID;  // [128][64]
    for (int i = threadIdx.x; i < HID * NODE_DIM_C; i += 256) {
      int n = i >> 6, k = i & 63;
      dst[n * NODE_DIM_C + k] = f2bf(nodew[k * HID + n]);
    }
  }
}

// ------- node encoder via MFMA: h = bf16(x_bf @ node_w + node_b), K=64 ------
__global__ __launch_bounds__(256)
void k_node_mfma(const unsigned short* __restrict__ xb,
                 const unsigned short* __restrict__ nwT,
                 const float* __restrict__ bias, unsigned short* __restrict__ h) {
  const int LD = NODE_DIM_C + 8;  // 72
  __shared__ unsigned short a_lds[128 * LD];  // 18 KB
  __shared__ unsigned short w_lds[128 * LD];  // 18 KB
  int t = threadIdx.x;
  int row0 = blockIdx.x * 128;
  {
    int r = t >> 3, c = t & 7;
#pragma unroll
    for (int it = 0; it < 4; ++it) {
      int row = it * 32 + r;
      int grow = row0 + row;
      uint4 va = (grow < N_NODES_C)
                     ? ((const uint4*)(xb + (size_t)grow * NODE_DIM_C))[c]
                     : make_uint4(0, 0, 0, 0);
      *(uint4*)&a_lds[row * LD + c * 8] = va;
      uint4 vw = ((const uint4*)(nwT + (size_t)row * NODE_DIM_C))[c];
      *(uint4*)&w_lds[row * LD + c * 8] = vw;
    }
  }
  __syncthreads();

  int lane = t & 63;
  int w = t >> 6;
  int l15 = lane & 15;
  int q = lane >> 4;

  f32x4 acc[2][8];
#pragma unroll
  for (int rt = 0; rt < 2; ++rt)
#pragma unroll
    for (int nt = 0; nt < 8; ++nt) acc[rt][nt] = (f32x4)0.f;

#pragma unroll
  for (int kk = 0; kk < 2; ++kk) {
    int k0 = kk * 32;
    bf16x8 af[2];
#pragma unroll
    for (int rt = 0; rt < 2; ++rt) {
      int arow = w * 32 + rt * 16 + l15;
      af[rt] = *(const bf16x8*)&a_lds[arow * LD + k0 + q * 8];
    }
#pragma unroll
    for (int nt = 0; nt < 8; ++nt) {
      bf16x8 bf = *(const bf16x8*)&w_lds[(nt * 16 + l15) * LD + k0 + q * 8];
#pragma unroll
      for (int rt = 0; rt < 2; ++rt)
        acc[rt][nt] = __builtin_amdgcn_mfma_f32_16x16x32_bf16(af[rt], bf, acc[rt][nt], 0, 0, 0);
    }
  }

#pragma unroll
  for (int nt = 0; nt < 8; ++nt) {
    int gcol = nt * 16 + l15;
    float bv = bias[gcol];
#pragma unroll
    for (int rt = 0; rt < 2; ++rt) {
#pragma unroll
      for (int i = 0; i < 4; ++i) {
        int grow = row0 + w * 32 + rt * 16 + q * 4 + i;
        if (grow < N_NODES_C) h[(size_t)grow * HID + gcol] = f2bf(acc[rt][nt][i] + bv);
      }
    }
  }
}

// ---------------- CSR build (counting sort by dst) ----------------
__global__ __launch_bounds__(256)
void k_histogram(const int* __restrict__ dst, int* __restrict__ counts) {
  int e = blockIdx.x * 256 + threadIdx.x;
  if (e < N_EDGES_C) atomicAdd(&counts[dst[e]], 1);
}

__global__ __launch_bounds__(256)
void k_blocksum(const int* __restrict__ cnt, int* __restrict__ partial) {
  __shared__ int ls[4];
  int t = threadIdx.x;
  int i = blockIdx.x * 256 + t;
  int v = (i < N_NODES_C) ? cnt[i] : 0;
#pragma unroll
  for (int o = 32; o > 0; o >>= 1) v += __shfl_down(v, o, 64);
  if ((t & 63) == 0) ls[t >> 6] = v;
  __syncthreads();
  if (t == 0) partial[blockIdx.x] = ls[0] + ls[1] + ls[2] + ls[3];
}

__global__ __launch_bounds__(256)
void k_scanpartials(const int* __restrict__ partial, int* __restrict__ partial_off) {
  __shared__ int s[256];
  int t = threadIdx.x;
  int v = (t < SCAN_NBLK) ? partial[t] : 0;
  s[t] = v;
  __syncthreads();
  for (int d = 1; d < 256; d <<= 1) {
    int x = (t >= d) ? s[t - d] : 0;
    __syncthreads();
    s[t] += x;
    __syncthreads();
  }
  if (t < SCAN_NBLK) partial_off[t] = s[t] - v;
}

__global__ __launch_bounds__(256)
void k_apply(int* __restrict__ cnt_cursor, const int* __restrict__ partial_off,
             int* __restrict__ row_ptr) {
  __shared__ int s[256];
  int t = threadIdx.x;
  int i = blockIdx.x * 256 + t;
  int v = (i < N_NODES_C) ? cnt_cursor[i] : 0;
  s[t] = v;
  __syncthreads();
  for (int d = 1; d < 256; d <<= 1) {
    int x = (t >= d) ? s[t - d] : 0;
    __syncthreads();
    s[t] += x;
    __syncthreads();
  }
  int excl = s[t] - v + partial_off[blockIdx.x];
  if (i < N_NODES_C) {
    row_ptr[i] = excl;
    cnt_cursor[i] = excl;
  }
  if (i == 0) row_ptr[N_NODES_C] = N_EDGES_C;
}

__global__ __launch_bounds__(256)
void k_bucket(const int* __restrict__ dst, const int* __restrict__ srcArr,
              int* __restrict__ cursor, int* __restrict__ perm,
              int* __restrict__ src_perm) {
  int e = blockIdx.x * 256 + threadIdx.x;
  if (e < N_EDGES_C) {
    int p = atomicAdd(&cursor[dst[e]], 1);
    perm[p] = e;
    src_perm[p] = srcArr[e];
  }
}

// ---- edge encoder via MFMA (layer-invariant, computed once):
// ea[i] = bf16(eattr[perm[i]] @ ew + eb) in CSR edge order.
// A/W staged via uint4 ds_writes; out tile stride 132 (conflict-free epilogue).
#define EE_LDW 40   // A/W row stride (shorts); K padded 16->32 + 8 pad
#define EE_OSW 132  // out tile row stride (shorts): 264 B -> quads hit banks 0/8/16/24
__global__ __launch_bounds__(256)
void k_edge_encode(const int* __restrict__ perm, const float* __restrict__ eattr,
                   const float* __restrict__ ew, const float* __restrict__ ebias,
                   unsigned short* __restrict__ ea16) {
  __shared__ unsigned short smem[128 * EE_OSW];  // 33 KB; overlays A,W then OUT
  unsigned short* a_lds = smem;                  // [128][EE_LDW]
  unsigned short* w_lds = smem + 128 * EE_LDW;   // [128][EE_LDW]
  int t = threadIdx.x;
  int EB = blockIdx.x * 128;

  // stage W: one thread per output column n; 2 valid uint4 + 2 zero uint4
  if (t < 128) {
    unsigned short tmp[16];
#pragma unroll
    for (int k = 0; k < 16; ++k) tmp[k] = f2bf(ew[k * HID + t]);
    uint4* wr = (uint4*)&w_lds[t * EE_LDW];  // byte ofs t*80: 16B aligned
    wr[0] = *(uint4*)&tmp[0];
    wr[1] = *(uint4*)&tmp[8];
    wr[2] = make_uint4(0, 0, 0, 0);
    wr[3] = make_uint4(0, 0, 0, 0);
  }
  // stage A: 2 threads per edge, 8 floats -> 1 uint4 + 1 zero uint4
  {
    int edge = t >> 1, half = t & 1;
    int gi = EB + edge;
    float4 v0 = make_float4(0, 0, 0, 0), v1 = v0;
    if (gi < N_EDGES_C) {
      int e = perm[gi];
      const float4* p = (const float4*)(eattr + (size_t)e * EDGE_DIM_C + half * 8);
      v0 = p[0];
      v1 = p[1];
    }
    unsigned short tmp[8] = {f2bf(v0.x), f2bf(v0.y), f2bf(v0.z), f2bf(v0.w),
                             f2bf(v1.x), f2bf(v1.y), f2bf(v1.z), f2bf(v1.w)};
    // byte ofs edge*80 + half*16: 16B aligned
    *(uint4*)&a_lds[edge * EE_LDW + half * 8] = *(uint4*)tmp;
    *(uint4*)&a_lds[edge * EE_LDW + 16 + half * 8] = make_uint4(0, 0, 0, 0);
  }
  __syncthreads();

  int lane = t & 63;
  int w = t >> 6;
  int l15 = lane & 15;
  int q = lane >> 4;

  f32x4 acc[2][8];
  {
    bf16x8 af[2];
#pragma unroll
    for (int rt = 0; rt < 2; ++rt) {
      int arow = w * 32 + rt * 16 + l15;
      af[rt] = *(const bf16x8*)&a_lds[arow * EE_LDW + q * 8];
    }
#pragma unroll
    for (int nt = 0; nt < 8; ++nt) {
      bf16x8 bf = *(const bf16x8*)&w_lds[(nt * 16 + l15) * EE_LDW + q * 8];
#pragma unroll
      for (int rt = 0; rt < 2; ++rt)
        acc[rt][nt] = __builtin_amdgcn_mfma_f32_16x16x32_bf16(
            af[rt], bf, (f32x4)0.f, 0, 0, 0);
    }
  }
  __syncthreads();  // done reading A/W; smem becomes the output tile [128][EE_OSW]

#pragma unroll
  for (int nt = 0; nt < 8; ++nt) {
    int col = nt * 16 + l15;
    float bv = ebias[col];
#pragma unroll
    for (int rt = 0; rt < 2; ++rt) {
#pragma unroll
      for (int i = 0; i < 4; ++i) {
        int row = w * 32 + rt * 16 + q * 4 + i;
        smem[row * EE_OSW + col] = f2bf(acc[rt][nt][i] + bv);
      }
    }
  }
  __syncthreads();

  int valid = min(128, N_EDGES_C - EB);
  for (int i = t; i < valid * 32; i += 256) {
    int row = i >> 5, c = i & 31;
    uint2 v = *(const uint2*)&smem[row * EE_OSW + c * 4];  // 8B aligned
    *(uint2*)&ea16[((size_t)EB + row) * HID + c * 4] = v;
  }
}

// -------- aggregate: z[n] = h[n] + sum_{e: dst=n} relu(h[src_e] + ea_e) -----
// block 0 also zero-inits gsum/gsumsq for this layer's stats GEMM
__global__ __launch_bounds__(256)
void k_aggregate(const unsigned* __restrict__ h32, const unsigned* __restrict__ ea,
                 const int* __restrict__ src_p, const int* __restrict__ row_ptr,
                 unsigned short* __restrict__ z, float* __restrict__ gsum,
                 float* __restrict__ gsumsq) {
  int t = threadIdx.x;
  if (blockIdx.x == 0 && t < HID) { gsum[t] = 0.f; gsumsq[t] = 0.f; }
  int lane = t & 63;
  int wave = t >> 6;
  int node = blockIdx.x * 4 + wave;
  if (node >= N_NODES_C) return;
  float2 base = bfp2f(h32[(size_t)node * 64 + lane]);
  float acc0 = base.x, acc1 = base.y;
  int beg = row_ptr[node], end = row_ptr[node + 1];
  int j = beg;
  for (; j + 8 <= end; j += 8) {
    int s0 = src_p[j],     s1 = src_p[j + 1], s2 = src_p[j + 2], s3 = src_p[j + 3];
    int s4 = src_p[j + 4], s5 = src_p[j + 5], s6 = src_p[j + 6], s7 = src_p[j + 7];
    unsigned g0 = h32[(size_t)s0 * 64 + lane];
    unsigned g1 = h32[(size_t)s1 * 64 + lane];
    unsigned g2 = h32[(size_t)s2 * 64 + lane];
    unsigned g3 = h32[(size_t)s3 * 64 + lane];
    unsigned g4 = h32[(size_t)s4 * 64 + lane];
    unsigned g5 = h32[(size_t)s5 * 64 + lane];
    unsigned g6 = h32[(size_t)s6 * 64 + lane];
    unsigned g7 = h32[(size_t)s7 * 64 + lane];
    unsigned u0 = ea[(size_t)j * 64 + lane];
    unsigned u1 = ea[(size_t)(j + 1) * 64 + lane];
    unsigned u2 = ea[(size_t)(j + 2) * 64 + lane];
    unsigned u3 = ea[(size_t)(j + 3) * 64 + lane];
    unsigned u4 = ea[(size_t)(j + 4) * 64 + lane];
    unsigned u5 = ea[(size_t)(j + 5) * 64 + lane];
    unsigned u6 = ea[(size_t)(j + 6) * 64 + lane];
    unsigned u7 = ea[(size_t)(j + 7) * 64 + lane];
    float2 a0 = bfp2f(g0), a1 = bfp2f(g1), a2 = bfp2f(g2), a3 = bfp2f(g3);
    float2 a4 = bfp2f(g4), a5 = bfp2f(g5), a6 = bfp2f(g6), a7 = bfp2f(g7);
    float2 e0 = bfp2f(u0), e1 = bfp2f(u1), e2 = bfp2f(u2), e3 = bfp2f(u3);
    float2 e4 = bfp2f(u4), e5 = bfp2f(u5), e6 = bfp2f(u6), e7 = bfp2f(u7);
    acc0 += fmaxf(a0.x + e0.x, 0.f) + fmaxf(a1.x + e1.x, 0.f) +
            fmaxf(a2.x + e2.x, 0.f) + fmaxf(a3.x + e3.x, 0.f) +
            fmaxf(a4.x + e4.x, 0.f) + fmaxf(a5.x + e5.x, 0.f) +
            fmaxf(a6.x + e6.x, 0.f) + fmaxf(a7.x + e7.x, 0.f);
    acc1 += fmaxf(a0.y + e0.y, 0.f) + fmaxf(a1.y + e1.y, 0.f) +
            fmaxf(a2.y + e2.y, 0.f) + fmaxf(a3.y + e3.y, 0.f) +
            fmaxf(a4.y + e4.y, 0.f) + fmaxf(a5.y + e5.y, 0.f) +
            fmaxf(a6.y + e6.y, 0.f) + fmaxf(a7.y + e7.y, 0.f);
  }
  for (; j + 4 <= end; j += 4) {
    int s0 = src_p[j], s1 = src_p[j + 1], s2 = src_p[j + 2], s3 = src_p[j + 3];
    unsigned g0 = h32[(size_t)s0 * 64 + lane];
    unsigned g1 = h32[(size_t)s1 * 64 + lane];
    unsigned g2 = h32[(size_t)s2 * 64 + lane];
    unsigned g3 = h32[(size_t)s3 * 64 + lane];
    unsigned u0 = ea[(size_t)j * 64 + lane];
    unsigned u1 = ea[(size_t)(j + 1) * 64 + lane];
    unsigned u2 = ea[(size_t)(j + 2) * 64 + lane];
    unsigned u3 = ea[(size_t)(j + 3) * 64 + lane];
    float2 a0 = bfp2f(g0), a1 = bfp2f(g1), a2 = bfp2f(g2), a3 = bfp2f(g3);
    float2 e0 = bfp2f(u0), e1 = bfp2f(u1), e2 = bfp2f(u2), e3 = bfp2f(u3);
    acc0 += fmaxf(a0.x + e0.x, 0.f) + fmaxf(a1.x + e1.x, 0.f) +
            fmaxf(a2.x + e2.x, 0.f) + fmaxf(a3.x + e3.x, 0.f);
    acc1 += fmaxf(a0.y + e0.y, 0.f) + fmaxf(a1.y + e1.y, 0.f) +
            fmaxf(a2.y + e2.y, 0.f) + fmaxf(a3.y + e3.y, 0.f);
  }
  for (; j < end; ++j) {
    int s0 = src_p[j];
    float2 a0 = bfp2f(h32[(size_t)s0 * 64 + lane]);
    float2 e0 = bfp2f(ea[(size_t)j * 64 + lane]);
    acc0 += fmaxf(a0.x + e0.x, 0.f);
    acc1 += fmaxf(a0.y + e0.y, 0.f);
  }
  unsigned packed = (unsigned)f2bf(acc0) | ((unsigned)f2bf(acc1) << 16);
  *(unsigned*)&z[(size_t)node * HID + lane * 2] = packed;
}

// ---------- MFMA GEMM: [50000,128](bf16) @ W^T[128,128](bf16) + bias --------
template <bool RELU, bool BF16OUT, bool STATS>
__global__ __launch_bounds__(256)
void k_gemm_mfma(const unsigned short* __restrict__ in,
                 const unsigned short* __restrict__ wT,
                 const float* __restrict__ bias,
                 unsigned short* __restrict__ outb, float* __restrict__ outf,
                 float* __restrict__ gsum, float* __restrict__ gsumsq) {
  const int LDA = HID + 8;
  __shared__ unsigned short a_lds[128 * LDA];
  __shared__ unsigned short w_lds[128 * LDA];
  int t = threadIdx.x;
  int row0 = blockIdx.x * 128;
  {
    int r = t >> 4, chunk = t & 15;
#pragma unroll
    for (int it = 0; it < 8; ++it) {
      int row = it * 16 + r;
      int grow = row0 + row;
      uint4 va = (grow < N_NODES_C)
                     ? ((const uint4*)(in + (size_t)grow * HID))[chunk]
                     : make_uint4(0, 0, 0, 0);
      *(uint4*)&a_lds[row * LDA + chunk * 8] = va;
      uint4 vw = ((const uint4*)(wT + (size_t)row * HID))[chunk];
      *(uint4*)&w_lds[row * LDA + chunk * 8] = vw;
    }
  }
  __syncthreads();

  int lane = t & 63;
  int w = t >> 6;
  int l15 = lane & 15;
  int q = lane >> 4;

  f32x4 acc[2][8];
#pragma unroll
  for (int rt = 0; rt < 2; ++rt)
#pragma unroll
    for (int nt = 0; nt < 8; ++nt) acc[rt][nt] = (f32x4)0.f;

#pragma unroll
  for (int kk = 0; kk < 4; ++kk) {
    int k0 = kk * 32;
    bf16x8 af[2];
#pragma unroll
    for (int rt = 0; rt < 2; ++rt) {
      int arow = w * 32 + rt * 16 + l15;
      af[rt] = *(const bf16x8*)&a_lds[arow * LDA + k0 + q * 8];
    }
#pragma unroll
    for (int nt = 0; nt < 8; ++nt) {
      int brow = nt * 16 + l15;
      bf16x8 bf = *(const bf16x8*)&w_lds[brow * LDA + k0 + q * 8];
#pragma unroll
      for (int rt = 0; rt < 2; ++rt)
        acc[rt][nt] = __builtin_amdgcn_mfma_f32_16x16x32_bf16(af[rt], bf, acc[rt][nt], 0, 0, 0);
    }
  }

  float sp[8], qp[8];
#pragma unroll
  for (int nt = 0; nt < 8; ++nt) { sp[nt] = 0.f; qp[nt] = 0.f; }

#pragma unroll
  for (int nt = 0; nt < 8; ++nt) {
    int gcol = nt * 16 + l15;
    float bv = bias[gcol];
#pragma unroll
    for (int rt = 0; rt < 2; ++rt) {
#pragma unroll
      for (int i = 0; i < 4; ++i) {
        int grow = row0 + w * 32 + rt * 16 + q * 4 + i;
        bool ok = (grow < N_NODES_C);
        float v = acc[rt][nt][i] + bv;
        if (RELU) v = fmaxf(v, 0.f);
        if (ok) {
          if (BF16OUT)
            outb[(size_t)grow * HID + gcol] = f2bf(v);
          else
            outf[(size_t)grow * HID + gcol] = v;
        }
        if (STATS) {
          float c = ok ? v : 0.f;
          sp[nt] += c;
          qp[nt] += c * c;
        }
      }
    }
  }

  if (STATS) {
    __syncthreads();
    float* sred = (float*)a_lds;        // [128][16]
    float* qred = sred + 128 * 16;
    int slot = w * 4 + q;
#pragma unroll
    for (int nt = 0; nt < 8; ++nt) {
      int gcol = nt * 16 + l15;
      sred[gcol * 16 + slot] = sp[nt];
      qred[gcol * 16 + slot] = qp[nt];
    }
    __syncthreads();
    if (t < 128) {
      float s = 0.f;
#pragma unroll
      for (int i = 0; i < 16; ++i) s += sred[t * 16 + i];
      atomicAdd(&gsum[t], s);
    } else {
      int f = t - 128;
      float s = 0.f;
#pragma unroll
      for (int i = 0; i < 16; ++i) s += qred[f * 16 + i];
      atomicAdd(&gsumsq[f], s);
    }
  }
}

__global__ void k_bn_finalize(const float* __restrict__ gsum, const float* __restrict__ gsumsq,
                              const float* __restrict__ gamma, const float* __restrict__ beta,
                              float* __restrict__ scale, float* __restrict__ shift) {
  int f = threadIdx.x;  // 128
  float mean = gsum[f] * (1.f / N_NODES_C);
  float var = gsumsq[f] * (1.f / N_NODES_C) - mean * mean;
  float inv = rsqrtf(var + BN_EPS_C);
  float sc = gamma[f] * inv;
  scale[f] = sc;
  shift[f] = beta[f] - mean * sc;
}

// BN + relu: reads t2 fp32, writes h bf16 packed (layers 0,1)
__global__ __launch_bounds__(256)
void k_bn_relu(const float* __restrict__ t2, const float* __restrict__ scale,
               const float* __restrict__ shift, unsigned short* __restrict__ h) {
  __shared__ float sc[HID], sh[HID];
  int t = threadIdx.x;
  if (t < HID) { sc[t] = scale[t]; sh[t] = shift[t]; }
  __syncthreads();
  size_t idx = ((size_t)blockIdx.x * 256 + t) * 4;
  if (idx < (size_t)N_NODES_C * HID) {
    float4 v = *(const float4*)&t2[idx];
    int f = (int)(idx & 127);
    float r0 = fmaxf(v.x * sc[f] + sh[f], 0.f);
    float r1 = fmaxf(v.y * sc[f + 1] + sh[f + 1], 0.f);
    float r2 = fmaxf(v.z * sc[f + 2] + sh[f + 2], 0.f);
    float r3 = fmaxf(v.w * sc[f + 3] + sh[f + 3], 0.f);
    uint2 o;
    o.x = (unsigned)f2bf(r0) | ((unsigned)f2bf(r1) << 16);
    o.y = (unsigned)f2bf(r2) | ((unsigned)f2bf(r3) << 16);
    *(uint2*)&h[idx] = o;
  }
}

// BN + relu + global_add_pool fused (last layer; h never materialized)
__global__ __launch_bounds__(128)
void k_bn_relu_pool(const float* __restrict__ t2, const float* __restrict__ scale,
                    const float* __restrict__ shift, const int* __restrict__ batch,
                    float* __restrict__ g) {
  int t = threadIdx.x;
  float sc = scale[t], sh = shift[t];
  int n0 = blockIdx.x * 64;
  if (n0 >= N_NODES_C) return;
  int end = min(n0 + 64, N_NODES_C);
  int cur = batch[n0];
  float acc = 0.f;
  for (int n = n0; n < end; ++n) {
    int b = batch[n];
    if (b != cur) {
      atomicAdd(&g[cur * HID + t], acc);
      acc = 0.f;
      cur = b;
    }
    acc += fmaxf(t2[(size_t)n * HID + t] * sc + sh, 0.f);
  }
  atomicAdd(&g[cur * HID + t], acc);
}

// ---------------- head: relu(g@w1+b1)@w2+b2 ----------------
__global__ __launch_bounds__(128)
void k_head(const float* __restrict__ g, const float* __restrict__ w1,
            const float* __restrict__ b1, const float* __restrict__ w2,
            const float* __restrict__ b2, float* __restrict__ out) {
  __shared__ float gs[HID];
  __shared__ float red[HID * 2];
  int gi = blockIdx.x, t = threadIdx.x;
  gs[t] = g[gi * HID + t];
  __syncthreads();
  float acc = b1[t];
#pragma unroll 8
  for (int k = 0; k < HID; ++k) acc += gs[k] * w1[k * HID + t];
  float hid = fmaxf(acc, 0.f);
  red[t * 2] = hid * w2[t * 2];
  red[t * 2 + 1] = hid * w2[t * 2 + 1];
  __syncthreads();
  for (int s = 64; s > 0; s >>= 1) {
    if (t < s) { red[t * 2] += red[(t + s) * 2]; red[t * 2 + 1] += red[(t + s) * 2 + 1]; }
    __syncthreads();
  }
  if (t == 0) {
    out[gi * 2] = red[0] + b2[0];
    out[gi * 2 + 1] = red[1] + b2[1];
  }
}

extern "C" void kernel_launch(void* const* d_in, const int* in_sizes, int n_in,
                              void* d_out, int out_size, void* d_ws, size_t ws_size,
                              hipStream_t stream) {
  const float* x      = (const float*)d_in[0];
  const int*   eidx   = (const int*)d_in[1];
  const float* eattr  = (const float*)d_in[2];
  const int*   batch  = (const int*)d_in[3];
  const float* node_w = (const float*)d_in[4];
  const float* node_b = (const float*)d_in[5];
  const float* edge_w = (const float*)d_in[6];
  const float* edge_b = (const float*)d_in[7];
  const float* mlp_w1 = (const float*)d_in[8];
  const float* mlp_b1 = (const float*)d_in[9];
  const float* mlp_w2 = (const float*)d_in[10];
  const float* mlp_b2 = (const float*)d_in[11];
  const float* bn_g   = (const float*)d_in[12];
  const float* bn_b   = (const float*)d_in[13];
  const float* hw1    = (const float*)d_in[14];
  const float* hb1    = (const float*)d_in[15];
  const float* hw2    = (const float*)d_in[16];
  const float* hb2    = (const float*)d_in[17];
  const int* srcArr = eidx;
  const int* dstArr = eidx + N_EDGES_C;

  char* wsp = (char*)d_ws;
  size_t off = 0;
  auto alloc = [&](size_t bytes) {
    void* p = wsp + off;
    off += (bytes + 255) & ~(size_t)255;
    return p;
  };
  unsigned short* h    = (unsigned short*)alloc((size_t)N_NODES_C * HID * 2);   // 12.8 MB
  unsigned short* zbf  = (unsigned short*)alloc((size_t)N_NODES_C * HID * 2);   // 12.8 MB
  unsigned short* t1bf = (unsigned short*)alloc((size_t)N_NODES_C * HID * 2);   // 12.8 MB
  float* t2f           = (float*)alloc((size_t)N_NODES_C * HID * 4);            // 25.6 MB
  unsigned short* ea16 = (unsigned short*)alloc((size_t)N_EDGES_C * HID * 2);   // 153.6 MB
  unsigned short* xb   = (unsigned short*)alloc((size_t)N_NODES_C * NODE_DIM_C * 2);  // 6.4 MB
  unsigned short* wT   = (unsigned short*)alloc(((size_t)6 * HID * HID + HID * NODE_DIM_C) * 2);
  int* row_ptr   = (int*)alloc((N_NODES_C + 1) * 4);
  int* cnt_cur   = (int*)alloc(N_NODES_C * 4);
  int* perm      = (int*)alloc((size_t)N_EDGES_C * 4);
  int* src_perm  = (int*)alloc((size_t)N_EDGES_C * 4);
  int* partial   = (int*)alloc(256 * 4);
  int* partial_off = (int*)alloc(256 * 4);
  float* gsum    = (float*)alloc(HID * 4);
  float* gsumsq  = (float*)alloc(HID * 4);
  float* scale   = (float*)alloc(HID * 4);
  float* shift   = (float*)alloc(HID * 4);
  float* g       = (float*)alloc((size_t)N_GRAPHS_C * HID * 4);
  unsigned short* nwT = wT + (size_t)6 * HID * HID;

  k_x2bf<<<(N_NODES_C * NODE_DIM_C / 4 + 255) / 256, 256, 0, stream>>>(x, xb,
                                                                       cnt_cur, g);
  k_prep_w<<<7, 256, 0, stream>>>(mlp_w1, mlp_w2, node_w, wT);
  k_node_mfma<<<(N_NODES_C + 127) / 128, 256, 0, stream>>>(xb, nwT, node_b, h);
  k_histogram<<<(N_EDGES_C + 255) / 256, 256, 0, stream>>>(dstArr, cnt_cur);
  k_blocksum<<<SCAN_NBLK, 256, 0, stream>>>(cnt_cur, partial);
  k_scanpartials<<<1, 256, 0, stream>>>(partial, partial_off);
  k_apply<<<SCAN_NBLK, 256, 0, stream>>>(cnt_cur, partial_off, row_ptr);
  k_bucket<<<(N_EDGES_C + 255) / 256, 256, 0, stream>>>(dstArr, srcArr, cnt_cur,
                                                        perm, src_perm);
  k_edge_encode<<<(N_EDGES_C + 127) / 128, 256, 0, stream>>>(perm, eattr, edge_w,
                                                             edge_b, ea16);

  const int GB = (N_NODES_C + 127) / 128;  // 391
  for (int l = 0; l < 3; ++l) {
    k_aggregate<<<(N_NODES_C + 3) / 4, 256, 0, stream>>>((const unsigned*)h,
                                                         (const unsigned*)ea16,
                                                         src_perm, row_ptr, zbf,
                                                         gsum, gsumsq);
    k_gemm_mfma<true, true, false><<<GB, 256, 0, stream>>>(
        zbf, wT + (size_t)l * HID * HID, mlp_b1 + l * HID, t1bf, nullptr,
        nullptr, nullptr);
    k_gemm_mfma<false, false, true><<<GB, 256, 0, stream>>>(
        t1bf, wT + (size_t)(3 + l) * HID * HID, mlp_b2 + l * HID, nullptr, t2f,
        gsum, gsumsq);
    k_bn_finalize<<<1, HID, 0, stream>>>(gsum, gsumsq, bn_g + l * HID, bn_b + l * HID,
                                         scale, shift);
    if (l < 2) {
      k_bn_relu<<<(N_NODES_C * HID / 4 + 255) / 256, 256, 0, stream>>>(t2f, scale,
                                                                       shift, h);
    } else {
      k_bn_relu_pool<<<(N_NODES_C + 63) / 64, 128, 0, stream>>>(t2f, scale, shift,
                                                                batch, g);
    }
  }
  k_head<<<N_GRAPHS_C, 128, 0, stream>>>(g, hw1, hb1, hw2, hb2, (float*)d_out);
}

// Round 9
// 568.005 us; speedup vs baseline: 2.1641x; 1.0119x over previous
//
#include <hip/hip_runtime.h>

#define N_NODES_C 50000
#define N_EDGES_C 600000
#define NODE_DIM_C 64
#define EDGE_DIM_C 16
#define HID 128
#define N_GRAPHS_C 256
#define BN_EPS_C 1e-5f
#define SCAN_NBLK ((N_NODES_C + 255) / 256)  // 196

typedef short bf16x8 __attribute__((ext_vector_type(8)));
typedef float f32x4 __attribute__((ext_vector_type(4)));

__device__ __forceinline__ unsigned short f2bf(float f) {
  union { float f; unsigned u; } v; v.f = f;
  unsigned r = (v.u + 0x7fffu + ((v.u >> 16) & 1u)) >> 16;
  return (unsigned short)r;
}

__device__ __forceinline__ float2 bfp2f(unsigned u) {
  union { unsigned u; float f; } lo, hi;
  lo.u = u << 16;
  hi.u = u & 0xffff0000u;
  return make_float2(lo.f, hi.f);
}

__device__ __forceinline__ float bf2f(unsigned short s) {
  union { unsigned u; float f; } v;
  v.u = ((unsigned)s) << 16;
  return v.f;
}

// ---------- x -> bf16 conversion; also zero-inits cnt_cur and g ----------
__global__ __launch_bounds__(256)
void k_x2bf(const float* __restrict__ x, unsigned short* __restrict__ xb,
            int* __restrict__ cnt, float* __restrict__ g) {
  int tid = blockIdx.x * 256 + threadIdx.x;
  size_t i = (size_t)tid * 4;
  if (i < (size_t)N_NODES_C * NODE_DIM_C) {
    float4 v = *(const float4*)&x[i];
    uint2 o;
    o.x = (unsigned)f2bf(v.x) | ((unsigned)f2bf(v.y) << 16);
    o.y = (unsigned)f2bf(v.z) | ((unsigned)f2bf(v.w) << 16);
    *(uint2*)&xb[i] = o;
  }
  if (tid < N_NODES_C) cnt[tid] = 0;
  if (tid < N_GRAPHS_C * HID) g[tid] = 0.f;
}

// ------- weight prep: 6 MLP mats -> wT[m][n*128+k]; node_w -> nwT[n*64+k] ---
__global__ __launch_bounds__(256)
void k_prep_w(const float* __restrict__ w1, const float* __restrict__ w2,
              const float* __restrict__ nodew, unsigned short* __restrict__ wT) {
  int m = blockIdx.x;  // 0..6
  if (m < 6) {
    const float* src = (m < 3) ? (w1 + (size_t)m * HID * HID)
                               : (w2 + (size_t)(m - 3) * HID * HID);
    unsigned short* dst = wT + (size_t)m * HID * HID;
    for (int i = threadIdx.x; i < HID * HID; i += 256) {
      int n = i >> 7, k = i & 127;
      dst[n * HID + k] = f2bf(src[k * HID + n]);
    }
  } else {
    unsigned short* dst = wT + (size_t)6 * HID * HID;  // [128][64]
    for (int i = threadIdx.x; i < HID * NODE_DIM_C; i += 256) {
      int n = i >> 6, k = i & 63;
      dst[n * NODE_DIM_C + k] = f2bf(nodew[k * HID + n]);
    }
  }
}

// ------- node encoder via MFMA: h = bf16(x_bf @ node_w + node_b), K=64 ------
__global__ __launch_bounds__(256)
void k_node_mfma(const unsigned short* __restrict__ xb,
                 const unsigned short* __restrict__ nwT,
                 const float* __restrict__ bias, unsigned short* __restrict__ h) {
  const int LD = NODE_DIM_C + 8;  // 72
  __shared__ unsigned short a_lds[128 * LD];  // 18 KB
  __shared__ unsigned short w_lds[128 * LD];  // 18 KB
  int t = threadIdx.x;
  int row0 = blockIdx.x * 128;
  {
    int r = t >> 3, c = t & 7;
#pragma unroll
    for (int it = 0; it < 4; ++it) {
      int row = it * 32 + r;
      int grow = row0 + row;
      uint4 va = (grow < N_NODES_C)
                     ? ((const uint4*)(xb + (size_t)grow * NODE_DIM_C))[c]
                     : make_uint4(0, 0, 0, 0);
      *(uint4*)&a_lds[row * LD + c * 8] = va;
      uint4 vw = ((const uint4*)(nwT + (size_t)row * NODE_DIM_C))[c];
      *(uint4*)&w_lds[row * LD + c * 8] = vw;
    }
  }
  __syncthreads();

  int lane = t & 63;
  int w = t >> 6;
  int l15 = lane & 15;
  int q = lane >> 4;

  f32x4 acc[2][8];
#pragma unroll
  for (int rt = 0; rt < 2; ++rt)
#pragma unroll
    for (int nt = 0; nt < 8; ++nt) acc[rt][nt] = (f32x4)0.f;

#pragma unroll
  for (int kk = 0; kk < 2; ++kk) {
    int k0 = kk * 32;
    bf16x8 af[2];
#pragma unroll
    for (int rt = 0; rt < 2; ++rt) {
      int arow = w * 32 + rt * 16 + l15;
      af[rt] = *(const bf16x8*)&a_lds[arow * LD + k0 + q * 8];
    }
#pragma unroll
    for (int nt = 0; nt < 8; ++nt) {
      bf16x8 bf = *(const bf16x8*)&w_lds[(nt * 16 + l15) * LD + k0 + q * 8];
#pragma unroll
      for (int rt = 0; rt < 2; ++rt)
        acc[rt][nt] = __builtin_amdgcn_mfma_f32_16x16x32_bf16(af[rt], bf, acc[rt][nt], 0, 0, 0);
    }
  }

#pragma unroll
  for (int nt = 0; nt < 8; ++nt) {
    int gcol = nt * 16 + l15;
    float bv = bias[gcol];
#pragma unroll
    for (int rt = 0; rt < 2; ++rt) {
#pragma unroll
      for (int i = 0; i < 4; ++i) {
        int grow = row0 + w * 32 + rt * 16 + q * 4 + i;
        if (grow < N_NODES_C) h[(size_t)grow * HID + gcol] = f2bf(acc[rt][nt][i] + bv);
      }
    }
  }
}

// ---------------- CSR build (counting sort by dst) ----------------
__global__ __launch_bounds__(256)
void k_histogram(const int* __restrict__ dst, int* __restrict__ counts) {
  int e = blockIdx.x * 256 + threadIdx.x;
  if (e < N_EDGES_C) atomicAdd(&counts[dst[e]], 1);
}

__global__ __launch_bounds__(256)
void k_blocksum(const int* __restrict__ cnt, int* __restrict__ partial) {
  __shared__ int ls[4];
  int t = threadIdx.x;
  int i = blockIdx.x * 256 + t;
  int v = (i < N_NODES_C) ? cnt[i] : 0;
#pragma unroll
  for (int o = 32; o > 0; o >>= 1) v += __shfl_down(v, o, 64);
  if ((t & 63) == 0) ls[t >> 6] = v;
  __syncthreads();
  if (t == 0) partial[blockIdx.x] = ls[0] + ls[1] + ls[2] + ls[3];
}

__global__ __launch_bounds__(256)
void k_scanpartials(const int* __restrict__ partial, int* __restrict__ partial_off) {
  __shared__ int s[256];
  int t = threadIdx.x;
  int v = (t < SCAN_NBLK) ? partial[t] : 0;
  s[t] = v;
  __syncthreads();
  for (int d = 1; d < 256; d <<= 1) {
    int x = (t >= d) ? s[t - d] : 0;
    __syncthreads();
    s[t] += x;
    __syncthreads();
  }
  if (t < SCAN_NBLK) partial_off[t] = s[t] - v;
}

__global__ __launch_bounds__(256)
void k_apply(int* __restrict__ cnt_cursor, const int* __restrict__ partial_off,
             int* __restrict__ row_ptr) {
  __shared__ int s[256];
  int t = threadIdx.x;
  int i = blockIdx.x * 256 + t;
  int v = (i < N_NODES_C) ? cnt_cursor[i] : 0;
  s[t] = v;
  __syncthreads();
  for (int d = 1; d < 256; d <<= 1) {
    int x = (t >= d) ? s[t - d] : 0;
    __syncthreads();
    s[t] += x;
    __syncthreads();
  }
  int excl = s[t] - v + partial_off[blockIdx.x];
  if (i < N_NODES_C) {
    row_ptr[i] = excl;
    cnt_cursor[i] = excl;
  }
  if (i == 0) row_ptr[N_NODES_C] = N_EDGES_C;
}

__global__ __launch_bounds__(256)
void k_bucket(const int* __restrict__ dst, const int* __restrict__ srcArr,
              int* __restrict__ cursor, int* __restrict__ perm,
              int* __restrict__ src_perm) {
  int e = blockIdx.x * 256 + threadIdx.x;
  if (e < N_EDGES_C) {
    int p = atomicAdd(&cursor[dst[e]], 1);
    perm[p] = e;
    src_perm[p] = srcArr[e];
  }
}

// ---- edge encoder via MFMA (layer-invariant, computed once):
// ea[i] = bf16(eattr[perm[i]] @ ew + eb) in CSR edge order.
// Out tile stride 130 shorts (word stride 65, odd) -> epilogue b16 writes and
// b32 copy-out both hit all 32 banks at 2 lanes/bank (free, m136).
#define EE_LDW 40   // A/W row stride (shorts); K padded 16->32 + 8 pad
#define EE_OSW 130
__global__ __launch_bounds__(256)
void k_edge_encode(const int* __restrict__ perm, const float* __restrict__ eattr,
                   const float* __restrict__ ew, const float* __restrict__ ebias,
                   unsigned short* __restrict__ ea16) {
  __shared__ unsigned short smem[128 * EE_OSW];  // 32.5 KB; overlays A,W then OUT
  unsigned short* a_lds = smem;                  // [128][EE_LDW]
  unsigned short* w_lds = smem + 128 * EE_LDW;   // [128][EE_LDW]
  int t = threadIdx.x;
  int EB = blockIdx.x * 128;

  // stage W: one thread per output column n; 2 valid uint4 + 2 zero uint4
  if (t < 128) {
    unsigned short tmp[16];
#pragma unroll
    for (int k = 0; k < 16; ++k) tmp[k] = f2bf(ew[k * HID + t]);
    uint4* wr = (uint4*)&w_lds[t * EE_LDW];  // byte ofs t*80: 16B aligned
    wr[0] = *(uint4*)&tmp[0];
    wr[1] = *(uint4*)&tmp[8];
    wr[2] = make_uint4(0, 0, 0, 0);
    wr[3] = make_uint4(0, 0, 0, 0);
  }
  // stage A: 2 threads per edge, 8 floats -> 1 uint4 + 1 zero uint4
  {
    int edge = t >> 1, half = t & 1;
    int gi = EB + edge;
    float4 v0 = make_float4(0, 0, 0, 0), v1 = v0;
    if (gi < N_EDGES_C) {
      int e = perm[gi];
      const float4* p = (const float4*)(eattr + (size_t)e * EDGE_DIM_C + half * 8);
      v0 = p[0];
      v1 = p[1];
    }
    unsigned short tmp[8] = {f2bf(v0.x), f2bf(v0.y), f2bf(v0.z), f2bf(v0.w),
                             f2bf(v1.x), f2bf(v1.y), f2bf(v1.z), f2bf(v1.w)};
    *(uint4*)&a_lds[edge * EE_LDW + half * 8] = *(uint4*)tmp;
    *(uint4*)&a_lds[edge * EE_LDW + 16 + half * 8] = make_uint4(0, 0, 0, 0);
  }
  __syncthreads();

  int lane = t & 63;
  int w = t >> 6;
  int l15 = lane & 15;
  int q = lane >> 4;

  f32x4 acc[2][8];
  {
    bf16x8 af[2];
#pragma unroll
    for (int rt = 0; rt < 2; ++rt) {
      int arow = w * 32 + rt * 16 + l15;
      af[rt] = *(const bf16x8*)&a_lds[arow * EE_LDW + q * 8];
    }
#pragma unroll
    for (int nt = 0; nt < 8; ++nt) {
      bf16x8 bf = *(const bf16x8*)&w_lds[(nt * 16 + l15) * EE_LDW + q * 8];
#pragma unroll
      for (int rt = 0; rt < 2; ++rt)
        acc[rt][nt] = __builtin_amdgcn_mfma_f32_16x16x32_bf16(
            af[rt], bf, (f32x4)0.f, 0, 0, 0);
    }
  }
  __syncthreads();  // done reading A/W; smem becomes the output tile [128][EE_OSW]

#pragma unroll
  for (int nt = 0; nt < 8; ++nt) {
    int col = nt * 16 + l15;
    float bv = ebias[col];
#pragma unroll
    for (int rt = 0; rt < 2; ++rt) {
#pragma unroll
      for (int i = 0; i < 4; ++i) {
        int row = w * 32 + rt * 16 + q * 4 + i;
        smem[row * EE_OSW + col] = f2bf(acc[rt][nt][i] + bv);
      }
    }
  }
  __syncthreads();

  int valid = min(128, N_EDGES_C - EB);
  for (int i = t; i < valid * 64; i += 256) {
    int row = i >> 6, c = i & 63;
    unsigned v = *(const unsigned*)&smem[row * EE_OSW + c * 2];  // 4B aligned
    *(unsigned*)&ea16[((size_t)EB + row) * HID + c * 2] = v;
  }
}

// -------- aggregate: z[n] = h[n] + sum_{e: dst=n} relu(h[src_e] + ea_e) -----
// block 0 also zero-inits gsum/gsumsq for this layer's stats GEMM
__global__ __launch_bounds__(256)
void k_aggregate(const unsigned* __restrict__ h32, const unsigned* __restrict__ ea,
                 const int* __restrict__ src_p, const int* __restrict__ row_ptr,
                 unsigned short* __restrict__ z, float* __restrict__ gsum,
                 float* __restrict__ gsumsq) {
  int t = threadIdx.x;
  if (blockIdx.x == 0 && t < HID) { gsum[t] = 0.f; gsumsq[t] = 0.f; }
  int lane = t & 63;
  int wave = t >> 6;
  int node = blockIdx.x * 4 + wave;
  if (node >= N_NODES_C) return;
  float2 base = bfp2f(h32[(size_t)node * 64 + lane]);
  float acc0 = base.x, acc1 = base.y;
  int beg = row_ptr[node], end = row_ptr[node + 1];
  int j = beg;
  for (; j + 8 <= end; j += 8) {
    int s0 = src_p[j],     s1 = src_p[j + 1], s2 = src_p[j + 2], s3 = src_p[j + 3];
    int s4 = src_p[j + 4], s5 = src_p[j + 5], s6 = src_p[j + 6], s7 = src_p[j + 7];
    unsigned g0 = h32[(size_t)s0 * 64 + lane];
    unsigned g1 = h32[(size_t)s1 * 64 + lane];
    unsigned g2 = h32[(size_t)s2 * 64 + lane];
    unsigned g3 = h32[(size_t)s3 * 64 + lane];
    unsigned g4 = h32[(size_t)s4 * 64 + lane];
    unsigned g5 = h32[(size_t)s5 * 64 + lane];
    unsigned g6 = h32[(size_t)s6 * 64 + lane];
    unsigned g7 = h32[(size_t)s7 * 64 + lane];
    unsigned u0 = ea[(size_t)j * 64 + lane];
    unsigned u1 = ea[(size_t)(j + 1) * 64 + lane];
    unsigned u2 = ea[(size_t)(j + 2) * 64 + lane];
    unsigned u3 = ea[(size_t)(j + 3) * 64 + lane];
    unsigned u4 = ea[(size_t)(j + 4) * 64 + lane];
    unsigned u5 = ea[(size_t)(j + 5) * 64 + lane];
    unsigned u6 = ea[(size_t)(j + 6) * 64 + lane];
    unsigned u7 = ea[(size_t)(j + 7) * 64 + lane];
    float2 a0 = bfp2f(g0), a1 = bfp2f(g1), a2 = bfp2f(g2), a3 = bfp2f(g3);
    float2 a4 = bfp2f(g4), a5 = bfp2f(g5), a6 = bfp2f(g6), a7 = bfp2f(g7);
    float2 e0 = bfp2f(u0), e1 = bfp2f(u1), e2 = bfp2f(u2), e3 = bfp2f(u3);
    float2 e4 = bfp2f(u4), e5 = bfp2f(u5), e6 = bfp2f(u6), e7 = bfp2f(u7);
    acc0 += fmaxf(a0.x + e0.x, 0.f) + fmaxf(a1.x + e1.x, 0.f) +
            fmaxf(a2.x + e2.x, 0.f) + fmaxf(a3.x + e3.x, 0.f) +
            fmaxf(a4.x + e4.x, 0.f) + fmaxf(a5.x + e5.x, 0.f) +
            fmaxf(a6.x + e6.x, 0.f) + fmaxf(a7.x + e7.x, 0.f);
    acc1 += fmaxf(a0.y + e0.y, 0.f) + fmaxf(a1.y + e1.y, 0.f) +
            fmaxf(a2.y + e2.y, 0.f) + fmaxf(a3.y + e3.y, 0.f) +
            fmaxf(a4.y + e4.y, 0.f) + fmaxf(a5.y + e5.y, 0.f) +
            fmaxf(a6.y + e6.y, 0.f) + fmaxf(a7.y + e7.y, 0.f);
  }
  for (; j + 4 <= end; j += 4) {
    int s0 = src_p[j], s1 = src_p[j + 1], s2 = src_p[j + 2], s3 = src_p[j + 3];
    unsigned g0 = h32[(size_t)s0 * 64 + lane];
    unsigned g1 = h32[(size_t)s1 * 64 + lane];
    unsigned g2 = h32[(size_t)s2 * 64 + lane];
    unsigned g3 = h32[(size_t)s3 * 64 + lane];
    unsigned u0 = ea[(size_t)j * 64 + lane];
    unsigned u1 = ea[(size_t)(j + 1) * 64 + lane];
    unsigned u2 = ea[(size_t)(j + 2) * 64 + lane];
    unsigned u3 = ea[(size_t)(j + 3) * 64 + lane];
    float2 a0 = bfp2f(g0), a1 = bfp2f(g1), a2 = bfp2f(g2), a3 = bfp2f(g3);
    float2 e0 = bfp2f(u0), e1 = bfp2f(u1), e2 = bfp2f(u2), e3 = bfp2f(u3);
    acc0 += fmaxf(a0.x + e0.x, 0.f) + fmaxf(a1.x + e1.x, 0.f) +
            fmaxf(a2.x + e2.x, 0.f) + fmaxf(a3.x + e3.x, 0.f);
    acc1 += fmaxf(a0.y + e0.y, 0.f) + fmaxf(a1.y + e1.y, 0.f) +
            fmaxf(a2.y + e2.y, 0.f) + fmaxf(a3.y + e3.y, 0.f);
  }
  for (; j < end; ++j) {
    int s0 = src_p[j];
    float2 a0 = bfp2f(h32[(size_t)s0 * 64 + lane]);
    float2 e0 = bfp2f(ea[(size_t)j * 64 + lane]);
    acc0 += fmaxf(a0.x + e0.x, 0.f);
    acc1 += fmaxf(a0.y + e0.y, 0.f);
  }
  unsigned packed = (unsigned)f2bf(acc0) | ((unsigned)f2bf(acc1) << 16);
  *(unsigned*)&z[(size_t)node * HID + lane * 2] = packed;
}

// ---------- MFMA GEMM: [50000,128](bf16) @ W^T[128,128](bf16) + bias --------
// output always bf16; STATS adds fused BN column sums/sumsq (fp32, pre-round)
template <bool RELU, bool STATS>
__global__ __launch_bounds__(256)
void k_gemm_mfma(const unsigned short* __restrict__ in,
                 const unsigned short* __restrict__ wT,
                 const float* __restrict__ bias,
                 unsigned short* __restrict__ outb,
                 float* __restrict__ gsum, float* __restrict__ gsumsq) {
  const int LDA = HID + 8;
  __shared__ unsigned short a_lds[128 * LDA];
  __shared__ unsigned short w_lds[128 * LDA];
  int t = threadIdx.x;
  int row0 = blockIdx.x * 128;
  {
    int r = t >> 4, chunk = t & 15;
#pragma unroll
    for (int it = 0; it < 8; ++it) {
      int row = it * 16 + r;
      int grow = row0 + row;
      uint4 va = (grow < N_NODES_C)
                     ? ((const uint4*)(in + (size_t)grow * HID))[chunk]
                     : make_uint4(0, 0, 0, 0);
      *(uint4*)&a_lds[row * LDA + chunk * 8] = va;
      uint4 vw = ((const uint4*)(wT + (size_t)row * HID))[chunk];
      *(uint4*)&w_lds[row * LDA + chunk * 8] = vw;
    }
  }
  __syncthreads();

  int lane = t & 63;
  int w = t >> 6;
  int l15 = lane & 15;
  int q = lane >> 4;

  f32x4 acc[2][8];
#pragma unroll
  for (int rt = 0; rt < 2; ++rt)
#pragma unroll
    for (int nt = 0; nt < 8; ++nt) acc[rt][nt] = (f32x4)0.f;

#pragma unroll
  for (int kk = 0; kk < 4; ++kk) {
    int k0 = kk * 32;
    bf16x8 af[2];
#pragma unroll
    for (int rt = 0; rt < 2; ++rt) {
      int arow = w * 32 + rt * 16 + l15;
      af[rt] = *(const bf16x8*)&a_lds[arow * LDA + k0 + q * 8];
    }
#pragma unroll
    for (int nt = 0; nt < 8; ++nt) {
      int brow = nt * 16 + l15;
      bf16x8 bf = *(const bf16x8*)&w_lds[brow * LDA + k0 + q * 8];
#pragma unroll
      for (int rt = 0; rt < 2; ++rt)
        acc[rt][nt] = __builtin_amdgcn_mfma_f32_16x16x32_bf16(af[rt], bf, acc[rt][nt], 0, 0, 0);
    }
  }

  float sp[8], qp[8];
#pragma unroll
  for (int nt = 0; nt < 8; ++nt) { sp[nt] = 0.f; qp[nt] = 0.f; }

#pragma unroll
  for (int nt = 0; nt < 8; ++nt) {
    int gcol = nt * 16 + l15;
    float bv = bias[gcol];
#pragma unroll
    for (int rt = 0; rt < 2; ++rt) {
#pragma unroll
      for (int i = 0; i < 4; ++i) {
        int grow = row0 + w * 32 + rt * 16 + q * 4 + i;
        bool ok = (grow < N_NODES_C);
        float v = acc[rt][nt][i] + bv;
        if (RELU) v = fmaxf(v, 0.f);
        if (ok) outb[(size_t)grow * HID + gcol] = f2bf(v);
        if (STATS) {
          float c = ok ? v : 0.f;
          sp[nt] += c;
          qp[nt] += c * c;
        }
      }
    }
  }

  if (STATS) {
    __syncthreads();
    float* sred = (float*)a_lds;        // [128][16]
    float* qred = sred + 128 * 16;
    int slot = w * 4 + q;
#pragma unroll
    for (int nt = 0; nt < 8; ++nt) {
      int gcol = nt * 16 + l15;
      sred[gcol * 16 + slot] = sp[nt];
      qred[gcol * 16 + slot] = qp[nt];
    }
    __syncthreads();
    if (t < 128) {
      float s = 0.f;
#pragma unroll
      for (int i = 0; i < 16; ++i) s += sred[t * 16 + i];
      atomicAdd(&gsum[t], s);
    } else {
      int f = t - 128;
      float s = 0.f;
#pragma unroll
      for (int i = 0; i < 16; ++i) s += qred[f * 16 + i];
      atomicAdd(&gsumsq[f], s);
    }
  }
}

__global__ void k_bn_finalize(const float* __restrict__ gsum, const float* __restrict__ gsumsq,
                              const float* __restrict__ gamma, const float* __restrict__ beta,
                              float* __restrict__ scale, float* __restrict__ shift) {
  int f = threadIdx.x;  // 128
  float mean = gsum[f] * (1.f / N_NODES_C);
  float var = gsumsq[f] * (1.f / N_NODES_C) - mean * mean;
  float inv = rsqrtf(var + BN_EPS_C);
  float sc = gamma[f] * inv;
  scale[f] = sc;
  shift[f] = beta[f] - mean * sc;
}

// BN + relu: reads t2 bf16 (8 elems/thread), writes h bf16 (layers 0,1)
__global__ __launch_bounds__(256)
void k_bn_relu(const unsigned short* __restrict__ t2, const float* __restrict__ scale,
               const float* __restrict__ shift, unsigned short* __restrict__ h) {
  __shared__ float sc[HID], sh[HID];
  int t = threadIdx.x;
  if (t < HID) { sc[t] = scale[t]; sh[t] = shift[t]; }
  __syncthreads();
  size_t idx = ((size_t)blockIdx.x * 256 + t) * 8;
  if (idx < (size_t)N_NODES_C * HID) {
    uint4 v = *(const uint4*)&t2[idx];
    int f = (int)(idx & 127);
    float2 p0 = bfp2f(v.x), p1 = bfp2f(v.y), p2 = bfp2f(v.z), p3 = bfp2f(v.w);
    float r0 = fmaxf(p0.x * sc[f + 0] + sh[f + 0], 0.f);
    float r1 = fmaxf(p0.y * sc[f + 1] + sh[f + 1], 0.f);
    float r2 = fmaxf(p1.x * sc[f + 2] + sh[f + 2], 0.f);
    float r3 = fmaxf(p1.y * sc[f + 3] + sh[f + 3], 0.f);
    float r4 = fmaxf(p2.x * sc[f + 4] + sh[f + 4], 0.f);
    float r5 = fmaxf(p2.y * sc[f + 5] + sh[f + 5], 0.f);
    float r6 = fmaxf(p3.x * sc[f + 6] + sh[f + 6], 0.f);
    float r7 = fmaxf(p3.y * sc[f + 7] + sh[f + 7], 0.f);
    uint4 o;
    o.x = (unsigned)f2bf(r0) | ((unsigned)f2bf(r1) << 16);
    o.y = (unsigned)f2bf(r2) | ((unsigned)f2bf(r3) << 16);
    o.z = (unsigned)f2bf(r4) | ((unsigned)f2bf(r5) << 16);
    o.w = (unsigned)f2bf(r6) | ((unsigned)f2bf(r7) << 16);
    *(uint4*)&h[idx] = o;
  }
}

// BN + relu + global_add_pool fused (last layer; h never materialized)
__global__ __launch_bounds__(128)
void k_bn_relu_pool(const unsigned short* __restrict__ t2, const float* __restrict__ scale,
                    const float* __restrict__ shift, const int* __restrict__ batch,
                    float* __restrict__ g) {
  int t = threadIdx.x;
  float sc = scale[t], sh = shift[t];
  int n0 = blockIdx.x * 64;
  if (n0 >= N_NODES_C) return;
  int end = min(n0 + 64, N_NODES_C);
  int cur = batch[n0];
  float acc = 0.f;
  for (int n = n0; n < end; ++n) {
    int b = batch[n];
    if (b != cur) {
      atomicAdd(&g[cur * HID + t], acc);
      acc = 0.f;
      cur = b;
    }
    acc += fmaxf(bf2f(t2[(size_t)n * HID + t]) * sc + sh, 0.f);
  }
  atomicAdd(&g[cur * HID + t], acc);
}

// ---------------- head: relu(g@w1+b1)@w2+b2 ----------------
__global__ __launch_bounds__(128)
void k_head(const float* __restrict__ g, const float* __restrict__ w1,
            const float* __restrict__ b1, const float* __restrict__ w2,
            const float* __restrict__ b2, float* __restrict__ out) {
  __shared__ float gs[HID];
  __shared__ float red[HID * 2];
  int gi = blockIdx.x, t = threadIdx.x;
  gs[t] = g[gi * HID + t];
  __syncthreads();
  float acc = b1[t];
#pragma unroll 8
  for (int k = 0; k < HID; ++k) acc += gs[k] * w1[k * HID + t];
  float hid = fmaxf(acc, 0.f);
  red[t * 2] = hid * w2[t * 2];
  red[t * 2 + 1] = hid * w2[t * 2 + 1];
  __syncthreads();
  for (int s = 64; s > 0; s >>= 1) {
    if (t < s) { red[t * 2] += red[(t + s) * 2]; red[t * 2 + 1] += red[(t + s) * 2 + 1]; }
    __syncthreads();
  }
  if (t == 0) {
    out[gi * 2] = red[0] + b2[0];
    out[gi * 2 + 1] = red[1] + b2[1];
  }
}

extern "C" void kernel_launch(void* const* d_in, const int* in_sizes, int n_in,
                              void* d_out, int out_size, void* d_ws, size_t ws_size,
                              hipStream_t stream) {
  const float* x      = (const float*)d_in[0];
  const int*   eidx   = (const int*)d_in[1];
  const float* eattr  = (const float*)d_in[2];
  const int*   batch  = (const int*)d_in[3];
  const float* node_w = (const float*)d_in[4];
  const float* node_b = (const float*)d_in[5];
  const float* edge_w = (const float*)d_in[6];
  const float* edge_b = (const float*)d_in[7];
  const float* mlp_w1 = (const float*)d_in[8];
  const float* mlp_b1 = (const float*)d_in[9];
  const float* mlp_w2 = (const float*)d_in[10];
  const float* mlp_b2 = (const float*)d_in[11];
  const float* bn_g   = (const float*)d_in[12];
  const float* bn_b   = (const float*)d_in[13];
  const float* hw1    = (const float*)d_in[14];
  const float* hb1    = (const float*)d_in[15];
  const float* hw2    = (const float*)d_in[16];
  const float* hb2    = (const float*)d_in[17];
  const int* srcArr = eidx;
  const int* dstArr = eidx + N_EDGES_C;

  char* wsp = (char*)d_ws;
  size_t off = 0;
  auto alloc = [&](size_t bytes) {
    void* p = wsp + off;
    off += (bytes + 255) & ~(size_t)255;
    return p;
  };
  unsigned short* h    = (unsigned short*)alloc((size_t)N_NODES_C * HID * 2);   // 12.8 MB
  unsigned short* zbf  = (unsigned short*)alloc((size_t)N_NODES_C * HID * 2);   // 12.8 MB
  unsigned short* t1bf = (unsigned short*)alloc((size_t)N_NODES_C * HID * 2);   // 12.8 MB
  unsigned short* t2bf = (unsigned short*)alloc((size_t)N_NODES_C * HID * 2);   // 12.8 MB
  unsigned short* ea16 = (unsigned short*)alloc((size_t)N_EDGES_C * HID * 2);   // 153.6 MB
  unsigned short* xb   = (unsigned short*)alloc((size_t)N_NODES_C * NODE_DIM_C * 2);  // 6.4 MB
  unsigned short* wT   = (unsigned short*)alloc(((size_t)6 * HID * HID + HID * NODE_DIM_C) * 2);
  int* row_ptr   = (int*)alloc((N_NODES_C + 1) * 4);
  int* cnt_cur   = (int*)alloc(N_NODES_C * 4);
  int* perm      = (int*)alloc((size_t)N_EDGES_C * 4);
  int* src_perm  = (int*)alloc((size_t)N_EDGES_C * 4);
  int* partial   = (int*)alloc(256 * 4);
  int* partial_off = (int*)alloc(256 * 4);
  float* gsum    = (float*)alloc(HID * 4);
  float* gsumsq  = (float*)alloc(HID * 4);
  float* scale   = (float*)alloc(HID * 4);
  float* shift   = (float*)alloc(HID * 4);
  float* g       = (float*)alloc((size_t)N_GRAPHS_C * HID * 4);
  unsigned short* nwT = wT + (size_t)6 * HID * HID;

  k_x2bf<<<(N_NODES_C * NODE_DIM_C / 4 + 255) / 256, 256, 0, stream>>>(x, xb,
                                                                       cnt_cur, g);
  k_prep_w<<<7, 256, 0, stream>>>(mlp_w1, mlp_w2, node_w, wT);
  k_node_mfma<<<(N_NODES_C + 127) / 128, 256, 0, stream>>>(xb, nwT, node_b, h);
  k_histogram<<<(N_EDGES_C + 255) / 256, 256, 0, stream>>>(dstArr, cnt_cur);
  k_blocksum<<<SCAN_NBLK, 256, 0, stream>>>(cnt_cur, partial);
  k_scanpartials<<<1, 256, 0, stream>>>(partial, partial_off);
  k_apply<<<SCAN_NBLK, 256, 0, stream>>>(cnt_cur, partial_off, row_ptr);
  k_bucket<<<(N_EDGES_C + 255) / 256, 256, 0, stream>>>(dstArr, srcArr, cnt_cur,
                                                        perm, src_perm);
  k_edge_encode<<<(N_EDGES_C + 127) / 128, 256, 0, stream>>>(perm, eattr, edge_w,
                                                             edge_b, ea16);

  const int GB = (N_NODES_C + 127) / 128;  // 391
  for (int l = 0; l < 3; ++l) {
    k_aggregate<<<(N_NODES_C + 3) / 4, 256, 0, stream>>>((const unsigned*)h,
                                                         (const unsigned*)ea16,
                                                         src_perm, row_ptr, zbf,
                                                         gsum, gsumsq);
    k_gemm_mfma<true, false><<<GB, 256, 0, stream>>>(
        zbf, wT + (size_t)l * HID * HID, mlp_b1 + l * HID, t1bf, nullptr, nullptr);
    k_gemm_mfma<false, true><<<GB, 256, 0, stream>>>(
        t1bf, wT + (size_t)(3 + l) * HID * HID, mlp_b2 + l * HID, t2bf,
        gsum, gsumsq);
    k_bn_finalize<<<1, HID, 0, stream>>>(gsum, gsumsq, bn_g + l * HID, bn_b + l * HID,
                                         scale, shift);
    if (l < 2) {
      k_bn_relu<<<(N_NODES_C * HID / 8 + 255) / 256, 256, 0, stream>>>(t2bf, scale,
                                                                       shift, h);
    } else {
      k_bn_relu_pool<<<(N_NODES_C + 63) / 64, 128, 0, stream>>>(t2bf, scale, shift,
                                                                batch, g);
    }
  }
  k_head<<<N_GRAPHS_C, 128, 0, stream>>>(g, hw1, hb1, hw2, hb2, (float*)d_out);
}

// Round 10
// 517.129 us; speedup vs baseline: 2.3770x; 1.0984x over previous
//
#include <hip/hip_runtime.h>

#define N_NODES_C 50000
#define N_EDGES_C 600000
#define NODE_DIM_C 64
#define EDGE_DIM_C 16
#define HID 128
#define N_GRAPHS_C 256
#define BN_EPS_C 1e-5f
#define SCAN_NBLK ((N_NODES_C + 255) / 256)  // 196

typedef short bf16x8 __attribute__((ext_vector_type(8)));
typedef float f32x4 __attribute__((ext_vector_type(4)));
typedef float f32x2 __attribute__((ext_vector_type(2)));

__device__ __forceinline__ unsigned short f2bf(float f) {
  union { float f; unsigned u; } v; v.f = f;
  unsigned r = (v.u + 0x7fffu + ((v.u >> 16) & 1u)) >> 16;
  return (unsigned short)r;
}

__device__ __forceinline__ float2 bfp2f(unsigned u) {
  union { unsigned u; float f; } lo, hi;
  lo.u = u << 16;
  hi.u = u & 0xffff0000u;
  return make_float2(lo.f, hi.f);
}

__device__ __forceinline__ float bf2f(unsigned short s) {
  union { unsigned u; float f; } v;
  v.u = ((unsigned)s) << 16;
  return v.f;
}

// 2 fp8 (e4m3, HW) packed in low 16 bits -> 2 floats
__device__ __forceinline__ float2 fp8p2f(unsigned short u) {
  f32x2 r = __builtin_amdgcn_cvt_pk_f32_fp8((int)(unsigned)u, false);
  return make_float2(r.x, r.y);
}

// ---------- x -> bf16 conversion; also zero-inits cnt_cur and g ----------
__global__ __launch_bounds__(256)
void k_x2bf(const float* __restrict__ x, unsigned short* __restrict__ xb,
            int* __restrict__ cnt, float* __restrict__ g) {
  int tid = blockIdx.x * 256 + threadIdx.x;
  size_t i = (size_t)tid * 4;
  if (i < (size_t)N_NODES_C * NODE_DIM_C) {
    float4 v = *(const float4*)&x[i];
    uint2 o;
    o.x = (unsigned)f2bf(v.x) | ((unsigned)f2bf(v.y) << 16);
    o.y = (unsigned)f2bf(v.z) | ((unsigned)f2bf(v.w) << 16);
    *(uint2*)&xb[i] = o;
  }
  if (tid < N_NODES_C) cnt[tid] = 0;
  if (tid < N_GRAPHS_C * HID) g[tid] = 0.f;
}

// ------- weight prep: 6 MLP mats -> wT[m][n*128+k]; node_w -> nwT[n*64+k] ---
__global__ __launch_bounds__(256)
void k_prep_w(const float* __restrict__ w1, const float* __restrict__ w2,
              const float* __restrict__ nodew, unsigned short* __restrict__ wT) {
  int m = blockIdx.x;  // 0..6
  if (m < 6) {
    const float* src = (m < 3) ? (w1 + (size_t)m * HID * HID)
                               : (w2 + (size_t)(m - 3) * HID * HID);
    unsigned short* dst = wT + (size_t)m * HID * HID;
    for (int i = threadIdx.x; i < HID * HID; i += 256) {
      int n = i >> 7, k = i & 127;
      dst[n * HID + k] = f2bf(src[k * HID + n]);
    }
  } else {
    unsigned short* dst = wT + (size_t)6 * HID * HID;  // [128][64]
    for (int i = threadIdx.x; i < HID * NODE_DIM_C; i += 256) {
      int n = i >> 6, k = i & 63;
      dst[n * NODE_DIM_C + k] = f2bf(nodew[k * HID + n]);
    }
  }
}

// ------- node encoder via MFMA: h = bf16(x_bf @ node_w + node_b), K=64 ------
__global__ __launch_bounds__(256)
void k_node_mfma(const unsigned short* __restrict__ xb,
                 const unsigned short* __restrict__ nwT,
                 const float* __restrict__ bias, unsigned short* __restrict__ h) {
  const int LD = NODE_DIM_C + 8;  // 72
  __shared__ unsigned short a_lds[128 * LD];  // 18 KB
  __shared__ unsigned short w_lds[128 * LD];  // 18 KB
  int t = threadIdx.x;
  int row0 = blockIdx.x * 128;
  {
    int r = t >> 3, c = t & 7;
#pragma unroll
    for (int it = 0; it < 4; ++it) {
      int row = it * 32 + r;
      int grow = row0 + row;
      uint4 va = (grow < N_NODES_C)
                     ? ((const uint4*)(xb + (size_t)grow * NODE_DIM_C))[c]
                     : make_uint4(0, 0, 0, 0);
      *(uint4*)&a_lds[row * LD + c * 8] = va;
      uint4 vw = ((const uint4*)(nwT + (size_t)row * NODE_DIM_C))[c];
      *(uint4*)&w_lds[row * LD + c * 8] = vw;
    }
  }
  __syncthreads();

  int lane = t & 63;
  int w = t >> 6;
  int l15 = lane & 15;
  int q = lane >> 4;

  f32x4 acc[2][8];
#pragma unroll
  for (int rt = 0; rt < 2; ++rt)
#pragma unroll
    for (int nt = 0; nt < 8; ++nt) acc[rt][nt] = (f32x4)0.f;

#pragma unroll
  for (int kk = 0; kk < 2; ++kk) {
    int k0 = kk * 32;
    bf16x8 af[2];
#pragma unroll
    for (int rt = 0; rt < 2; ++rt) {
      int arow = w * 32 + rt * 16 + l15;
      af[rt] = *(const bf16x8*)&a_lds[arow * LD + k0 + q * 8];
    }
#pragma unroll
    for (int nt = 0; nt < 8; ++nt) {
      bf16x8 bf = *(const bf16x8*)&w_lds[(nt * 16 + l15) * LD + k0 + q * 8];
#pragma unroll
      for (int rt = 0; rt < 2; ++rt)
        acc[rt][nt] = __builtin_amdgcn_mfma_f32_16x16x32_bf16(af[rt], bf, acc[rt][nt], 0, 0, 0);
    }
  }

#pragma unroll
  for (int nt = 0; nt < 8; ++nt) {
    int gcol = nt * 16 + l15;
    float bv = bias[gcol];
#pragma unroll
    for (int rt = 0; rt < 2; ++rt) {
#pragma unroll
      for (int i = 0; i < 4; ++i) {
        int grow = row0 + w * 32 + rt * 16 + q * 4 + i;
        if (grow < N_NODES_C) h[(size_t)grow * HID + gcol] = f2bf(acc[rt][nt][i] + bv);
      }
    }
  }
}

// ---------------- CSR build (counting sort by dst) ----------------
__global__ __launch_bounds__(256)
void k_histogram(const int* __restrict__ dst, int* __restrict__ counts) {
  int e = blockIdx.x * 256 + threadIdx.x;
  if (e < N_EDGES_C) atomicAdd(&counts[dst[e]], 1);
}

__global__ __launch_bounds__(256)
void k_blocksum(const int* __restrict__ cnt, int* __restrict__ partial) {
  __shared__ int ls[4];
  int t = threadIdx.x;
  int i = blockIdx.x * 256 + t;
  int v = (i < N_NODES_C) ? cnt[i] : 0;
#pragma unroll
  for (int o = 32; o > 0; o >>= 1) v += __shfl_down(v, o, 64);
  if ((t & 63) == 0) ls[t >> 6] = v;
  __syncthreads();
  if (t == 0) partial[blockIdx.x] = ls[0] + ls[1] + ls[2] + ls[3];
}

__global__ __launch_bounds__(256)
void k_scanpartials(const int* __restrict__ partial, int* __restrict__ partial_off) {
  __shared__ int s[256];
  int t = threadIdx.x;
  int v = (t < SCAN_NBLK) ? partial[t] : 0;
  s[t] = v;
  __syncthreads();
  for (int d = 1; d < 256; d <<= 1) {
    int x = (t >= d) ? s[t - d] : 0;
    __syncthreads();
    s[t] += x;
    __syncthreads();
  }
  if (t < SCAN_NBLK) partial_off[t] = s[t] - v;
}

__global__ __launch_bounds__(256)
void k_apply(int* __restrict__ cnt_cursor, const int* __restrict__ partial_off,
             int* __restrict__ row_ptr) {
  __shared__ int s[256];
  int t = threadIdx.x;
  int i = blockIdx.x * 256 + t;
  int v = (i < N_NODES_C) ? cnt_cursor[i] : 0;
  s[t] = v;
  __syncthreads();
  for (int d = 1; d < 256; d <<= 1) {
    int x = (t >= d) ? s[t - d] : 0;
    __syncthreads();
    s[t] += x;
    __syncthreads();
  }
  int excl = s[t] - v + partial_off[blockIdx.x];
  if (i < N_NODES_C) {
    row_ptr[i] = excl;
    cnt_cursor[i] = excl;
  }
  if (i == 0) row_ptr[N_NODES_C] = N_EDGES_C;
}

__global__ __launch_bounds__(256)
void k_bucket(const int* __restrict__ dst, const int* __restrict__ srcArr,
              int* __restrict__ cursor, int* __restrict__ perm,
              int* __restrict__ src_perm) {
  int e = blockIdx.x * 256 + threadIdx.x;
  if (e < N_EDGES_C) {
    int p = atomicAdd(&cursor[dst[e]], 1);
    perm[p] = e;
    src_perm[p] = srcArr[e];
  }
}

// ---- edge encoder via MFMA (layer-invariant, computed once):
// ea8[i] = fp8(eattr[perm[i]] @ ew + eb) in CSR edge order.
// bf16 LDS tile with stride 132 (round-8 proven: epilogue conflict-free);
// copy-out converts bf16 -> fp8 (HW cvt_pk) and writes 4B/thread.
#define EE_LDW 40   // A/W row stride (shorts)
#define EE_OSW 132  // out tile row stride (shorts): epilogue banks (8q+l15/2), free
__global__ __launch_bounds__(256)
void k_edge_encode(const int* __restrict__ perm, const float* __restrict__ eattr,
                   const float* __restrict__ ew, const float* __restrict__ ebias,
                   unsigned char* __restrict__ ea8) {
  __shared__ unsigned short smem[128 * EE_OSW];  // 33 KB; overlays A,W then OUT
  unsigned short* a_lds = smem;                  // [128][EE_LDW]
  unsigned short* w_lds = smem + 128 * EE_LDW;   // [128][EE_LDW]
  int t = threadIdx.x;
  int EB = blockIdx.x * 128;

  // stage W: one thread per output column n; 2 valid uint4 + 2 zero uint4
  if (t < 128) {
    unsigned short tmp[16];
#pragma unroll
    for (int k = 0; k < 16; ++k) tmp[k] = f2bf(ew[k * HID + t]);
    uint4* wr = (uint4*)&w_lds[t * EE_LDW];
    wr[0] = *(uint4*)&tmp[0];
    wr[1] = *(uint4*)&tmp[8];
    wr[2] = make_uint4(0, 0, 0, 0);
    wr[3] = make_uint4(0, 0, 0, 0);
  }
  // stage A: 2 threads per edge, 8 floats -> 1 uint4 + 1 zero uint4
  {
    int edge = t >> 1, half = t & 1;
    int gi = EB + edge;
    float4 v0 = make_float4(0, 0, 0, 0), v1 = v0;
    if (gi < N_EDGES_C) {
      int e = perm[gi];
      const float4* p = (const float4*)(eattr + (size_t)e * EDGE_DIM_C + half * 8);
      v0 = p[0];
      v1 = p[1];
    }
    unsigned short tmp[8] = {f2bf(v0.x), f2bf(v0.y), f2bf(v0.z), f2bf(v0.w),
                             f2bf(v1.x), f2bf(v1.y), f2bf(v1.z), f2bf(v1.w)};
    *(uint4*)&a_lds[edge * EE_LDW + half * 8] = *(uint4*)tmp;
    *(uint4*)&a_lds[edge * EE_LDW + 16 + half * 8] = make_uint4(0, 0, 0, 0);
  }
  __syncthreads();

  int lane = t & 63;
  int w = t >> 6;
  int l15 = lane & 15;
  int q = lane >> 4;

  f32x4 acc[2][8];
  {
    bf16x8 af[2];
#pragma unroll
    for (int rt = 0; rt < 2; ++rt) {
      int arow = w * 32 + rt * 16 + l15;
      af[rt] = *(const bf16x8*)&a_lds[arow * EE_LDW + q * 8];
    }
#pragma unroll
    for (int nt = 0; nt < 8; ++nt) {
      bf16x8 bf = *(const bf16x8*)&w_lds[(nt * 16 + l15) * EE_LDW + q * 8];
#pragma unroll
      for (int rt = 0; rt < 2; ++rt)
        acc[rt][nt] = __builtin_amdgcn_mfma_f32_16x16x32_bf16(
            af[rt], bf, (f32x4)0.f, 0, 0, 0);
    }
  }
  __syncthreads();  // smem becomes the output tile [128][EE_OSW]

#pragma unroll
  for (int nt = 0; nt < 8; ++nt) {
    int col = nt * 16 + l15;
    float bv = ebias[col];
#pragma unroll
    for (int rt = 0; rt < 2; ++rt) {
#pragma unroll
      for (int i = 0; i < 4; ++i) {
        int row = w * 32 + rt * 16 + q * 4 + i;
        smem[row * EE_OSW + col] = f2bf(acc[rt][nt][i] + bv);
      }
    }
  }
  __syncthreads();

  int valid = min(128, N_EDGES_C - EB);
  for (int i = t; i < valid * 32; i += 256) {
    int row = i >> 5, c = i & 31;
    uint2 v = *(const uint2*)&smem[row * EE_OSW + c * 4];  // 264B row stride: 8B-aligned
    float2 p0 = bfp2f(v.x);
    float2 p1 = bfp2f(v.y);
    int r = __builtin_amdgcn_cvt_pk_fp8_f32(p0.x, p0.y, 0, false);
    r = __builtin_amdgcn_cvt_pk_fp8_f32(p1.x, p1.y, r, true);
    *(unsigned*)&ea8[((size_t)EB + row) * 128 + c * 4] = (unsigned)r;
  }
}

// -------- aggregate: z[n] = h[n] + sum_{e: dst=n} relu(h[src_e] + ea_e) -----
// h bf16, ea fp8 (HW cvt decode); block 0 zero-inits gsum/gsumsq
__global__ __launch_bounds__(256)
void k_aggregate(const unsigned* __restrict__ h32, const unsigned char* __restrict__ ea8,
                 const int* __restrict__ src_p, const int* __restrict__ row_ptr,
                 unsigned short* __restrict__ z, float* __restrict__ gsum,
                 float* __restrict__ gsumsq) {
  int t = threadIdx.x;
  if (blockIdx.x == 0 && t < HID) { gsum[t] = 0.f; gsumsq[t] = 0.f; }
  int lane = t & 63;
  int wave = t >> 6;
  int node = blockIdx.x * 4 + wave;
  if (node >= N_NODES_C) return;
  float2 base = bfp2f(h32[(size_t)node * 64 + lane]);
  float acc0 = base.x, acc1 = base.y;
  int beg = row_ptr[node], end = row_ptr[node + 1];
  const unsigned char* eap = ea8 + lane * 2;
  int j = beg;
  for (; j + 8 <= end; j += 8) {
    int s0 = src_p[j],     s1 = src_p[j + 1], s2 = src_p[j + 2], s3 = src_p[j + 3];
    int s4 = src_p[j + 4], s5 = src_p[j + 5], s6 = src_p[j + 6], s7 = src_p[j + 7];
    unsigned g0 = h32[(size_t)s0 * 64 + lane];
    unsigned g1 = h32[(size_t)s1 * 64 + lane];
    unsigned g2 = h32[(size_t)s2 * 64 + lane];
    unsigned g3 = h32[(size_t)s3 * 64 + lane];
    unsigned g4 = h32[(size_t)s4 * 64 + lane];
    unsigned g5 = h32[(size_t)s5 * 64 + lane];
    unsigned g6 = h32[(size_t)s6 * 64 + lane];
    unsigned g7 = h32[(size_t)s7 * 64 + lane];
    unsigned short u0 = *(const unsigned short*)(eap + (size_t)j * 128);
    unsigned short u1 = *(const unsigned short*)(eap + (size_t)(j + 1) * 128);
    unsigned short u2 = *(const unsigned short*)(eap + (size_t)(j + 2) * 128);
    unsigned short u3 = *(const unsigned short*)(eap + (size_t)(j + 3) * 128);
    unsigned short u4 = *(const unsigned short*)(eap + (size_t)(j + 4) * 128);
    unsigned short u5 = *(const unsigned short*)(eap + (size_t)(j + 5) * 128);
    unsigned short u6 = *(const unsigned short*)(eap + (size_t)(j + 6) * 128);
    unsigned short u7 = *(const unsigned short*)(eap + (size_t)(j + 7) * 128);
    float2 a0 = bfp2f(g0), a1 = bfp2f(g1), a2 = bfp2f(g2), a3 = bfp2f(g3);
    float2 a4 = bfp2f(g4), a5 = bfp2f(g5), a6 = bfp2f(g6), a7 = bfp2f(g7);
    float2 e0 = fp8p2f(u0), e1 = fp8p2f(u1), e2 = fp8p2f(u2), e3 = fp8p2f(u3);
    float2 e4 = fp8p2f(u4), e5 = fp8p2f(u5), e6 = fp8p2f(u6), e7 = fp8p2f(u7);
    acc0 += fmaxf(a0.x + e0.x, 0.f) + fmaxf(a1.x + e1.x, 0.f) +
            fmaxf(a2.x + e2.x, 0.f) + fmaxf(a3.x + e3.x, 0.f) +
            fmaxf(a4.x + e4.x, 0.f) + fmaxf(a5.x + e5.x, 0.f) +
            fmaxf(a6.x + e6.x, 0.f) + fmaxf(a7.x + e7.x, 0.f);
    acc1 += fmaxf(a0.y + e0.y, 0.f) + fmaxf(a1.y + e1.y, 0.f) +
            fmaxf(a2.y + e2.y, 0.f) + fmaxf(a3.y + e3.y, 0.f) +
            fmaxf(a4.y + e4.y, 0.f) + fmaxf(a5.y + e5.y, 0.f) +
            fmaxf(a6.y + e6.y, 0.f) + fmaxf(a7.y + e7.y, 0.f);
  }
  for (; j + 4 <= end; j += 4) {
    int s0 = src_p[j], s1 = src_p[j + 1], s2 = src_p[j + 2], s3 = src_p[j + 3];
    unsigned g0 = h32[(size_t)s0 * 64 + lane];
    unsigned g1 = h32[(size_t)s1 * 64 + lane];
    unsigned g2 = h32[(size_t)s2 * 64 + lane];
    unsigned g3 = h32[(size_t)s3 * 64 + lane];
    unsigned short u0 = *(const unsigned short*)(eap + (size_t)j * 128);
    unsigned short u1 = *(const unsigned short*)(eap + (size_t)(j + 1) * 128);
    unsigned short u2 = *(const unsigned short*)(eap + (size_t)(j + 2) * 128);
    unsigned short u3 = *(const unsigned short*)(eap + (size_t)(j + 3) * 128);
    float2 a0 = bfp2f(g0), a1 = bfp2f(g1), a2 = bfp2f(g2), a3 = bfp2f(g3);
    float2 e0 = fp8p2f(u0), e1 = fp8p2f(u1), e2 = fp8p2f(u2), e3 = fp8p2f(u3);
    acc0 += fmaxf(a0.x + e0.x, 0.f) + fmaxf(a1.x + e1.x, 0.f) +
            fmaxf(a2.x + e2.x, 0.f) + fmaxf(a3.x + e3.x, 0.f);
    acc1 += fmaxf(a0.y + e0.y, 0.f) + fmaxf(a1.y + e1.y, 0.f) +
            fmaxf(a2.y + e2.y, 0.f) + fmaxf(a3.y + e3.y, 0.f);
  }
  for (; j < end; ++j) {
    int s0 = src_p[j];
    float2 a0 = bfp2f(h32[(size_t)s0 * 64 + lane]);
    float2 e0 = fp8p2f(*(const unsigned short*)(eap + (size_t)j * 128));
    acc0 += fmaxf(a0.x + e0.x, 0.f);
    acc1 += fmaxf(a0.y + e0.y, 0.f);
  }
  unsigned packed = (unsigned)f2bf(acc0) | ((unsigned)f2bf(acc1) << 16);
  *(unsigned*)&z[(size_t)node * HID + lane * 2] = packed;
}

// ---------- MFMA GEMM: [50000,128](bf16) @ W^T[128,128](bf16) + bias --------
template <bool RELU, bool STATS>
__global__ __launch_bounds__(256)
void k_gemm_mfma(const unsigned short* __restrict__ in,
                 const unsigned short* __restrict__ wT,
                 const float* __restrict__ bias,
                 unsigned short* __restrict__ outb,
                 float* __restrict__ gsum, float* __restrict__ gsumsq) {
  const int LDA = HID + 8;
  __shared__ unsigned short a_lds[128 * LDA];
  __shared__ unsigned short w_lds[128 * LDA];
  int t = threadIdx.x;
  int row0 = blockIdx.x * 128;
  {
    int r = t >> 4, chunk = t & 15;
#pragma unroll
    for (int it = 0; it < 8; ++it) {
      int row = it * 16 + r;
      int grow = row0 + row;
      uint4 va = (grow < N_NODES_C)
                     ? ((const uint4*)(in + (size_t)grow * HID))[chunk]
                     : make_uint4(0, 0, 0, 0);
      *(uint4*)&a_lds[row * LDA + chunk * 8] = va;
      uint4 vw = ((const uint4*)(wT + (size_t)row * HID))[chunk];
      *(uint4*)&w_lds[row * LDA + chunk * 8] = vw;
    }
  }
  __syncthreads();

  int lane = t & 63;
  int w = t >> 6;
  int l15 = lane & 15;
  int q = lane >> 4;

  f32x4 acc[2][8];
#pragma unroll
  for (int rt = 0; rt < 2; ++rt)
#pragma unroll
    for (int nt = 0; nt < 8; ++nt) acc[rt][nt] = (f32x4)0.f;

#pragma unroll
  for (int kk = 0; kk < 4; ++kk) {
    int k0 = kk * 32;
    bf16x8 af[2];
#pragma unroll
    for (int rt = 0; rt < 2; ++rt) {
      int arow = w * 32 + rt * 16 + l15;
      af[rt] = *(const bf16x8*)&a_lds[arow * LDA + k0 + q * 8];
    }
#pragma unroll
    for (int nt = 0; nt < 8; ++nt) {
      int brow = nt * 16 + l15;
      bf16x8 bf = *(const bf16x8*)&w_lds[brow * LDA + k0 + q * 8];
#pragma unroll
      for (int rt = 0; rt < 2; ++rt)
        acc[rt][nt] = __builtin_amdgcn_mfma_f32_16x16x32_bf16(af[rt], bf, acc[rt][nt], 0, 0, 0);
    }
  }

  float sp[8], qp[8];
#pragma unroll
  for (int nt = 0; nt < 8; ++nt) { sp[nt] = 0.f; qp[nt] = 0.f; }

#pragma unroll
  for (int nt = 0; nt < 8; ++nt) {
    int gcol = nt * 16 + l15;
    float bv = bias[gcol];
#pragma unroll
    for (int rt = 0; rt < 2; ++rt) {
#pragma unroll
      for (int i = 0; i < 4; ++i) {
        int grow = row0 + w * 32 + rt * 16 + q * 4 + i;
        bool ok = (grow < N_NODES_C);
        float v = acc[rt][nt][i] + bv;
        if (RELU) v = fmaxf(v, 0.f);
        if (ok) outb[(size_t)grow * HID + gcol] = f2bf(v);
        if (STATS) {
          float c = ok ? v : 0.f;
          sp[nt] += c;
          qp[nt] += c * c;
        }
      }
    }
  }

  if (STATS) {
    __syncthreads();
    float* sred = (float*)a_lds;        // [128][16]
    float* qred = sred + 128 * 16;
    int slot = w * 4 + q;
#pragma unroll
    for (int nt = 0; nt < 8; ++nt) {
      int gcol = nt * 16 + l15;
      sred[gcol * 16 + slot] = sp[nt];
      qred[gcol * 16 + slot] = qp[nt];
    }
    __syncthreads();
    if (t < 128) {
      float s = 0.f;
#pragma unroll
      for (int i = 0; i < 16; ++i) s += sred[t * 16 + i];
      atomicAdd(&gsum[t], s);
    } else {
      int f = t - 128;
      float s = 0.f;
#pragma unroll
      for (int i = 0; i < 16; ++i) s += qred[f * 16 + i];
      atomicAdd(&gsumsq[f], s);
    }
  }
}

// BN (finalize folded in) + relu: reads t2 bf16, writes h bf16 (layers 0,1)
__global__ __launch_bounds__(256)
void k_bn_relu(const unsigned short* __restrict__ t2, const float* __restrict__ gsum,
               const float* __restrict__ gsumsq, const float* __restrict__ gamma,
               const float* __restrict__ beta, unsigned short* __restrict__ h) {
  __shared__ float sc[HID], sh[HID];
  int t = threadIdx.x;
  if (t < HID) {
    float mean = gsum[t] * (1.f / N_NODES_C);
    float var = gsumsq[t] * (1.f / N_NODES_C) - mean * mean;
    float inv = rsqrtf(var + BN_EPS_C);
    float s = gamma[t] * inv;
    sc[t] = s;
    sh[t] = beta[t] - mean * s;
  }
  __syncthreads();
  size_t idx = ((size_t)blockIdx.x * 256 + t) * 8;
  if (idx < (size_t)N_NODES_C * HID) {
    uint4 v = *(const uint4*)&t2[idx];
    int f = (int)(idx & 127);
    float2 p0 = bfp2f(v.x), p1 = bfp2f(v.y), p2 = bfp2f(v.z), p3 = bfp2f(v.w);
    float r0 = fmaxf(p0.x * sc[f + 0] + sh[f + 0], 0.f);
    float r1 = fmaxf(p0.y * sc[f + 1] + sh[f + 1], 0.f);
    float r2 = fmaxf(p1.x * sc[f + 2] + sh[f + 2], 0.f);
    float r3 = fmaxf(p1.y * sc[f + 3] + sh[f + 3], 0.f);
    float r4 = fmaxf(p2.x * sc[f + 4] + sh[f + 4], 0.f);
    float r5 = fmaxf(p2.y * sc[f + 5] + sh[f + 5], 0.f);
    float r6 = fmaxf(p3.x * sc[f + 6] + sh[f + 6], 0.f);
    float r7 = fmaxf(p3.y * sc[f + 7] + sh[f + 7], 0.f);
    uint4 o;
    o.x = (unsigned)f2bf(r0) | ((unsigned)f2bf(r1) << 16);
    o.y = (unsigned)f2bf(r2) | ((unsigned)f2bf(r3) << 16);
    o.z = (unsigned)f2bf(r4) | ((unsigned)f2bf(r5) << 16);
    o.w = (unsigned)f2bf(r6) | ((unsigned)f2bf(r7) << 16);
    *(uint4*)&h[idx] = o;
  }
}

// BN (finalize folded in) + relu + global_add_pool fused (last layer)
__global__ __launch_bounds__(128)
void k_bn_relu_pool(const unsigned short* __restrict__ t2, const float* __restrict__ gsum,
                    const float* __restrict__ gsumsq, const float* __restrict__ gamma,
                    const float* __restrict__ beta, const int* __restrict__ batch,
                    float* __restrict__ g) {
  int t = threadIdx.x;
  float mean = gsum[t] * (1.f / N_NODES_C);
  float var = gsumsq[t] * (1.f / N_NODES_C) - mean * mean;
  float inv = rsqrtf(var + BN_EPS_C);
  float sc = gamma[t] * inv;
  float sh = beta[t] - mean * sc;
  int n0 = blockIdx.x * 64;
  if (n0 >= N_NODES_C) return;
  int end = min(n0 + 64, N_NODES_C);
  int cur = batch[n0];
  float acc = 0.f;
  for (int n = n0; n < end; ++n) {
    int b = batch[n];
    if (b != cur) {
      atomicAdd(&g[cur * HID + t], acc);
      acc = 0.f;
      cur = b;
    }
    acc += fmaxf(bf2f(t2[(size_t)n * HID + t]) * sc + sh, 0.f);
  }
  atomicAdd(&g[cur * HID + t], acc);
}

// ---------------- head: relu(g@w1+b1)@w2+b2 ----------------
__global__ __launch_bounds__(128)
void k_head(const float* __restrict__ g, const float* __restrict__ w1,
            const float* __restrict__ b1, const float* __restrict__ w2,
            const float* __restrict__ b2, float* __restrict__ out) {
  __shared__ float gs[HID];
  __shared__ float red[HID * 2];
  int gi = blockIdx.x, t = threadIdx.x;
  gs[t] = g[gi * HID + t];
  __syncthreads();
  float acc = b1[t];
#pragma unroll 8
  for (int k = 0; k < HID; ++k) acc += gs[k] * w1[k * HID + t];
  float hid = fmaxf(acc, 0.f);
  red[t * 2] = hid * w2[t * 2];
  red[t * 2 + 1] = hid * w2[t * 2 + 1];
  __syncthreads();
  for (int s = 64; s > 0; s >>= 1) {
    if (t < s) { red[t * 2] += red[(t + s) * 2]; red[t * 2 + 1] += red[(t + s) * 2 + 1]; }
    __syncthreads();
  }
  if (t == 0) {
    out[gi * 2] = red[0] + b2[0];
    out[gi * 2 + 1] = red[1] + b2[1];
  }
}

extern "C" void kernel_launch(void* const* d_in, const int* in_sizes, int n_in,
                              void* d_out, int out_size, void* d_ws, size_t ws_size,
                              hipStream_t stream) {
  const float* x      = (const float*)d_in[0];
  const int*   eidx   = (const int*)d_in[1];
  const float* eattr  = (const float*)d_in[2];
  const int*   batch  = (const int*)d_in[3];
  const float* node_w = (const float*)d_in[4];
  const float* node_b = (const float*)d_in[5];
  const float* edge_w = (const float*)d_in[6];
  const float* edge_b = (const float*)d_in[7];
  const float* mlp_w1 = (const float*)d_in[8];
  const float* mlp_b1 = (const float*)d_in[9];
  const float* mlp_w2 = (const float*)d_in[10];
  const float* mlp_b2 = (const float*)d_in[11];
  const float* bn_g   = (const float*)d_in[12];
  const float* bn_b   = (const float*)d_in[13];
  const float* hw1    = (const float*)d_in[14];
  const float* hb1    = (const float*)d_in[15];
  const float* hw2    = (const float*)d_in[16];
  const float* hb2    = (const float*)d_in[17];
  const int* srcArr = eidx;
  const int* dstArr = eidx + N_EDGES_C;

  char* wsp = (char*)d_ws;
  size_t off = 0;
  auto alloc = [&](size_t bytes) {
    void* p = wsp + off;
    off += (bytes + 255) & ~(size_t)255;
    return p;
  };
  unsigned short* h    = (unsigned short*)alloc((size_t)N_NODES_C * HID * 2);   // 12.8 MB
  unsigned short* zbf  = (unsigned short*)alloc((size_t)N_NODES_C * HID * 2);   // 12.8 MB
  unsigned short* t1bf = (unsigned short*)alloc((size_t)N_NODES_C * HID * 2);   // 12.8 MB
  unsigned short* t2bf = (unsigned short*)alloc((size_t)N_NODES_C * HID * 2);   // 12.8 MB
  unsigned char* ea8   = (unsigned char*)alloc((size_t)N_EDGES_C * HID);        // 76.8 MB
  unsigned short* xb   = (unsigned short*)alloc((size_t)N_NODES_C * NODE_DIM_C * 2);  // 6.4 MB
  unsigned short* wT   = (unsigned short*)alloc(((size_t)6 * HID * HID + HID * NODE_DIM_C) * 2);
  int* row_ptr   = (int*)alloc((N_NODES_C + 1) * 4);
  int* cnt_cur   = (int*)alloc(N_NODES_C * 4);
  int* perm      = (int*)alloc((size_t)N_EDGES_C * 4);
  int* src_perm  = (int*)alloc((size_t)N_EDGES_C * 4);
  int* partial   = (int*)alloc(256 * 4);
  int* partial_off = (int*)alloc(256 * 4);
  float* gsum    = (float*)alloc(HID * 4);
  float* gsumsq  = (float*)alloc(HID * 4);
  float* g       = (float*)alloc((size_t)N_GRAPHS_C * HID * 4);
  unsigned short* nwT = wT + (size_t)6 * HID * HID;

  k_x2bf<<<(N_NODES_C * NODE_DIM_C / 4 + 255) / 256, 256, 0, stream>>>(x, xb,
                                                                       cnt_cur, g);
  k_prep_w<<<7, 256, 0, stream>>>(mlp_w1, mlp_w2, node_w, wT);
  k_node_mfma<<<(N_NODES_C + 127) / 128, 256, 0, stream>>>(xb, nwT, node_b, h);
  k_histogram<<<(N_EDGES_C + 255) / 256, 256, 0, stream>>>(dstArr, cnt_cur);
  k_blocksum<<<SCAN_NBLK, 256, 0, stream>>>(cnt_cur, partial);
  k_scanpartials<<<1, 256, 0, stream>>>(partial, partial_off);
  k_apply<<<SCAN_NBLK, 256, 0, stream>>>(cnt_cur, partial_off, row_ptr);
  k_bucket<<<(N_EDGES_C + 255) / 256, 256, 0, stream>>>(dstArr, srcArr, cnt_cur,
                                                        perm, src_perm);
  k_edge_encode<<<(N_EDGES_C + 127) / 128, 256, 0, stream>>>(perm, eattr, edge_w,
                                                             edge_b, ea8);

  const int GB = (N_NODES_C + 127) / 128;  // 391
  for (int l = 0; l < 3; ++l) {
    k_aggregate<<<(N_NODES_C + 3) / 4, 256, 0, stream>>>((const unsigned*)h, ea8,
                                                         src_perm, row_ptr, zbf,
                                                         gsum, gsumsq);
    k_gemm_mfma<true, false><<<GB, 256, 0, stream>>>(
        zbf, wT + (size_t)l * HID * HID, mlp_b1 + l * HID, t1bf, nullptr, nullptr);
    k_gemm_mfma<false, true><<<GB, 256, 0, stream>>>(
        t1bf, wT + (size_t)(3 + l) * HID * HID, mlp_b2 + l * HID, t2bf,
        gsum, gsumsq);
    if (l < 2) {
      k_bn_relu<<<(N_NODES_C * HID / 8 + 255) / 256, 256, 0, stream>>>(
          t2bf, gsum, gsumsq, bn_g + l * HID, bn_b + l * HID, h);
    } else {
      k_bn_relu_pool<<<(N_NODES_C + 63) / 64, 128, 0, stream>>>(
          t2bf, gsum, gsumsq, bn_g + l * HID, bn_b + l * HID, batch, g);
    }
  }
  k_head<<<N_GRAPHS_C, 128, 0, stream>>>(g, hw1, hb1, hw2, hb2, (float*)d_out);
}

// Round 11
// 479.554 us; speedup vs baseline: 2.5632x; 1.0784x over previous
//
#include <hip/hip_runtime.h>

#define N_NODES_C 50000
#define N_EDGES_C 600000
#define NODE_DIM_C 64
#define EDGE_DIM_C 16
#define HID 128
#define N_GRAPHS_C 256
#define BN_EPS_C 1e-5f
#define SCAN_NBLK ((N_NODES_C + 255) / 256)  // 196

typedef short bf16x8 __attribute__((ext_vector_type(8)));
typedef float f32x4 __attribute__((ext_vector_type(4)));
typedef float f32x2 __attribute__((ext_vector_type(2)));

__device__ __forceinline__ unsigned short f2bf(float f) {
  union { float f; unsigned u; } v; v.f = f;
  unsigned r = (v.u + 0x7fffu + ((v.u >> 16) & 1u)) >> 16;
  return (unsigned short)r;
}

__device__ __forceinline__ float2 bfp2f(unsigned u) {
  union { unsigned u; float f; } lo, hi;
  lo.u = u << 16;
  hi.u = u & 0xffff0000u;
  return make_float2(lo.f, hi.f);
}

__device__ __forceinline__ float bf2f(unsigned short s) {
  union { unsigned u; float f; } v;
  v.u = ((unsigned)s) << 16;
  return v.f;
}

// 2 fp8 (e4m3, HW) packed in low 16 bits -> 2 floats
__device__ __forceinline__ float2 fp8p2f(unsigned short u) {
  f32x2 r = __builtin_amdgcn_cvt_pk_f32_fp8((int)(unsigned)u, false);
  return make_float2(r.x, r.y);
}

// ---------- x -> bf16 conversion; also zero-inits cnt_cur and g ----------
__global__ __launch_bounds__(256)
void k_x2bf(const float* __restrict__ x, unsigned short* __restrict__ xb,
            int* __restrict__ cnt, float* __restrict__ g) {
  int tid = blockIdx.x * 256 + threadIdx.x;
  size_t i = (size_t)tid * 4;
  if (i < (size_t)N_NODES_C * NODE_DIM_C) {
    float4 v = *(const float4*)&x[i];
    uint2 o;
    o.x = (unsigned)f2bf(v.x) | ((unsigned)f2bf(v.y) << 16);
    o.y = (unsigned)f2bf(v.z) | ((unsigned)f2bf(v.w) << 16);
    *(uint2*)&xb[i] = o;
  }
  if (tid < N_NODES_C) cnt[tid] = 0;
  if (tid < N_GRAPHS_C * HID) g[tid] = 0.f;
}

// ------- weight prep: 6 MLP mats -> wT[m][n*128+k]; node_w -> nwT[n*64+k] ---
__global__ __launch_bounds__(256)
void k_prep_w(const float* __restrict__ w1, const float* __restrict__ w2,
              const float* __restrict__ nodew, unsigned short* __restrict__ wT) {
  int m = blockIdx.x;  // 0..6
  if (m < 6) {
    const float* src = (m < 3) ? (w1 + (size_t)m * HID * HID)
                               : (w2 + (size_t)(m - 3) * HID * HID);
    unsigned short* dst = wT + (size_t)m * HID * HID;
    for (int i = threadIdx.x; i < HID * HID; i += 256) {
      int n = i >> 7, k = i & 127;
      dst[n * HID + k] = f2bf(src[k * HID + n]);
    }
  } else {
    unsigned short* dst = wT + (size_t)6 * HID * HID;  // [128][64]
    for (int i = threadIdx.x; i < HID * NODE_DIM_C; i += 256) {
      int n = i >> 6, k = i & 63;
      dst[n * NODE_DIM_C + k] = f2bf(nodew[k * HID + n]);
    }
  }
}

// ------- node encoder via MFMA: h = bf16(x_bf @ node_w + node_b), K=64 ------
__global__ __launch_bounds__(256)
void k_node_mfma(const unsigned short* __restrict__ xb,
                 const unsigned short* __restrict__ nwT,
                 const float* __restrict__ bias, unsigned short* __restrict__ h) {
  const int LD = NODE_DIM_C + 8;  // 72
  __shared__ unsigned short a_lds[128 * LD];  // 18 KB
  __shared__ unsigned short w_lds[128 * LD];  // 18 KB
  int t = threadIdx.x;
  int row0 = blockIdx.x * 128;
  {
    int r = t >> 3, c = t & 7;
#pragma unroll
    for (int it = 0; it < 4; ++it) {
      int row = it * 32 + r;
      int grow = row0 + row;
      uint4 va = (grow < N_NODES_C)
                     ? ((const uint4*)(xb + (size_t)grow * NODE_DIM_C))[c]
                     : make_uint4(0, 0, 0, 0);
      *(uint4*)&a_lds[row * LD + c * 8] = va;
      uint4 vw = ((const uint4*)(nwT + (size_t)row * NODE_DIM_C))[c];
      *(uint4*)&w_lds[row * LD + c * 8] = vw;
    }
  }
  __syncthreads();

  int lane = t & 63;
  int w = t >> 6;
  int l15 = lane & 15;
  int q = lane >> 4;

  f32x4 acc[2][8];
#pragma unroll
  for (int rt = 0; rt < 2; ++rt)
#pragma unroll
    for (int nt = 0; nt < 8; ++nt) acc[rt][nt] = (f32x4)0.f;

#pragma unroll
  for (int kk = 0; kk < 2; ++kk) {
    int k0 = kk * 32;
    bf16x8 af[2];
#pragma unroll
    for (int rt = 0; rt < 2; ++rt) {
      int arow = w * 32 + rt * 16 + l15;
      af[rt] = *(const bf16x8*)&a_lds[arow * LD + k0 + q * 8];
    }
#pragma unroll
    for (int nt = 0; nt < 8; ++nt) {
      bf16x8 bf = *(const bf16x8*)&w_lds[(nt * 16 + l15) * LD + k0 + q * 8];
#pragma unroll
      for (int rt = 0; rt < 2; ++rt)
        acc[rt][nt] = __builtin_amdgcn_mfma_f32_16x16x32_bf16(af[rt], bf, acc[rt][nt], 0, 0, 0);
    }
  }

#pragma unroll
  for (int nt = 0; nt < 8; ++nt) {
    int gcol = nt * 16 + l15;
    float bv = bias[gcol];
#pragma unroll
    for (int rt = 0; rt < 2; ++rt) {
#pragma unroll
      for (int i = 0; i < 4; ++i) {
        int grow = row0 + w * 32 + rt * 16 + q * 4 + i;
        if (grow < N_NODES_C) h[(size_t)grow * HID + gcol] = f2bf(acc[rt][nt][i] + bv);
      }
    }
  }
}

// ---------------- CSR build (counting sort by dst) ----------------
__global__ __launch_bounds__(256)
void k_histogram(const int* __restrict__ dst, int* __restrict__ counts) {
  int e = blockIdx.x * 256 + threadIdx.x;
  if (e < N_EDGES_C) atomicAdd(&counts[dst[e]], 1);
}

__global__ __launch_bounds__(256)
void k_blocksum(const int* __restrict__ cnt, int* __restrict__ partial) {
  __shared__ int ls[4];
  int t = threadIdx.x;
  int i = blockIdx.x * 256 + t;
  int v = (i < N_NODES_C) ? cnt[i] : 0;
#pragma unroll
  for (int o = 32; o > 0; o >>= 1) v += __shfl_down(v, o, 64);
  if ((t & 63) == 0) ls[t >> 6] = v;
  __syncthreads();
  if (t == 0) partial[blockIdx.x] = ls[0] + ls[1] + ls[2] + ls[3];
}

__global__ __launch_bounds__(256)
void k_scanpartials(const int* __restrict__ partial, int* __restrict__ partial_off) {
  __shared__ int s[256];
  int t = threadIdx.x;
  int v = (t < SCAN_NBLK) ? partial[t] : 0;
  s[t] = v;
  __syncthreads();
  for (int d = 1; d < 256; d <<= 1) {
    int x = (t >= d) ? s[t - d] : 0;
    __syncthreads();
    s[t] += x;
    __syncthreads();
  }
  if (t < SCAN_NBLK) partial_off[t] = s[t] - v;
}

__global__ __launch_bounds__(256)
void k_apply(int* __restrict__ cnt_cursor, const int* __restrict__ partial_off,
             int* __restrict__ row_ptr) {
  __shared__ int s[256];
  int t = threadIdx.x;
  int i = blockIdx.x * 256 + t;
  int v = (i < N_NODES_C) ? cnt_cursor[i] : 0;
  s[t] = v;
  __syncthreads();
  for (int d = 1; d < 256; d <<= 1) {
    int x = (t >= d) ? s[t - d] : 0;
    __syncthreads();
    s[t] += x;
    __syncthreads();
  }
  int excl = s[t] - v + partial_off[blockIdx.x];
  if (i < N_NODES_C) {
    row_ptr[i] = excl;
    cnt_cursor[i] = excl;
  }
  if (i == 0) row_ptr[N_NODES_C] = N_EDGES_C;
}

// bucket: single 8B scattered store per edge (halves dirty-line amplification)
__global__ __launch_bounds__(256)
void k_bucket(const int* __restrict__ dst, const int* __restrict__ srcArr,
              int* __restrict__ cursor, int2* __restrict__ edata) {
  int e = blockIdx.x * 256 + threadIdx.x;
  if (e < N_EDGES_C) {
    int d = dst[e];
    int s = srcArr[e];
    int p = atomicAdd(&cursor[d], 1);
    edata[p] = make_int2(e, s);
  }
}

// ---- edge encoder via MFMA: ea8[i] = fp8(eattr[edata[i].x] @ ew + eb);
// also emits src_perm[i] = edata[i].y coalesced.
#define EE_LDW 40   // A/W row stride (shorts)
#define EE_OSW 132  // out tile row stride: epilogue banks (8q+l15/2), conflict-free
__global__ __launch_bounds__(256)
void k_edge_encode(const int2* __restrict__ edata, const float* __restrict__ eattr,
                   const float* __restrict__ ew, const float* __restrict__ ebias,
                   unsigned char* __restrict__ ea8, int* __restrict__ src_perm) {
  __shared__ unsigned short smem[128 * EE_OSW];  // 33 KB; overlays A,W then OUT
  unsigned short* a_lds = smem;                  // [128][EE_LDW]
  unsigned short* w_lds = smem + 128 * EE_LDW;   // [128][EE_LDW]
  int t = threadIdx.x;
  int EB = blockIdx.x * 128;

  // stage W: one thread per output column n
  if (t < 128) {
    unsigned short tmp[16];
#pragma unroll
    for (int k = 0; k < 16; ++k) tmp[k] = f2bf(ew[k * HID + t]);
    uint4* wr = (uint4*)&w_lds[t * EE_LDW];
    wr[0] = *(uint4*)&tmp[0];
    wr[1] = *(uint4*)&tmp[8];
    wr[2] = make_uint4(0, 0, 0, 0);
    wr[3] = make_uint4(0, 0, 0, 0);
  }
  // stage A: 2 threads per edge
  {
    int edge = t >> 1, half = t & 1;
    int gi = EB + edge;
    float4 v0 = make_float4(0, 0, 0, 0), v1 = v0;
    if (gi < N_EDGES_C) {
      int2 ed = edata[gi];
      if (half == 0) src_perm[gi] = ed.y;
      const float4* p = (const float4*)(eattr + (size_t)ed.x * EDGE_DIM_C + half * 8);
      v0 = p[0];
      v1 = p[1];
    }
    unsigned short tmp[8] = {f2bf(v0.x), f2bf(v0.y), f2bf(v0.z), f2bf(v0.w),
                             f2bf(v1.x), f2bf(v1.y), f2bf(v1.z), f2bf(v1.w)};
    *(uint4*)&a_lds[edge * EE_LDW + half * 8] = *(uint4*)tmp;
    *(uint4*)&a_lds[edge * EE_LDW + 16 + half * 8] = make_uint4(0, 0, 0, 0);
  }
  __syncthreads();

  int lane = t & 63;
  int w = t >> 6;
  int l15 = lane & 15;
  int q = lane >> 4;

  f32x4 acc[2][8];
  {
    bf16x8 af[2];
#pragma unroll
    for (int rt = 0; rt < 2; ++rt) {
      int arow = w * 32 + rt * 16 + l15;
      af[rt] = *(const bf16x8*)&a_lds[arow * EE_LDW + q * 8];
    }
#pragma unroll
    for (int nt = 0; nt < 8; ++nt) {
      bf16x8 bf = *(const bf16x8*)&w_lds[(nt * 16 + l15) * EE_LDW + q * 8];
#pragma unroll
      for (int rt = 0; rt < 2; ++rt)
        acc[rt][nt] = __builtin_amdgcn_mfma_f32_16x16x32_bf16(
            af[rt], bf, (f32x4)0.f, 0, 0, 0);
    }
  }
  __syncthreads();  // smem becomes the output tile [128][EE_OSW]

#pragma unroll
  for (int nt = 0; nt < 8; ++nt) {
    int col = nt * 16 + l15;
    float bv = ebias[col];
#pragma unroll
    for (int rt = 0; rt < 2; ++rt) {
#pragma unroll
      for (int i = 0; i < 4; ++i) {
        int row = w * 32 + rt * 16 + q * 4 + i;
        smem[row * EE_OSW + col] = f2bf(acc[rt][nt][i] + bv);
      }
    }
  }
  __syncthreads();

  int valid = min(128, N_EDGES_C - EB);
  for (int i = t; i < valid * 32; i += 256) {
    int row = i >> 5, c = i & 31;
    uint2 v = *(const uint2*)&smem[row * EE_OSW + c * 4];
    float2 p0 = bfp2f(v.x);
    float2 p1 = bfp2f(v.y);
    int r = __builtin_amdgcn_cvt_pk_fp8_f32(p0.x, p0.y, 0, false);
    r = __builtin_amdgcn_cvt_pk_fp8_f32(p1.x, p1.y, r, true);
    *(unsigned*)&ea8[((size_t)EB + row) * 128 + c * 4] = (unsigned)r;
  }
}

// -------- aggregate: z[n] = h[n] + sum_{e: dst=n} relu(h[src_e] + ea_e) -----
__global__ __launch_bounds__(256)
void k_aggregate(const unsigned* __restrict__ h32, const unsigned char* __restrict__ ea8,
                 const int* __restrict__ src_p, const int* __restrict__ row_ptr,
                 unsigned short* __restrict__ z, float* __restrict__ gsum,
                 float* __restrict__ gsumsq) {
  int t = threadIdx.x;
  if (blockIdx.x == 0 && t < HID) { gsum[t] = 0.f; gsumsq[t] = 0.f; }
  int lane = t & 63;
  int wave = t >> 6;
  int node = blockIdx.x * 4 + wave;
  if (node >= N_NODES_C) return;
  float2 base = bfp2f(h32[(size_t)node * 64 + lane]);
  float acc0 = base.x, acc1 = base.y;
  int beg = row_ptr[node], end = row_ptr[node + 1];
  const unsigned char* eap = ea8 + lane * 2;
  int j = beg;
  for (; j + 8 <= end; j += 8) {
    int s0 = src_p[j],     s1 = src_p[j + 1], s2 = src_p[j + 2], s3 = src_p[j + 3];
    int s4 = src_p[j + 4], s5 = src_p[j + 5], s6 = src_p[j + 6], s7 = src_p[j + 7];
    unsigned g0 = h32[(size_t)s0 * 64 + lane];
    unsigned g1 = h32[(size_t)s1 * 64 + lane];
    unsigned g2 = h32[(size_t)s2 * 64 + lane];
    unsigned g3 = h32[(size_t)s3 * 64 + lane];
    unsigned g4 = h32[(size_t)s4 * 64 + lane];
    unsigned g5 = h32[(size_t)s5 * 64 + lane];
    unsigned g6 = h32[(size_t)s6 * 64 + lane];
    unsigned g7 = h32[(size_t)s7 * 64 + lane];
    unsigned short u0 = *(const unsigned short*)(eap + (size_t)j * 128);
    unsigned short u1 = *(const unsigned short*)(eap + (size_t)(j + 1) * 128);
    unsigned short u2 = *(const unsigned short*)(eap + (size_t)(j + 2) * 128);
    unsigned short u3 = *(const unsigned short*)(eap + (size_t)(j + 3) * 128);
    unsigned short u4 = *(const unsigned short*)(eap + (size_t)(j + 4) * 128);
    unsigned short u5 = *(const unsigned short*)(eap + (size_t)(j + 5) * 128);
    unsigned short u6 = *(const unsigned short*)(eap + (size_t)(j + 6) * 128);
    unsigned short u7 = *(const unsigned short*)(eap + (size_t)(j + 7) * 128);
    float2 a0 = bfp2f(g0), a1 = bfp2f(g1), a2 = bfp2f(g2), a3 = bfp2f(g3);
    float2 a4 = bfp2f(g4), a5 = bfp2f(g5), a6 = bfp2f(g6), a7 = bfp2f(g7);
    float2 e0 = fp8p2f(u0), e1 = fp8p2f(u1), e2 = fp8p2f(u2), e3 = fp8p2f(u3);
    float2 e4 = fp8p2f(u4), e5 = fp8p2f(u5), e6 = fp8p2f(u6), e7 = fp8p2f(u7);
    acc0 += fmaxf(a0.x + e0.x, 0.f) + fmaxf(a1.x + e1.x, 0.f) +
            fmaxf(a2.x + e2.x, 0.f) + fmaxf(a3.x + e3.x, 0.f) +
            fmaxf(a4.x + e4.x, 0.f) + fmaxf(a5.x + e5.x, 0.f) +
            fmaxf(a6.x + e6.x, 0.f) + fmaxf(a7.x + e7.x, 0.f);
    acc1 += fmaxf(a0.y + e0.y, 0.f) + fmaxf(a1.y + e1.y, 0.f) +
            fmaxf(a2.y + e2.y, 0.f) + fmaxf(a3.y + e3.y, 0.f) +
            fmaxf(a4.y + e4.y, 0.f) + fmaxf(a5.y + e5.y, 0.f) +
            fmaxf(a6.y + e6.y, 0.f) + fmaxf(a7.y + e7.y, 0.f);
  }
  for (; j + 4 <= end; j += 4) {
    int s0 = src_p[j], s1 = src_p[j + 1], s2 = src_p[j + 2], s3 = src_p[j + 3];
    unsigned g0 = h32[(size_t)s0 * 64 + lane];
    unsigned g1 = h32[(size_t)s1 * 64 + lane];
    unsigned g2 = h32[(size_t)s2 * 64 + lane];
    unsigned g3 = h32[(size_t)s3 * 64 + lane];
    unsigned short u0 = *(const unsigned short*)(eap + (size_t)j * 128);
    unsigned short u1 = *(const unsigned short*)(eap + (size_t)(j + 1) * 128);
    unsigned short u2 = *(const unsigned short*)(eap + (size_t)(j + 2) * 128);
    unsigned short u3 = *(const unsigned short*)(eap + (size_t)(j + 3) * 128);
    float2 a0 = bfp2f(g0), a1 = bfp2f(g1), a2 = bfp2f(g2), a3 = bfp2f(g3);
    float2 e0 = fp8p2f(u0), e1 = fp8p2f(u1), e2 = fp8p2f(u2), e3 = fp8p2f(u3);
    acc0 += fmaxf(a0.x + e0.x, 0.f) + fmaxf(a1.x + e1.x, 0.f) +
            fmaxf(a2.x + e2.x, 0.f) + fmaxf(a3.x + e3.x, 0.f);
    acc1 += fmaxf(a0.y + e0.y, 0.f) + fmaxf(a1.y + e1.y, 0.f) +
            fmaxf(a2.y + e2.y, 0.f) + fmaxf(a3.y + e3.y, 0.f);
  }
  for (; j < end; ++j) {
    int s0 = src_p[j];
    float2 a0 = bfp2f(h32[(size_t)s0 * 64 + lane]);
    float2 e0 = fp8p2f(*(const unsigned short*)(eap + (size_t)j * 128));
    acc0 += fmaxf(a0.x + e0.x, 0.f);
    acc1 += fmaxf(a0.y + e0.y, 0.f);
  }
  unsigned packed = (unsigned)f2bf(acc0) | ((unsigned)f2bf(acc1) << 16);
  *(unsigned*)&z[(size_t)node * HID + lane * 2] = packed;
}

// ---- fused MLP: t2 = (relu(z@w1+b1))@w2+b2, both GEMMs in one kernel ------
// pass 1 result lives in LDS (stride 132, conflict-free); w2 restaged over w1.
// Output bf16 + fused BN column stats (fp32, pre-round). Pad rows masked.
__global__ __launch_bounds__(256)
void k_mlp_fused(const unsigned short* __restrict__ in,
                 const unsigned short* __restrict__ w1T,
                 const float* __restrict__ b1,
                 const unsigned short* __restrict__ w2T,
                 const float* __restrict__ b2,
                 unsigned short* __restrict__ outb,
                 float* __restrict__ gsum, float* __restrict__ gsumsq) {
  const int LDA = HID + 8;  // 136
  const int OS = 132;       // t1 tile stride: epilogue write conflict-free
  __shared__ unsigned short a_lds[128 * LDA];  // 34.8 KB (z, then t1 @ stride OS)
  __shared__ unsigned short w_lds[128 * LDA];  // 34.8 KB (w1T, then w2T)
  int t = threadIdx.x;
  int row0 = blockIdx.x * 128;
  {
    int r = t >> 4, chunk = t & 15;
#pragma unroll
    for (int it = 0; it < 8; ++it) {
      int row = it * 16 + r;
      int grow = row0 + row;
      uint4 va = (grow < N_NODES_C)
                     ? ((const uint4*)(in + (size_t)grow * HID))[chunk]
                     : make_uint4(0, 0, 0, 0);
      *(uint4*)&a_lds[row * LDA + chunk * 8] = va;
      uint4 vw = ((const uint4*)(w1T + (size_t)row * HID))[chunk];
      *(uint4*)&w_lds[row * LDA + chunk * 8] = vw;
    }
  }
  __syncthreads();

  int lane = t & 63;
  int w = t >> 6;
  int l15 = lane & 15;
  int q = lane >> 4;

  // ---- pass 1: z @ w1 ----
  f32x4 acc[2][8];
#pragma unroll
  for (int rt = 0; rt < 2; ++rt)
#pragma unroll
    for (int nt = 0; nt < 8; ++nt) acc[rt][nt] = (f32x4)0.f;

#pragma unroll
  for (int kk = 0; kk < 4; ++kk) {
    int k0 = kk * 32;
    bf16x8 af[2];
#pragma unroll
    for (int rt = 0; rt < 2; ++rt) {
      int arow = w * 32 + rt * 16 + l15;
      af[rt] = *(const bf16x8*)&a_lds[arow * LDA + k0 + q * 8];
    }
#pragma unroll
    for (int nt = 0; nt < 8; ++nt) {
      int brow = nt * 16 + l15;
      bf16x8 bf = *(const bf16x8*)&w_lds[brow * LDA + k0 + q * 8];
#pragma unroll
      for (int rt = 0; rt < 2; ++rt)
        acc[rt][nt] = __builtin_amdgcn_mfma_f32_16x16x32_bf16(af[rt], bf, acc[rt][nt], 0, 0, 0);
    }
  }
  __syncthreads();  // all pass-1 LDS reads done; safe to overwrite

  // t1 = bf16(relu(acc + b1)) -> a_lds at stride OS; restage w2T -> w_lds
#pragma unroll
  for (int nt = 0; nt < 8; ++nt) {
    int col = nt * 16 + l15;
    float bv = b1[col];
#pragma unroll
    for (int rt = 0; rt < 2; ++rt) {
#pragma unroll
      for (int i = 0; i < 4; ++i) {
        int row = w * 32 + rt * 16 + q * 4 + i;
        a_lds[row * OS + col] = f2bf(fmaxf(acc[rt][nt][i] + bv, 0.f));
      }
    }
  }
  {
    int r = t >> 4, chunk = t & 15;
#pragma unroll
    for (int it = 0; it < 8; ++it) {
      int row = it * 16 + r;
      uint4 vw = ((const uint4*)(w2T + (size_t)row * HID))[chunk];
      *(uint4*)&w_lds[row * LDA + chunk * 8] = vw;
    }
  }
  __syncthreads();

  // ---- pass 2: t1 @ w2 ----
#pragma unroll
  for (int rt = 0; rt < 2; ++rt)
#pragma unroll
    for (int nt = 0; nt < 8; ++nt) acc[rt][nt] = (f32x4)0.f;

#pragma unroll
  for (int kk = 0; kk < 4; ++kk) {
    int k0 = kk * 32;
    bf16x8 af[2];
#pragma unroll
    for (int rt = 0; rt < 2; ++rt) {
      int arow = w * 32 + rt * 16 + l15;
      af[rt] = *(const bf16x8*)&a_lds[arow * OS + k0 + q * 8];
    }
#pragma unroll
    for (int nt = 0; nt < 8; ++nt) {
      int brow = nt * 16 + l15;
      bf16x8 bf = *(const bf16x8*)&w_lds[brow * LDA + k0 + q * 8];
#pragma unroll
      for (int rt = 0; rt < 2; ++rt)
        acc[rt][nt] = __builtin_amdgcn_mfma_f32_16x16x32_bf16(af[rt], bf, acc[rt][nt], 0, 0, 0);
    }
  }

  float sp[8], qp[8];
#pragma unroll
  for (int nt = 0; nt < 8; ++nt) { sp[nt] = 0.f; qp[nt] = 0.f; }

#pragma unroll
  for (int nt = 0; nt < 8; ++nt) {
    int gcol = nt * 16 + l15;
    float bv = b2[gcol];
#pragma unroll
    for (int rt = 0; rt < 2; ++rt) {
#pragma unroll
      for (int i = 0; i < 4; ++i) {
        int grow = row0 + w * 32 + rt * 16 + q * 4 + i;
        bool ok = (grow < N_NODES_C);
        float v = acc[rt][nt][i] + bv;
        if (ok) outb[(size_t)grow * HID + gcol] = f2bf(v);
        float c = ok ? v : 0.f;
        sp[nt] += c;
        qp[nt] += c * c;
      }
    }
  }

  __syncthreads();  // all pass-2 LDS reads done; reuse a_lds as reduce scratch
  float* sred = (float*)a_lds;        // [128][16]
  float* qred = sred + 128 * 16;
  int slot = w * 4 + q;
#pragma unroll
  for (int nt = 0; nt < 8; ++nt) {
    int gcol = nt * 16 + l15;
    sred[gcol * 16 + slot] = sp[nt];
    qred[gcol * 16 + slot] = qp[nt];
  }
  __syncthreads();
  if (t < 128) {
    float s = 0.f;
#pragma unroll
    for (int i = 0; i < 16; ++i) s += sred[t * 16 + i];
    atomicAdd(&gsum[t], s);
  } else {
    int f = t - 128;
    float s = 0.f;
#pragma unroll
    for (int i = 0; i < 16; ++i) s += qred[f * 16 + i];
    atomicAdd(&gsumsq[f], s);
  }
}

// BN (finalize folded in) + relu: reads t2 bf16, writes h bf16 (layers 0,1)
__global__ __launch_bounds__(256)
void k_bn_relu(const unsigned short* __restrict__ t2, const float* __restrict__ gsum,
               const float* __restrict__ gsumsq, const float* __restrict__ gamma,
               const float* __restrict__ beta, unsigned short* __restrict__ h) {
  __shared__ float sc[HID], sh[HID];
  int t = threadIdx.x;
  if (t < HID) {
    float mean = gsum[t] * (1.f / N_NODES_C);
    float var = gsumsq[t] * (1.f / N_NODES_C) - mean * mean;
    float inv = rsqrtf(var + BN_EPS_C);
    float s = gamma[t] * inv;
    sc[t] = s;
    sh[t] = beta[t] - mean * s;
  }
  __syncthreads();
  size_t idx = ((size_t)blockIdx.x * 256 + t) * 8;
  if (idx < (size_t)N_NODES_C * HID) {
    uint4 v = *(const uint4*)&t2[idx];
    int f = (int)(idx & 127);
    float2 p0 = bfp2f(v.x), p1 = bfp2f(v.y), p2 = bfp2f(v.z), p3 = bfp2f(v.w);
    float r0 = fmaxf(p0.x * sc[f + 0] + sh[f + 0], 0.f);
    float r1 = fmaxf(p0.y * sc[f + 1] + sh[f + 1], 0.f);
    float r2 = fmaxf(p1.x * sc[f + 2] + sh[f + 2], 0.f);
    float r3 = fmaxf(p1.y * sc[f + 3] + sh[f + 3], 0.f);
    float r4 = fmaxf(p2.x * sc[f + 4] + sh[f + 4], 0.f);
    float r5 = fmaxf(p2.y * sc[f + 5] + sh[f + 5], 0.f);
    float r6 = fmaxf(p3.x * sc[f + 6] + sh[f + 6], 0.f);
    float r7 = fmaxf(p3.y * sc[f + 7] + sh[f + 7], 0.f);
    uint4 o;
    o.x = (unsigned)f2bf(r0) | ((unsigned)f2bf(r1) << 16);
    o.y = (unsigned)f2bf(r2) | ((unsigned)f2bf(r3) << 16);
    o.z = (unsigned)f2bf(r4) | ((unsigned)f2bf(r5) << 16);
    o.w = (unsigned)f2bf(r6) | ((unsigned)f2bf(r7) << 16);
    *(uint4*)&h[idx] = o;
  }
}

// BN (finalize folded in) + relu + global_add_pool fused (last layer)
__global__ __launch_bounds__(128)
void k_bn_relu_pool(const unsigned short* __restrict__ t2, const float* __restrict__ gsum,
                    const float* __restrict__ gsumsq, const float* __restrict__ gamma,
                    const float* __restrict__ beta, const int* __restrict__ batch,
                    float* __restrict__ g) {
  int t = threadIdx.x;
  float mean = gsum[t] * (1.f / N_NODES_C);
  float var = gsumsq[t] * (1.f / N_NODES_C) - mean * mean;
  float inv = rsqrtf(var + BN_EPS_C);
  float sc = gamma[t] * inv;
  float sh = beta[t] - mean * sc;
  int n0 = blockIdx.x * 64;
  if (n0 >= N_NODES_C) return;
  int end = min(n0 + 64, N_NODES_C);
  int cur = batch[n0];
  float acc = 0.f;
  for (int n = n0; n < end; ++n) {
    int b = batch[n];
    if (b != cur) {
      atomicAdd(&g[cur * HID + t], acc);
      acc = 0.f;
      cur = b;
    }
    acc += fmaxf(bf2f(t2[(size_t)n * HID + t]) * sc + sh, 0.f);
  }
  atomicAdd(&g[cur * HID + t], acc);
}

// ---------------- head: relu(g@w1+b1)@w2+b2 ----------------
__global__ __launch_bounds__(128)
void k_head(const float* __restrict__ g, const float* __restrict__ w1,
            const float* __restrict__ b1, const float* __restrict__ w2,
            const float* __restrict__ b2, float* __restrict__ out) {
  __shared__ float gs[HID];
  __shared__ float red[HID * 2];
  int gi = blockIdx.x, t = threadIdx.x;
  gs[t] = g[gi * HID + t];
  __syncthreads();
  float acc = b1[t];
#pragma unroll 8
  for (int k = 0; k < HID; ++k) acc += gs[k] * w1[k * HID + t];
  float hid = fmaxf(acc, 0.f);
  red[t * 2] = hid * w2[t * 2];
  red[t * 2 + 1] = hid * w2[t * 2 + 1];
  __syncthreads();
  for (int s = 64; s > 0; s >>= 1) {
    if (t < s) { red[t * 2] += red[(t + s) * 2]; red[t * 2 + 1] += red[(t + s) * 2 + 1]; }
    __syncthreads();
  }
  if (t == 0) {
    out[gi * 2] = red[0] + b2[0];
    out[gi * 2 + 1] = red[1] + b2[1];
  }
}

extern "C" void kernel_launch(void* const* d_in, const int* in_sizes, int n_in,
                              void* d_out, int out_size, void* d_ws, size_t ws_size,
                              hipStream_t stream) {
  const float* x      = (const float*)d_in[0];
  const int*   eidx   = (const int*)d_in[1];
  const float* eattr  = (const float*)d_in[2];
  const int*   batch  = (const int*)d_in[3];
  const float* node_w = (const float*)d_in[4];
  const float* node_b = (const float*)d_in[5];
  const float* edge_w = (const float*)d_in[6];
  const float* edge_b = (const float*)d_in[7];
  const float* mlp_w1 = (const float*)d_in[8];
  const float* mlp_b1 = (const float*)d_in[9];
  const float* mlp_w2 = (const float*)d_in[10];
  const float* mlp_b2 = (const float*)d_in[11];
  const float* bn_g   = (const float*)d_in[12];
  const float* bn_b   = (const float*)d_in[13];
  const float* hw1    = (const float*)d_in[14];
  const float* hb1    = (const float*)d_in[15];
  const float* hw2    = (const float*)d_in[16];
  const float* hb2    = (const float*)d_in[17];
  const int* srcArr = eidx;
  const int* dstArr = eidx + N_EDGES_C;

  char* wsp = (char*)d_ws;
  size_t off = 0;
  auto alloc = [&](size_t bytes) {
    void* p = wsp + off;
    off += (bytes + 255) & ~(size_t)255;
    return p;
  };
  unsigned short* h    = (unsigned short*)alloc((size_t)N_NODES_C * HID * 2);   // 12.8 MB
  unsigned short* zbf  = (unsigned short*)alloc((size_t)N_NODES_C * HID * 2);   // 12.8 MB
  unsigned short* t2bf = (unsigned short*)alloc((size_t)N_NODES_C * HID * 2);   // 12.8 MB
  unsigned char* ea8   = (unsigned char*)alloc((size_t)N_EDGES_C * HID);        // 76.8 MB
  unsigned short* xb   = (unsigned short*)alloc((size_t)N_NODES_C * NODE_DIM_C * 2);  // 6.4 MB
  unsigned short* wT   = (unsigned short*)alloc(((size_t)6 * HID * HID + HID * NODE_DIM_C) * 2);
  int* row_ptr   = (int*)alloc((N_NODES_C + 1) * 4);
  int* cnt_cur   = (int*)alloc(N_NODES_C * 4);
  int2* edata    = (int2*)alloc((size_t)N_EDGES_C * 8);  // 4.8 MB
  int* src_perm  = (int*)alloc((size_t)N_EDGES_C * 4);
  int* partial   = (int*)alloc(256 * 4);
  int* partial_off = (int*)alloc(256 * 4);
  float* gsum    = (float*)alloc(HID * 4);
  float* gsumsq  = (float*)alloc(HID * 4);
  float* g       = (float*)alloc((size_t)N_GRAPHS_C * HID * 4);
  unsigned short* nwT = wT + (size_t)6 * HID * HID;

  k_x2bf<<<(N_NODES_C * NODE_DIM_C / 4 + 255) / 256, 256, 0, stream>>>(x, xb,
                                                                       cnt_cur, g);
  k_prep_w<<<7, 256, 0, stream>>>(mlp_w1, mlp_w2, node_w, wT);
  k_node_mfma<<<(N_NODES_C + 127) / 128, 256, 0, stream>>>(xb, nwT, node_b, h);
  k_histogram<<<(N_EDGES_C + 255) / 256, 256, 0, stream>>>(dstArr, cnt_cur);
  k_blocksum<<<SCAN_NBLK, 256, 0, stream>>>(cnt_cur, partial);
  k_scanpartials<<<1, 256, 0, stream>>>(partial, partial_off);
  k_apply<<<SCAN_NBLK, 256, 0, stream>>>(cnt_cur, partial_off, row_ptr);
  k_bucket<<<(N_EDGES_C + 255) / 256, 256, 0, stream>>>(dstArr, srcArr, cnt_cur,
                                                        edata);
  k_edge_encode<<<(N_EDGES_C + 127) / 128, 256, 0, stream>>>(edata, eattr, edge_w,
                                                             edge_b, ea8, src_perm);

  const int GB = (N_NODES_C + 127) / 128;  // 391
  for (int l = 0; l < 3; ++l) {
    k_aggregate<<<(N_NODES_C + 3) / 4, 256, 0, stream>>>((const unsigned*)h, ea8,
                                                         src_perm, row_ptr, zbf,
                                                         gsum, gsumsq);
    k_mlp_fused<<<GB, 256, 0, stream>>>(
        zbf, wT + (size_t)l * HID * HID, mlp_b1 + l * HID,
        wT + (size_t)(3 + l) * HID * HID, mlp_b2 + l * HID, t2bf, gsum, gsumsq);
    if (l < 2) {
      k_bn_relu<<<(N_NODES_C * HID / 8 + 255) / 256, 256, 0, stream>>>(
          t2bf, gsum, gsumsq, bn_g + l * HID, bn_b + l * HID, h);
    } else {
      k_bn_relu_pool<<<(N_NODES_C + 63) / 64, 128, 0, stream>>>(
          t2bf, gsum, gsumsq, bn_g + l * HID, bn_b + l * HID, batch, g);
    }
  }
  k_head<<<N_GRAPHS_C, 128, 0, stream>>>(g, hw1, hb1, hw2, hb2, (float*)d_out);
}